// Round 1
// baseline (1791.481 us; speedup 1.0000x reference)
//
#include <hip/hip_runtime.h>
#include <hip/hip_bf16.h>
#include <math.h>

#define CDIM 384
#define NHEAD 8
#define HD 48
#define OUTD 32
#define MAXB 16

// ---- order-preserving float<->uint encoding for atomicMax-based segment max ----
__device__ __forceinline__ unsigned enc_f(float f) {
  unsigned u = __float_as_uint(f);
  return (u & 0x80000000u) ? ~u : (u | 0x80000000u);
}
__device__ __forceinline__ float dec_f(unsigned u) {
  unsigned v = (u & 0x80000000u) ? (u ^ 0x80000000u) : ~u;
  return __uint_as_float(v);
}

__global__ void init_small_kernel(int* smin, int* smax, int* eb) {
  int t = threadIdx.x;
  if (t < MAXB * 3) { smin[t] = 0x7fffffff; smax[t] = (int)0x80000000; }
  if (t <= MAXB) eb[t] = 0;
}

__global__ void minmax_kernel(const int* __restrict__ ec, int Me,
                              const int* __restrict__ pc, int Mp,
                              int* smin, int* smax) {
  __shared__ int lmin[MAXB * 3], lmax[MAXB * 3];
  int t = threadIdx.x;
  if (t < MAXB * 3) { lmin[t] = 0x7fffffff; lmax[t] = (int)0x80000000; }
  __syncthreads();
  int i = blockIdx.x * blockDim.x + t;
  int tot = Me + Mp;
  if (i < tot) {
    const int* r = (i < Me) ? (ec + 4 * i) : (pc + 4 * (i - Me));
    int b = r[0];
    #pragma unroll
    for (int d = 0; d < 3; ++d) {
      atomicMin(&lmin[b * 3 + d], r[1 + d]);
      atomicMax(&lmax[b * 3 + d], r[1 + d]);
    }
  }
  __syncthreads();
  if (t < MAXB * 3) {
    if (lmin[t] != 0x7fffffff) atomicMin(&smin[t], lmin[t]);
    if (lmax[t] != (int)0x80000000) atomicMax(&smax[t], lmax[t]);
  }
}

// emb_coords are sorted by batch (np.unique) -> find per-batch [start,end) ranges
__global__ void ebound_kernel(const int* __restrict__ ec, int Me,
                              const int* __restrict__ bsz, int* eb) {
  int e = blockIdx.x * blockDim.x + threadIdx.x;
  if (e == 0) { eb[0] = 0; eb[bsz[0]] = Me; }
  if (e > 0 && e < Me) {
    int b0 = ec[4 * (e - 1)], b1 = ec[4 * e];
    for (int bb = b0 + 1; bb <= b1; ++bb) eb[bb] = e;
  }
}

// C[M x 384] = A[M x 384] @ W[384 x 384] + bias
// SCATTER: atomicMax(dstU[inv[row]*384 + col], enc(val))   (segment max)
// else:    dstF[row*384 + col] = val
template <bool SCATTER>
__global__ __launch_bounds__(256) void gemm_kernel(
    const float* __restrict__ A, int M,
    const float* __restrict__ W, const float* __restrict__ bias,
    float* __restrict__ dstF, unsigned* __restrict__ dstU,
    const int* __restrict__ inv) {
  __shared__ float As[16][68];  // [k][row], padded
  __shared__ float Bs[16][64];  // [k][col]
  int r0 = blockIdx.x * 64;
  int n0 = blockIdx.y * 64;
  int t = threadIdx.x;
  int tx = t & 15, ty = t >> 4;
  float acc[4][4] = {};
  for (int k0 = 0; k0 < CDIM; k0 += 16) {
    {
      int row = t >> 2, kg = (t & 3) * 4;
      float4 a = make_float4(0.f, 0.f, 0.f, 0.f);
      int gr = r0 + row;
      if (gr < M) a = *reinterpret_cast<const float4*>(A + (size_t)gr * CDIM + k0 + kg);
      As[kg + 0][row] = a.x; As[kg + 1][row] = a.y;
      As[kg + 2][row] = a.z; As[kg + 3][row] = a.w;
    }
    {
      int kk = t >> 4, cg = (t & 15) * 4;
      float4 b = *reinterpret_cast<const float4*>(W + (size_t)(k0 + kk) * CDIM + n0 + cg);
      *reinterpret_cast<float4*>(&Bs[kk][cg]) = b;
    }
    __syncthreads();
    #pragma unroll
    for (int kk = 0; kk < 16; ++kk) {
      float4 av = *reinterpret_cast<const float4*>(&As[kk][ty * 4]);
      float4 bv = *reinterpret_cast<const float4*>(&Bs[kk][tx * 4]);
      float a[4] = {av.x, av.y, av.z, av.w};
      float b[4] = {bv.x, bv.y, bv.z, bv.w};
      #pragma unroll
      for (int i = 0; i < 4; ++i)
        #pragma unroll
        for (int j = 0; j < 4; ++j) acc[i][j] += a[i] * b[j];
    }
    __syncthreads();
  }
  #pragma unroll
  for (int i = 0; i < 4; ++i) {
    int gr = r0 + ty * 4 + i;
    if (gr >= M) break;
    int seg = SCATTER ? inv[gr] : 0;
    #pragma unroll
    for (int j = 0; j < 4; ++j) {
      int gc = n0 + tx * 4 + j;
      float v = acc[i][j] + bias[gc];
      if (SCATTER) atomicMax(&dstU[(size_t)seg * CDIM + gc], enc_f(v));
      else dstF[(size_t)gr * CDIM + gc] = v;
    }
  }
}

// decode encoded segment-max in place, add sine positional encoding
__global__ void pe_kernel(unsigned* __restrict__ pool_buf, unsigned* __restrict__ emb_buf,
                          const int* __restrict__ pc, int Mp,
                          const int* __restrict__ ec, int Me,
                          const int* __restrict__ smin, const int* __restrict__ smax) {
  int gid = blockIdx.x * blockDim.x + threadIdx.x;
  int total = (Mp + Me) * CDIM;
  if (gid >= total) return;
  int row = gid / CDIM, c = gid - row * CDIM;
  const int* coords;
  unsigned* buf;
  int lrow;
  if (row < Me) { lrow = row; coords = ec + 4 * row; buf = emb_buf; }
  else { lrow = row - Me; coords = pc + 4 * lrow; buf = pool_buf; }
  int b = coords[0];
  int dim = c >> 7;       // c / 128
  int i = c & 127;
  int j = i >> 1;
  float x = (float)coords[1 + dim];
  float mn = (float)smin[b * 3 + dim];
  float mx = (float)smax[b * 3 + dim];
  float nrm = (x - mn) / (mx - mn + 1e-6f);
  float freq = exp2f(-(float)j * 0.20762050593046014f);  // 10000^(-j/64)
  float arg = nrm * 6.283185307179586f * freq;
  float pe = (i & 1) ? cosf(arg) : sinf(arg);
  float val = dec_f(buf[(size_t)lrow * CDIM + c]) + pe;
  buf[(size_t)lrow * CDIM + c] = __float_as_uint(val);
}

// flash-style batch-masked cross attention.
// grid (ceil(Mp/8), H); 8 waves/block, wave w handles query p = bx*8+w, head by.
__global__ __launch_bounds__(512) void attn_kernel(
    const float* __restrict__ q, const float* __restrict__ k, const float* __restrict__ v,
    const int* __restrict__ pc, int Mp, int Me,
    const int* __restrict__ eb, float* __restrict__ o) {
  __shared__ float kt[64][52];  // pad 52: stride mod 32 != 16, float4-aligned
  __shared__ float vt[64][52];
  __shared__ int wlo[8], whi[8];
  int h = blockIdx.y;
  int w = threadIdx.x >> 6;
  int lane = threadIdx.x & 63;
  int p = blockIdx.x * 8 + w;
  bool active = p < Mp;
  int pcl = active ? p : (Mp - 1);
  int b = pc[4 * pcl];
  int lo = eb[b], hi = eb[b + 1];
  if (lane == 0) { wlo[w] = active ? lo : 0x7fffffff; whi[w] = active ? hi : 0; }
  __syncthreads();
  int blo = 0x7fffffff, bhi = 0;
  #pragma unroll
  for (int i = 0; i < 8; ++i) { blo = min(blo, wlo[i]); bhi = max(bhi, whi[i]); }

  float qr[HD];
  const float* qp = q + (size_t)pcl * CDIM + h * HD;
  #pragma unroll
  for (int c = 0; c < HD; c += 4) {
    float4 t4 = *reinterpret_cast<const float4*>(qp + c);
    qr[c] = t4.x; qr[c + 1] = t4.y; qr[c + 2] = t4.z; qr[c + 3] = t4.w;
  }
  float m = -3.0e38f, l = 0.f;
  float acc[HD];
  #pragma unroll
  for (int c = 0; c < HD; ++c) acc[c] = 0.f;
  const float scale = 0.14433756729740643f;  // 1/sqrt(48)

  for (int et = blo; et < bhi; et += 64) {
    __syncthreads();
    for (int idx = threadIdx.x; idx < 64 * HD; idx += 512) {
      int r = idx / HD, cc = idx - r * HD;
      int e = et + r;
      if (e < bhi) {
        kt[r][cc] = k[(size_t)e * CDIM + h * HD + cc];
        vt[r][cc] = v[(size_t)e * CDIM + h * HD + cc];
      }
    }
    __syncthreads();
    int e = et + lane;
    if (active && e >= lo && e < hi) {
      float s = 0.f;
      #pragma unroll
      for (int c = 0; c < HD; c += 4) {
        float4 k4 = *reinterpret_cast<const float4*>(&kt[lane][c]);
        s += k4.x * qr[c] + k4.y * qr[c + 1] + k4.z * qr[c + 2] + k4.w * qr[c + 3];
      }
      s *= scale;
      if (s > m) {  // new max: rescale old state (rare amortized)
        float corr = __expf(m - s);
        l = l * corr + 1.0f;
        #pragma unroll
        for (int c = 0; c < HD; c += 4) {
          float4 v4 = *reinterpret_cast<const float4*>(&vt[lane][c]);
          acc[c] = acc[c] * corr + v4.x;
          acc[c + 1] = acc[c + 1] * corr + v4.y;
          acc[c + 2] = acc[c + 2] * corr + v4.z;
          acc[c + 3] = acc[c + 3] * corr + v4.w;
        }
        m = s;
      } else {
        float wgt = __expf(s - m);
        l += wgt;
        #pragma unroll
        for (int c = 0; c < HD; c += 4) {
          float4 v4 = *reinterpret_cast<const float4*>(&vt[lane][c]);
          acc[c] += wgt * v4.x;
          acc[c + 1] += wgt * v4.y;
          acc[c + 2] += wgt * v4.z;
          acc[c + 3] += wgt * v4.w;
        }
      }
    }
  }

  // butterfly merge of (m, l, acc[48]) across the 64 lanes
  #pragma unroll
  for (int off = 1; off < 64; off <<= 1) {
    float m2 = __shfl_xor(m, off);
    float l2 = __shfl_xor(l, off);
    float mn = fmaxf(m, m2);
    float c1 = __expf(m - mn), c2 = __expf(m2 - mn);
    l = l * c1 + l2 * c2;
    #pragma unroll
    for (int c = 0; c < HD; ++c) {
      float a2 = __shfl_xor(acc[c], off);
      acc[c] = acc[c] * c1 + a2 * c2;
    }
    m = mn;
  }
  if (active && lane == 0) {
    float inv_l = 1.0f / l;
    float* op = o + (size_t)p * CDIM + h * HD;
    #pragma unroll
    for (int c = 0; c < HD; c += 4) {
      float4 r4 = make_float4(acc[c] * inv_l, acc[c + 1] * inv_l,
                              acc[c + 2] * inv_l, acc[c + 3] * inv_l);
      *reinterpret_cast<float4*>(op + c) = r4;
    }
  }
}

// logits[n,o] = sum_k sum_c (feats[nbr[n,k]] + o2[pool_inv[nbr[n,k]]])[c] * Wc[k,c,o] + bc[o]
__global__ __launch_bounds__(256) void conv_kernel(
    const float* __restrict__ feats, const float* __restrict__ o2,
    const int* __restrict__ pool_inv, const int* __restrict__ nbr,
    const float* __restrict__ Wc, const float* __restrict__ bc,
    float* __restrict__ out, int N) {
  __shared__ float rows[8][CDIM];
  int n0 = blockIdx.x * 8;
  int t = threadIdx.x;
  int nl = t >> 5;
  int oo = t & 31;
  float acc = bc[oo];
  for (int kk = 0; kk < 27; ++kk) {
    __syncthreads();
    for (int idx = t; idx < 8 * CDIM; idx += 256) {
      int rn = idx / CDIM, cc = idx - rn * CDIM;
      int n = n0 + rn;
      float val = 0.f;
      if (n < N) {
        int j = nbr[(size_t)n * 27 + kk];
        if (j >= 0) val = feats[(size_t)j * CDIM + cc] + o2[(size_t)pool_inv[j] * CDIM + cc];
      }
      rows[rn][cc] = val;
    }
    __syncthreads();
    const float* wk = Wc + (size_t)kk * CDIM * OUTD;
    #pragma unroll 4
    for (int cc = 0; cc < CDIM; ++cc) acc += rows[nl][cc] * wk[cc * OUTD + oo];
  }
  int n = n0 + nl;
  if (n < N) out[(size_t)n * OUTD + oo] = acc;
}

extern "C" void kernel_launch(void* const* d_in, const int* in_sizes, int n_in,
                              void* d_out, int out_size, void* d_ws, size_t ws_size,
                              hipStream_t stream) {
  const float* feats  = (const float*)d_in[0];
  const float* W_pool = (const float*)d_in[1];
  const float* b_pool = (const float*)d_in[2];
  const float* W_emb  = (const float*)d_in[3];
  const float* b_emb  = (const float*)d_in[4];
  const float* Wq = (const float*)d_in[5];  const float* bq = (const float*)d_in[6];
  const float* Wk = (const float*)d_in[7];  const float* bk = (const float*)d_in[8];
  const float* Wv = (const float*)d_in[9];  const float* bv = (const float*)d_in[10];
  const float* Wo = (const float*)d_in[11]; const float* bo = (const float*)d_in[12];
  const float* Wc = (const float*)d_in[13]; const float* bc = (const float*)d_in[14];
  const int* pool_inv    = (const int*)d_in[15];
  const int* pool_coords = (const int*)d_in[16];
  const int* emb_coords  = (const int*)d_in[18];
  const int* nbr         = (const int*)d_in[19];
  const int* bsz         = (const int*)d_in[20];
  int N  = in_sizes[0] / CDIM;
  int Mp = in_sizes[16] / 4;
  int Me = in_sizes[18] / 4;

  char* wsb = (char*)d_ws;
  size_t off = 0;
  auto alloc = [&](size_t elems) { void* p = wsb + off; off += elems * 4; return p; };
  unsigned* pool_buf = (unsigned*)alloc((size_t)Mp * CDIM);
  unsigned* emb_buf  = (unsigned*)alloc((size_t)Me * CDIM);
  float* qb = (float*)alloc((size_t)Mp * CDIM);
  float* kb = (float*)alloc((size_t)Me * CDIM);
  float* vb = (float*)alloc((size_t)Me * CDIM);
  float* ob = (float*)alloc((size_t)Mp * CDIM);
  int* smin = (int*)alloc(MAXB * 3);
  int* smax = (int*)alloc(MAXB * 3);
  int* eb   = (int*)alloc(MAXB + 1);
  float* o2 = qb;  // q dead after attention; reuse for o@Wo

  hipMemsetAsync(pool_buf, 0, (size_t)Mp * CDIM * 4, stream);  // enc(-inf)-ish floor
  hipMemsetAsync(emb_buf, 0, (size_t)Me * CDIM * 4, stream);
  init_small_kernel<<<1, 64, 0, stream>>>(smin, smax, eb);
  {
    int tot = Me + Mp;
    minmax_kernel<<<(tot + 255) / 256, 256, 0, stream>>>(emb_coords, Me, pool_coords, Mp, smin, smax);
    ebound_kernel<<<(Me + 255) / 256, 256, 0, stream>>>(emb_coords, Me, bsz, eb);
  }
  dim3 gN((N + 63) / 64, CDIM / 64);
  gemm_kernel<true><<<gN, 256, 0, stream>>>(feats, N, W_pool, b_pool, nullptr, pool_buf, pool_inv);
  gemm_kernel<true><<<gN, 256, 0, stream>>>(feats, N, W_emb, b_emb, nullptr, emb_buf, (const int*)d_in[17]);
  {
    int tot = (Mp + Me) * CDIM;
    pe_kernel<<<(tot + 255) / 256, 256, 0, stream>>>(pool_buf, emb_buf, pool_coords, Mp,
                                                     emb_coords, Me, smin, smax);
  }
  dim3 gMp((Mp + 63) / 64, CDIM / 64), gMe((Me + 63) / 64, CDIM / 64);
  gemm_kernel<false><<<gMp, 256, 0, stream>>>((const float*)pool_buf, Mp, Wq, bq, qb, nullptr, nullptr);
  gemm_kernel<false><<<gMe, 256, 0, stream>>>((const float*)emb_buf, Me, Wk, bk, kb, nullptr, nullptr);
  gemm_kernel<false><<<gMe, 256, 0, stream>>>((const float*)emb_buf, Me, Wv, bv, vb, nullptr, nullptr);

  attn_kernel<<<dim3((Mp + 7) / 8, NHEAD), 512, 0, stream>>>(qb, kb, vb, pool_coords, Mp, Me, eb, ob);

  gemm_kernel<false><<<gMp, 256, 0, stream>>>(ob, Mp, Wo, bo, o2, nullptr, nullptr);

  conv_kernel<<<(N + 7) / 8, 256, 0, stream>>>(feats, o2, pool_inv, nbr, Wc, bc, (float*)d_out, N);
}

// Round 2
// 499.830 us; speedup vs baseline: 3.5842x; 3.5842x over previous
//
#include <hip/hip_runtime.h>
#include <hip/hip_bf16.h>
#include <math.h>

#define CDIM 384
#define NHEAD 8
#define HD 48
#define OUTD 32
#define MAXB 16

typedef __bf16 bf16x8 __attribute__((ext_vector_type(8)));
typedef float f32x4 __attribute__((ext_vector_type(4)));

__device__ __forceinline__ f32x4 mfma16(bf16x8 a, bf16x8 b, f32x4 c) {
  return __builtin_amdgcn_mfma_f32_16x16x32_bf16(a, b, c, 0, 0, 0);
}

// ---- order-preserving float<->uint encoding for atomicMax-based segment max ----
__device__ __forceinline__ unsigned enc_f(float f) {
  unsigned u = __float_as_uint(f);
  return (u & 0x80000000u) ? ~u : (u | 0x80000000u);
}
__device__ __forceinline__ float dec_f(unsigned u) {
  unsigned v = (u & 0x80000000u) ? (u ^ 0x80000000u) : ~u;
  return __uint_as_float(v);
}

__global__ void init_small_kernel(int* smin, int* smax, int* eb) {
  int t = threadIdx.x;
  if (t < MAXB * 3) { smin[t] = 0x7fffffff; smax[t] = (int)0x80000000; }
  if (t <= MAXB) eb[t] = 0;
}

__global__ void minmax_kernel(const int* __restrict__ ec, int Me,
                              const int* __restrict__ pc, int Mp,
                              int* smin, int* smax) {
  __shared__ int lmin[MAXB * 3], lmax[MAXB * 3];
  int t = threadIdx.x;
  if (t < MAXB * 3) { lmin[t] = 0x7fffffff; lmax[t] = (int)0x80000000; }
  __syncthreads();
  int i = blockIdx.x * blockDim.x + t;
  int tot = Me + Mp;
  if (i < tot) {
    const int* r = (i < Me) ? (ec + 4 * i) : (pc + 4 * (i - Me));
    int b = r[0];
    #pragma unroll
    for (int d = 0; d < 3; ++d) {
      atomicMin(&lmin[b * 3 + d], r[1 + d]);
      atomicMax(&lmax[b * 3 + d], r[1 + d]);
    }
  }
  __syncthreads();
  if (t < MAXB * 3) {
    if (lmin[t] != 0x7fffffff) atomicMin(&smin[t], lmin[t]);
    if (lmax[t] != (int)0x80000000) atomicMax(&smax[t], lmax[t]);
  }
}

__global__ void ebound_kernel(const int* __restrict__ ec, int Me,
                              const int* __restrict__ bsz, int* eb) {
  int e = blockIdx.x * blockDim.x + threadIdx.x;
  if (e == 0) { eb[0] = 0; eb[bsz[0]] = Me; }
  if (e > 0 && e < Me) {
    int b0 = ec[4 * (e - 1)], b1 = ec[4 * e];
    for (int bb = b0 + 1; bb <= b1; ++bb) eb[bb] = e;
  }
}

// C[M x 384] = A[M x 384] @ W[384 x 384] + bias  (fp32)
template <bool SCATTER>
__global__ __launch_bounds__(256) void gemm_kernel(
    const float* __restrict__ A, int M,
    const float* __restrict__ W, const float* __restrict__ bias,
    float* __restrict__ dstF, unsigned* __restrict__ dstU,
    const int* __restrict__ inv) {
  __shared__ float As[16][68];
  __shared__ float Bs[16][64];
  int r0 = blockIdx.x * 64;
  int n0 = blockIdx.y * 64;
  int t = threadIdx.x;
  int tx = t & 15, ty = t >> 4;
  float acc[4][4] = {};
  for (int k0 = 0; k0 < CDIM; k0 += 16) {
    {
      int row = t >> 2, kg = (t & 3) * 4;
      float4 a = make_float4(0.f, 0.f, 0.f, 0.f);
      int gr = r0 + row;
      if (gr < M) a = *reinterpret_cast<const float4*>(A + (size_t)gr * CDIM + k0 + kg);
      As[kg + 0][row] = a.x; As[kg + 1][row] = a.y;
      As[kg + 2][row] = a.z; As[kg + 3][row] = a.w;
    }
    {
      int kk = t >> 4, cg = (t & 15) * 4;
      float4 b = *reinterpret_cast<const float4*>(W + (size_t)(k0 + kk) * CDIM + n0 + cg);
      *reinterpret_cast<float4*>(&Bs[kk][cg]) = b;
    }
    __syncthreads();
    #pragma unroll
    for (int kk = 0; kk < 16; ++kk) {
      float4 av = *reinterpret_cast<const float4*>(&As[kk][ty * 4]);
      float4 bv = *reinterpret_cast<const float4*>(&Bs[kk][tx * 4]);
      float a[4] = {av.x, av.y, av.z, av.w};
      float b[4] = {bv.x, bv.y, bv.z, bv.w};
      #pragma unroll
      for (int i = 0; i < 4; ++i)
        #pragma unroll
        for (int j = 0; j < 4; ++j) acc[i][j] += a[i] * b[j];
    }
    __syncthreads();
  }
  #pragma unroll
  for (int i = 0; i < 4; ++i) {
    int gr = r0 + ty * 4 + i;
    if (gr >= M) break;
    int seg = SCATTER ? inv[gr] : 0;
    #pragma unroll
    for (int j = 0; j < 4; ++j) {
      int gc = n0 + tx * 4 + j;
      float v = acc[i][j] + bias[gc];
      if (SCATTER) atomicMax(&dstU[(size_t)seg * CDIM + gc], enc_f(v));
      else dstF[(size_t)gr * CDIM + gc] = v;
    }
  }
}

// decode encoded segment-max in place, add sine positional encoding
__global__ void pe_kernel(unsigned* __restrict__ pool_buf, unsigned* __restrict__ emb_buf,
                          const int* __restrict__ pc, int Mp,
                          const int* __restrict__ ec, int Me,
                          const int* __restrict__ smin, const int* __restrict__ smax) {
  int gid = blockIdx.x * blockDim.x + threadIdx.x;
  int total = (Mp + Me) * CDIM;
  if (gid >= total) return;
  int row = gid / CDIM, c = gid - row * CDIM;
  const int* coords;
  unsigned* buf;
  int lrow;
  if (row < Me) { lrow = row; coords = ec + 4 * row; buf = emb_buf; }
  else { lrow = row - Me; coords = pc + 4 * lrow; buf = pool_buf; }
  int b = coords[0];
  int dim = c >> 7;
  int i = c & 127;
  int j = i >> 1;
  float x = (float)coords[1 + dim];
  float mn = (float)smin[b * 3 + dim];
  float mx = (float)smax[b * 3 + dim];
  float nrm = (x - mn) / (mx - mn + 1e-6f);
  float freq = exp2f(-(float)j * 0.20762050593046014f);
  float arg = nrm * 6.283185307179586f * freq;
  float pe = (i & 1) ? cosf(arg) : sinf(arg);
  float val = dec_f(buf[(size_t)lrow * CDIM + c]) + pe;
  buf[(size_t)lrow * CDIM + c] = __float_as_uint(val);
}

// q/k fp32 -> bf16, head-dim padded 48->64, scale folded into q
__global__ __launch_bounds__(512) void convert_qk_kernel(
    const float* __restrict__ qf, const float* __restrict__ kf,
    __hip_bfloat16* __restrict__ q16, __hip_bfloat16* __restrict__ k16,
    int Mp, int Me) {
  int r = blockIdx.x, t = threadIdx.x;
  int h = t >> 6, d = t & 63;
  const float scale = 0.14433756729740643f;  // 1/sqrt(48)
  if (r < Mp) {
    float v = (d < HD) ? qf[(size_t)r * CDIM + h * HD + d] * scale : 0.f;
    q16[(size_t)r * 512 + t] = __float2bfloat16(v);
  }
  if (r < Me) {
    float v = (d < HD) ? kf[(size_t)r * CDIM + h * HD + d] : 0.f;
    k16[(size_t)r * 512 + t] = __float2bfloat16(v);
  }
}

// v fp32 [Me][384] -> vt bf16 [8 heads][64 rows][Mepad]; row 48 = ones (row-sum
// trick), rows 49..63 = 0; cols >= Me zero-padded. LDS transpose for coalescing.
__global__ __launch_bounds__(256) void convert_v_kernel(
    const float* __restrict__ vf, __hip_bfloat16* __restrict__ vt,
    int Me, int Mepad) {
  __shared__ __hip_bfloat16 tile[64][386];  // 386: odd half-stride -> conflict-free col reads
  int e0 = blockIdx.x * 64;
  int t = threadIdx.x;
  for (int i = 0; i < 24; ++i) {
    int v = t + i * 256;               // 64 rows x 96 float4
    int e = v / 96, c4 = v - e * 96;
    float4 x = make_float4(0.f, 0.f, 0.f, 0.f);
    if (e0 + e < Me) x = *reinterpret_cast<const float4*>(vf + (size_t)(e0 + e) * CDIM + c4 * 4);
    tile[e][c4 * 4 + 0] = __float2bfloat16(x.x);
    tile[e][c4 * 4 + 1] = __float2bfloat16(x.y);
    tile[e][c4 * 4 + 2] = __float2bfloat16(x.z);
    tile[e][c4 * 4 + 3] = __float2bfloat16(x.w);
  }
  __syncthreads();
  for (int i = 0; i < 128; ++i) {
    int v = t + i * 256;               // 512 rows x 64 cols
    int row = v >> 6, e = v & 63;
    int hh = row >> 6, dr = row & 63;
    __hip_bfloat16 val;
    if (dr < HD) val = tile[e][hh * HD + dr];
    else val = __float2bfloat16((dr == HD) ? 1.0f : 0.0f);
    vt[(size_t)row * Mepad + e0 + e] = val;
  }
}

// MFMA flash attention: wave = 16 queries x one head; e-tiles of 32.
// No max-subtraction (scores bounded); row-sum via ones-column of vt (dt=3).
__global__ __launch_bounds__(256) void attn_mfma_kernel(
    const __hip_bfloat16* __restrict__ qb, const __hip_bfloat16* __restrict__ kb,
    const __hip_bfloat16* __restrict__ vt, int Mepad,
    const int* __restrict__ pc, const int* __restrict__ eb,
    int Mp, int Me, float* __restrict__ ob) {
  __shared__ __align__(16) __hip_bfloat16 pl[4][16][40];
  int h = blockIdx.y;
  int wv = threadIdx.x >> 6, lane = threadIdx.x & 63;
  int lq = lane & 15, lg = lane >> 4;
  int q0 = blockIdx.x * 64 + wv * 16;

  int lo[4], hi[4];
  #pragma unroll
  for (int r = 0; r < 4; ++r) {
    int q = q0 + lg * 4 + r;
    if (q < Mp) { int b = pc[4 * q]; lo[r] = eb[b]; hi[r] = eb[b + 1]; }
    else { lo[r] = 0x7fffffff; hi[r] = 0; }
  }
  int blo = min(min(lo[0], lo[1]), min(lo[2], lo[3]));
  int bhi = max(max(hi[0], hi[1]), max(hi[2], hi[3]));
  #pragma unroll
  for (int off = 1; off < 64; off <<= 1) {
    blo = min(blo, __shfl_xor(blo, off));
    bhi = max(bhi, __shfl_xor(bhi, off));
  }

  int qrow = min(q0 + lq, Mp - 1);
  const __hip_bfloat16* qp = qb + (size_t)qrow * 512 + h * 64 + lg * 8;
  bf16x8 aq0 = *reinterpret_cast<const bf16x8*>(qp);
  bf16x8 aq1 = *reinterpret_cast<const bf16x8*>(qp + 32);

  f32x4 zero = {0.f, 0.f, 0.f, 0.f};
  f32x4 oacc[4];
  oacc[0] = zero; oacc[1] = zero; oacc[2] = zero; oacc[3] = zero;

  for (int e0 = (blo & ~31); e0 < bhi; e0 += 32) {
    f32x4 sf[2];
    #pragma unroll
    for (int s = 0; s < 2; ++s) {
      int er = min(e0 + s * 16 + lq, Me - 1);
      const __hip_bfloat16* kp = kb + (size_t)er * 512 + h * 64 + lg * 8;
      bf16x8 bk0 = *reinterpret_cast<const bf16x8*>(kp);
      bf16x8 bk1 = *reinterpret_cast<const bf16x8*>(kp + 32);
      f32x4 z = zero;
      z = mfma16(aq0, bk0, z);
      z = mfma16(aq1, bk1, z);
      sf[s] = z;
    }
    int ea = e0 + lq, eb2 = e0 + 16 + lq;
    #pragma unroll
    for (int r = 0; r < 4; ++r) {
      bool m0 = (ea >= lo[r]) && (ea < hi[r]);
      bool m1 = (eb2 >= lo[r]) && (eb2 < hi[r]);
      float p0 = m0 ? __expf(sf[0][r]) : 0.f;
      float p1 = m1 ? __expf(sf[1][r]) : 0.f;
      pl[wv][lg * 4 + r][lq] = __float2bfloat16(p0);
      pl[wv][lg * 4 + r][16 + lq] = __float2bfloat16(p1);
    }
    asm volatile("s_waitcnt lgkmcnt(0)" ::: "memory");
    bf16x8 ap = *reinterpret_cast<const bf16x8*>(&pl[wv][lq][lg * 8]);
    #pragma unroll
    for (int dt = 0; dt < 4; ++dt) {
      const __hip_bfloat16* vp = vt + (size_t)(h * 64 + dt * 16 + lq) * Mepad + e0 + lg * 8;
      bf16x8 bv = *reinterpret_cast<const bf16x8*>(vp);
      oacc[dt] = mfma16(ap, bv, oacc[dt]);
    }
  }

  #pragma unroll
  for (int r = 0; r < 4; ++r) {
    float l = __shfl(oacc[3][r], (lane & 48));  // lane lq==0 of this lg group holds row-sum
    int q = q0 + lg * 4 + r;
    if (q < Mp && l > 0.f) {
      float inv = 1.0f / l;
      float* op = ob + (size_t)q * CDIM + h * HD;
      op[lq]      = oacc[0][r] * inv;
      op[16 + lq] = oacc[1][r] * inv;
      op[32 + lq] = oacc[2][r] * inv;
    }
  }
}

__global__ void newf_kernel(const float* __restrict__ feats, const float* __restrict__ o2,
                            const int* __restrict__ pinv, float* __restrict__ nf, int N) {
  int v = blockIdx.x * 256 + threadIdx.x;
  if (v >= N * (CDIM / 4)) return;
  int n = v / (CDIM / 4), c4 = (v - n * (CDIM / 4)) * 4;
  float4 a = *reinterpret_cast<const float4*>(feats + (size_t)n * CDIM + c4);
  float4 b = *reinterpret_cast<const float4*>(o2 + (size_t)pinv[n] * CDIM + c4);
  float4 r = make_float4(a.x + b.x, a.y + b.y, a.z + b.z, a.w + b.w);
  *reinterpret_cast<float4*>(nf + (size_t)n * CDIM + c4) = r;
}

// conv as tiled GEMM with K split into 9 groups of 3 taps; deterministic partials.
// tile 128 rows x 32 cols, 128 threads, thread = 4 rows x 8 cols.
__global__ __launch_bounds__(128) void conv_part_kernel(
    const float* __restrict__ nf, const int* __restrict__ nbr,
    const float* __restrict__ Wc, float* __restrict__ outp, int N) {
  __shared__ float As[64][132];
  __shared__ float Bs[64][36];
  int n0 = blockIdx.x * 128;
  int kg = blockIdx.y;
  int t = threadIdx.x;
  int rg = t >> 2, cg = t & 3;  // rows rg*4.., cols cg*8..
  float acc[4][8] = {};
  for (int kk = kg * 3; kk < kg * 3 + 3; ++kk) {
    int j = nbr[(size_t)(n0 + t) * 27 + kk];
    for (int c0 = 0; c0 < CDIM; c0 += 64) {
      // stage A: 128 rows x 64 cols (transposed: As[k][row])
      {
        const float* src = (j >= 0) ? (nf + (size_t)j * CDIM + c0) : nullptr;
        #pragma unroll
        for (int i4 = 0; i4 < 16; ++i4) {
          float4 x = make_float4(0.f, 0.f, 0.f, 0.f);
          if (src) x = *reinterpret_cast<const float4*>(src + i4 * 4);
          As[i4 * 4 + 0][t] = x.x; As[i4 * 4 + 1][t] = x.y;
          As[i4 * 4 + 2][t] = x.z; As[i4 * 4 + 3][t] = x.w;
        }
      }
      // stage B: Wc[kk][c0+k][0..32] -> Bs[k][...]
      {
        int k = t >> 1, half = t & 1;
        const float* src = Wc + (size_t)kk * CDIM * OUTD + (size_t)(c0 + k) * OUTD + half * 16;
        #pragma unroll
        for (int i = 0; i < 4; ++i) {
          float4 x = *reinterpret_cast<const float4*>(src + i * 4);
          *reinterpret_cast<float4*>(&Bs[k][half * 16 + i * 4]) = x;
        }
      }
      __syncthreads();
      #pragma unroll 4
      for (int k = 0; k < 64; ++k) {
        float4 a4 = *reinterpret_cast<const float4*>(&As[k][rg * 4]);
        float4 b40 = *reinterpret_cast<const float4*>(&Bs[k][cg * 8]);
        float4 b41 = *reinterpret_cast<const float4*>(&Bs[k][cg * 8 + 4]);
        float av[4] = {a4.x, a4.y, a4.z, a4.w};
        float bv[8] = {b40.x, b40.y, b40.z, b40.w, b41.x, b41.y, b41.z, b41.w};
        #pragma unroll
        for (int i = 0; i < 4; ++i)
          #pragma unroll
          for (int jj = 0; jj < 8; ++jj) acc[i][jj] += av[i] * bv[jj];
      }
      __syncthreads();
    }
  }
  #pragma unroll
  for (int i = 0; i < 4; ++i) {
    float* dst = outp + ((size_t)kg * N + n0 + rg * 4 + i) * OUTD + cg * 8;
    #pragma unroll
    for (int jj = 0; jj < 8; ++jj) dst[jj] = acc[i][jj];
  }
}

__global__ void conv_reduce_kernel(const float* __restrict__ outp,
                                   const float* __restrict__ bc,
                                   float* __restrict__ out, int N) {
  int v = blockIdx.x * 256 + threadIdx.x;
  if (v >= N * OUTD) return;
  int oo = v & (OUTD - 1);
  float s = bc[oo];
  #pragma unroll
  for (int kg = 0; kg < 9; ++kg) s += outp[(size_t)kg * N * OUTD + v];
  out[v] = s;
}

extern "C" void kernel_launch(void* const* d_in, const int* in_sizes, int n_in,
                              void* d_out, int out_size, void* d_ws, size_t ws_size,
                              hipStream_t stream) {
  const float* feats  = (const float*)d_in[0];
  const float* W_pool = (const float*)d_in[1];
  const float* b_pool = (const float*)d_in[2];
  const float* W_emb  = (const float*)d_in[3];
  const float* b_emb  = (const float*)d_in[4];
  const float* Wq = (const float*)d_in[5];  const float* bq = (const float*)d_in[6];
  const float* Wk = (const float*)d_in[7];  const float* bk = (const float*)d_in[8];
  const float* Wv = (const float*)d_in[9];  const float* bv = (const float*)d_in[10];
  const float* Wo = (const float*)d_in[11]; const float* bo = (const float*)d_in[12];
  const float* Wc = (const float*)d_in[13]; const float* bc = (const float*)d_in[14];
  const int* pool_inv    = (const int*)d_in[15];
  const int* pool_coords = (const int*)d_in[16];
  const int* emb_inv     = (const int*)d_in[17];
  const int* emb_coords  = (const int*)d_in[18];
  const int* nbr         = (const int*)d_in[19];
  const int* bsz         = (const int*)d_in[20];
  int N  = in_sizes[0] / CDIM;
  int Mp = in_sizes[16] / 4;
  int Me = in_sizes[18] / 4;
  int Mepad = ((Me >> 6) + 2) << 6;  // >= Me+64, 64-aligned

  char* wsb = (char*)d_ws;
  size_t off = 0;
  auto alloc = [&](size_t elems) { void* p = wsb + off; off += elems * 4; return p; };
  // Region reuse plan (sequential lifetimes):
  //  bufA: pool_buf(enc fp32) -> qb16(bf16)
  //  bufB: emb_buf(enc fp32) -> kb16(bf16) -> conv partials
  //  qreg: q fp32 -> vt bf16 -> o2 fp32
  //  obN : attn out ob (Mp rows) -> new_f (N rows)
  unsigned* bufA = (unsigned*)alloc((size_t)Mp * CDIM);
  unsigned* bufB = (unsigned*)alloc((size_t)Me * CDIM);
  float* qreg = (float*)alloc((size_t)Mp * CDIM);
  float* kb   = (float*)alloc((size_t)Me * CDIM);
  float* vb   = (float*)alloc((size_t)Me * CDIM);
  float* obN  = (float*)alloc((size_t)N * CDIM);
  int* smin = (int*)alloc(MAXB * 3);
  int* smax = (int*)alloc(MAXB * 3);
  int* eb   = (int*)alloc(MAXB + 1);

  __hip_bfloat16* qb16 = (__hip_bfloat16*)bufA;
  __hip_bfloat16* kb16 = (__hip_bfloat16*)bufB;
  __hip_bfloat16* vt   = (__hip_bfloat16*)qreg;
  float* o2   = qreg;
  float* newf = obN;
  float* outp = (float*)bufB;

  hipMemsetAsync(bufA, 0, (size_t)Mp * CDIM * 4, stream);
  hipMemsetAsync(bufB, 0, (size_t)Me * CDIM * 4, stream);
  init_small_kernel<<<1, 64, 0, stream>>>(smin, smax, eb);
  {
    int tot = Me + Mp;
    minmax_kernel<<<(tot + 255) / 256, 256, 0, stream>>>(emb_coords, Me, pool_coords, Mp, smin, smax);
    ebound_kernel<<<(Me + 255) / 256, 256, 0, stream>>>(emb_coords, Me, bsz, eb);
  }
  dim3 gN((N + 63) / 64, CDIM / 64);
  gemm_kernel<true><<<gN, 256, 0, stream>>>(feats, N, W_pool, b_pool, nullptr, bufA, pool_inv);
  gemm_kernel<true><<<gN, 256, 0, stream>>>(feats, N, W_emb, b_emb, nullptr, bufB, emb_inv);
  {
    int tot = (Mp + Me) * CDIM;
    pe_kernel<<<(tot + 255) / 256, 256, 0, stream>>>(bufA, bufB, pool_coords, Mp,
                                                     emb_coords, Me, smin, smax);
  }
  dim3 gMp((Mp + 63) / 64, CDIM / 64), gMe((Me + 63) / 64, CDIM / 64);
  gemm_kernel<false><<<gMp, 256, 0, stream>>>((const float*)bufA, Mp, Wq, bq, qreg, nullptr, nullptr);
  gemm_kernel<false><<<gMe, 256, 0, stream>>>((const float*)bufB, Me, Wk, bk, kb, nullptr, nullptr);
  gemm_kernel<false><<<gMe, 256, 0, stream>>>((const float*)bufB, Me, Wv, bv, vb, nullptr, nullptr);

  int gmax = max(Mp, Me);
  convert_qk_kernel<<<gmax, 512, 0, stream>>>(qreg, kb, qb16, kb16, Mp, Me);
  convert_v_kernel<<<Mepad / 64, 256, 0, stream>>>(vb, vt, Me, Mepad);

  attn_mfma_kernel<<<dim3((Mp + 63) / 64, NHEAD), 256, 0, stream>>>(
      qb16, kb16, vt, Mepad, pool_coords, eb, Mp, Me, obN);

  gemm_kernel<false><<<gMp, 256, 0, stream>>>(obN, Mp, Wo, bo, o2, nullptr, nullptr);

  newf_kernel<<<(N * (CDIM / 4) + 255) / 256, 256, 0, stream>>>(feats, o2, pool_inv, newf, N);

  conv_part_kernel<<<dim3(N / 128, 9), 128, 0, stream>>>(newf, nbr, Wc, outp, N);
  conv_reduce_kernel<<<(N * OUTD + 255) / 256, 256, 0, stream>>>(outp, bc, (float*)d_out, N);
}

// Round 4
// 254.293 us; speedup vs baseline: 7.0450x; 1.9656x over previous
//
#include <hip/hip_runtime.h>
#include <hip/hip_bf16.h>
#include <math.h>

#define CDIM 384
#define NHEAD 8
#define HD 48
#define OUTD 32
#define MAXB 16
#define CONVK 10368  // 27*384

typedef __bf16 bf16x8 __attribute__((ext_vector_type(8)));
typedef float f32x4 __attribute__((ext_vector_type(4)));

__device__ __forceinline__ f32x4 mfma16(bf16x8 a, bf16x8 b, f32x4 c) {
  return __builtin_amdgcn_mfma_f32_16x16x32_bf16(a, b, c, 0, 0, 0);
}
__device__ __forceinline__ bf16x8 zero8() {
  bf16x8 z = {(__bf16)0.f, (__bf16)0.f, (__bf16)0.f, (__bf16)0.f,
              (__bf16)0.f, (__bf16)0.f, (__bf16)0.f, (__bf16)0.f};
  return z;
}

// ---- order-preserving float<->uint encoding for atomicMax segment max ----
__device__ __forceinline__ unsigned enc_f(float f) {
  unsigned u = __float_as_uint(f);
  return (u & 0x80000000u) ? ~u : (u | 0x80000000u);
}
__device__ __forceinline__ float dec_f(unsigned u) {
  unsigned v = (u & 0x80000000u) ? (u ^ 0x80000000u) : ~u;
  return __uint_as_float(v);
}

__global__ void init_small_kernel(int* smin, int* smax, int* eb) {
  int t = threadIdx.x;
  if (t < MAXB * 3) { smin[t] = 0x7fffffff; smax[t] = (int)0x80000000; }
  if (t <= MAXB) eb[t] = 0;
}

__global__ void minmax_kernel(const int* __restrict__ ec, int Me,
                              const int* __restrict__ pc, int Mp,
                              int* smin, int* smax) {
  __shared__ int lmin[MAXB * 3], lmax[MAXB * 3];
  int t = threadIdx.x;
  if (t < MAXB * 3) { lmin[t] = 0x7fffffff; lmax[t] = (int)0x80000000; }
  __syncthreads();
  int i = blockIdx.x * blockDim.x + t;
  int tot = Me + Mp;
  if (i < tot) {
    const int* r = (i < Me) ? (ec + 4 * i) : (pc + 4 * (i - Me));
    int b = r[0];
    #pragma unroll
    for (int d = 0; d < 3; ++d) {
      atomicMin(&lmin[b * 3 + d], r[1 + d]);
      atomicMax(&lmax[b * 3 + d], r[1 + d]);
    }
  }
  __syncthreads();
  if (t < MAXB * 3) {
    if (lmin[t] != 0x7fffffff) atomicMin(&smin[t], lmin[t]);
    if (lmax[t] != (int)0x80000000) atomicMax(&smax[t], lmax[t]);
  }
}

__global__ void ebound_kernel(const int* __restrict__ ec, int Me,
                              const int* __restrict__ bsz, int* eb) {
  int e = blockIdx.x * blockDim.x + threadIdx.x;
  if (e == 0) { eb[0] = 0; eb[bsz[0]] = Me; }
  if (e > 0 && e < Me) {
    int b0 = ec[4 * (e - 1)], b1 = ec[4 * e];
    for (int bb = b0 + 1; bb <= b1; ++bb) eb[bb] = e;
  }
}

// fp32 [K][Nc] -> bf16 [Nc][K] (weights; small, one-shot; reads hit L2)
__global__ void wtrans_kernel(const float* __restrict__ src, __hip_bfloat16* __restrict__ dst,
                              int K, int Nc) {
  int v = blockIdx.x * 256 + threadIdx.x;
  int k8c = K >> 3;
  if (v >= Nc * k8c) return;
  int n = v / k8c;
  int k8 = (v - n * k8c) * 8;
  __hip_bfloat16 tmp[8];
  #pragma unroll
  for (int u = 0; u < 8; ++u) tmp[u] = __float2bfloat16(src[(size_t)(k8 + u) * Nc + n]);
  *reinterpret_cast<bf16x8*>(dst + (size_t)n * K + k8) = *reinterpret_cast<const bf16x8*>(tmp);
}

__global__ void tobf16_kernel(const float* __restrict__ src, __hip_bfloat16* __restrict__ dst,
                              int total8) {
  int v = blockIdx.x * 256 + threadIdx.x;
  if (v >= total8) return;
  float4 a0 = *reinterpret_cast<const float4*>(src + (size_t)v * 8);
  float4 a1 = *reinterpret_cast<const float4*>(src + (size_t)v * 8 + 4);
  __hip_bfloat16 tmp[8] = {
    __float2bfloat16(a0.x), __float2bfloat16(a0.y), __float2bfloat16(a0.z), __float2bfloat16(a0.w),
    __float2bfloat16(a1.x), __float2bfloat16(a1.y), __float2bfloat16(a1.z), __float2bfloat16(a1.w)};
  *reinterpret_cast<bf16x8*>(dst + (size_t)v * 8) = *reinterpret_cast<const bf16x8*>(tmp);
}

// decode segment-max, add sine PE, emit bf16 activations
__global__ void pe_kernel(const unsigned* __restrict__ encP, const unsigned* __restrict__ encE,
                          __hip_bfloat16* __restrict__ pool16, __hip_bfloat16* __restrict__ emb16,
                          const int* __restrict__ pc, int Mp,
                          const int* __restrict__ ec, int Me,
                          const int* __restrict__ smin, const int* __restrict__ smax) {
  int gid = blockIdx.x * blockDim.x + threadIdx.x;
  int total = (Mp + Me) * CDIM;
  if (gid >= total) return;
  int row = gid / CDIM, c = gid - row * CDIM;
  const int* coords;
  const unsigned* src;
  __hip_bfloat16* dst;
  int lrow;
  if (row < Me) { lrow = row; coords = ec + 4 * row; src = encE; dst = emb16; }
  else { lrow = row - Me; coords = pc + 4 * lrow; src = encP; dst = pool16; }
  int b = coords[0];
  int dim = c >> 7;
  int i = c & 127;
  int j = i >> 1;
  float x = (float)coords[1 + dim];
  float mn = (float)smin[b * 3 + dim];
  float mx = (float)smax[b * 3 + dim];
  float nrm = (x - mn) / (mx - mn + 1e-6f);
  float freq = exp2f(-(float)j * 0.20762050593046014f);  // 10000^(-j/64)
  float arg = nrm * 6.283185307179586f * freq;
  float pe = (i & 1) ? cosf(arg) : sinf(arg);
  float val = dec_f(src[(size_t)lrow * CDIM + c]) + pe;
  dst[(size_t)lrow * CDIM + c] = __float2bfloat16(val);
}

__global__ void vones_kernel(__hip_bfloat16* __restrict__ vt, int Mepad) {
  int v = blockIdx.x * 256 + threadIdx.x;
  if (v >= NHEAD * Mepad) return;
  int h = v / Mepad, e = v - h * Mepad;
  vt[(size_t)(h * 64 + HD) * Mepad + e] = __float2bfloat16(1.0f);
}

// Unified bf16 MFMA GEMM: C[M x Ncols] = A[M x 384](bf16) @ Wt^T + bias.
// Wt is [Ncols][384] bf16 (pre-transposed). BM=128 BN=64 BK=64, 4 waves.
// EPI 0: dual scatter-max (cols<384 -> d0/inv0/bias0, else d1/inv1/bias1)
// EPI 1: fp32 += bias -> d0 [M][384]
// EPI 2: bf16 q-layout [M][512] (head-padded 48->64), * 1/sqrt(48)
//        NOTE: pad lanes d=48..63 must be pre-zeroed by the caller (memset).
// EPI 3: cols<384 -> k16 [M][512] (pads pre-zeroed); cols>=384 -> vt transposed
template <int EPI>
__global__ __launch_bounds__(256) void mgemm_kernel(
    const __hip_bfloat16* __restrict__ A, int M,
    const __hip_bfloat16* __restrict__ Wt,
    const float* __restrict__ bias0, const float* __restrict__ bias1,
    void* __restrict__ d0, void* __restrict__ d1,
    const int* __restrict__ inv0, const int* __restrict__ inv1,
    int Mepad) {
  __shared__ __align__(16) __hip_bfloat16 As[128][72];
  __shared__ __align__(16) __hip_bfloat16 Bs[64][72];
  const int m0 = blockIdx.x * 128;
  const int n0 = blockIdx.y * 64;
  const int t = threadIdx.x;
  const int lane = t & 63, w = t >> 6;
  const int wr = w >> 1, wc = w & 1;
  const int lq = lane & 15, lg = lane >> 4;

  f32x4 acc[4][2];
  #pragma unroll
  for (int i = 0; i < 4; ++i) {
    acc[i][0] = (f32x4){0.f, 0.f, 0.f, 0.f};
    acc[i][1] = (f32x4){0.f, 0.f, 0.f, 0.f};
  }
  const int arow = t >> 3;         // 0..31
  const int acol = (t & 7) * 8;    // 0..56

  for (int k0 = 0; k0 < CDIM; k0 += 64) {
    #pragma unroll
    for (int i = 0; i < 4; ++i) {
      int r = arow + i * 32;
      int gr = m0 + r;
      bf16x8 val = zero8();
      if (gr < M) val = *reinterpret_cast<const bf16x8*>(A + (size_t)gr * CDIM + k0 + acol);
      *reinterpret_cast<bf16x8*>(&As[r][acol]) = val;
    }
    #pragma unroll
    for (int i = 0; i < 2; ++i) {
      int r = arow + i * 32;
      bf16x8 val = *reinterpret_cast<const bf16x8*>(Wt + (size_t)(n0 + r) * CDIM + k0 + acol);
      *reinterpret_cast<bf16x8*>(&Bs[r][acol]) = val;
    }
    __syncthreads();
    #pragma unroll
    for (int ks = 0; ks < 2; ++ks) {
      bf16x8 af[4], bfv[2];
      #pragma unroll
      for (int fm = 0; fm < 4; ++fm)
        af[fm] = *reinterpret_cast<const bf16x8*>(&As[wr * 64 + fm * 16 + lq][ks * 32 + lg * 8]);
      #pragma unroll
      for (int fn = 0; fn < 2; ++fn)
        bfv[fn] = *reinterpret_cast<const bf16x8*>(&Bs[wc * 32 + fn * 16 + lq][ks * 32 + lg * 8]);
      #pragma unroll
      for (int fm = 0; fm < 4; ++fm)
        #pragma unroll
        for (int fn = 0; fn < 2; ++fn)
          acc[fm][fn] = mfma16(af[fm], bfv[fn], acc[fm][fn]);
    }
    __syncthreads();
  }

  // ---- epilogue ----
  const bool sec = (n0 >= CDIM);        // block-uniform (64 | 384)
  const int nb = n0 - (sec ? CDIM : 0) + wc * 32;
  const int nA = nb + lq, nB = nb + 16 + lq;   // the lane's two columns

  if (EPI == 0) {
    const float* bias = sec ? bias1 : bias0;
    unsigned* dst = (unsigned*)(sec ? d1 : d0);
    const int* inv = sec ? inv1 : inv0;
    float bA = bias[nA], bB = bias[nB];
    #pragma unroll
    for (int fm = 0; fm < 4; ++fm)
      #pragma unroll
      for (int j = 0; j < 4; ++j) {
        int r = m0 + wr * 64 + fm * 16 + lg * 4 + j;
        if (r < M) {
          int seg = inv[r];
          atomicMax(&dst[(size_t)seg * CDIM + nA], enc_f(acc[fm][0][j] + bA));
          atomicMax(&dst[(size_t)seg * CDIM + nB], enc_f(acc[fm][1][j] + bB));
        }
      }
  } else if (EPI == 1) {
    float bA = bias0[nA], bB = bias0[nB];
    float* dst = (float*)d0;
    #pragma unroll
    for (int fm = 0; fm < 4; ++fm)
      #pragma unroll
      for (int j = 0; j < 4; ++j) {
        int r = m0 + wr * 64 + fm * 16 + lg * 4 + j;
        if (r < M) {
          dst[(size_t)r * CDIM + nA] = acc[fm][0][j] + bA;
          dst[(size_t)r * CDIM + nB] = acc[fm][1][j] + bB;
        }
      }
  } else if (EPI == 2) {
    const float scale = 0.14433756729740643f;
    float bA = bias0[nA], bB = bias0[nB];
    int hA = nA / HD, dA = nA - hA * HD;
    int hB = nB / HD, dB = nB - hB * HD;
    __hip_bfloat16* dst = (__hip_bfloat16*)d0;
    #pragma unroll
    for (int fm = 0; fm < 4; ++fm)
      #pragma unroll
      for (int j = 0; j < 4; ++j) {
        int r = m0 + wr * 64 + fm * 16 + lg * 4 + j;
        if (r < M) {
          dst[(size_t)r * 512 + hA * 64 + dA] = __float2bfloat16((acc[fm][0][j] + bA) * scale);
          dst[(size_t)r * 512 + hB * 64 + dB] = __float2bfloat16((acc[fm][1][j] + bB) * scale);
        }
      }
  } else {  // EPI 3
    if (!sec) {
      float bA = bias0[nA], bB = bias0[nB];
      int hA = nA / HD, dA = nA - hA * HD;
      int hB = nB / HD, dB = nB - hB * HD;
      __hip_bfloat16* dst = (__hip_bfloat16*)d0;
      #pragma unroll
      for (int fm = 0; fm < 4; ++fm)
        #pragma unroll
        for (int j = 0; j < 4; ++j) {
          int r = m0 + wr * 64 + fm * 16 + lg * 4 + j;
          if (r < M) {
            dst[(size_t)r * 512 + hA * 64 + dA] = __float2bfloat16(acc[fm][0][j] + bA);
            dst[(size_t)r * 512 + hB * 64 + dB] = __float2bfloat16(acc[fm][1][j] + bB);
          }
        }
    } else {
      float bA = bias1[nA], bB = bias1[nB];
      int hA = nA / HD, dA = nA - hA * HD;
      int hB = nB / HD, dB = nB - hB * HD;
      __hip_bfloat16* dst = (__hip_bfloat16*)d1;
      #pragma unroll
      for (int fm = 0; fm < 4; ++fm)
        #pragma unroll
        for (int j = 0; j < 4; ++j) {
          int r = m0 + wr * 64 + fm * 16 + lg * 4 + j;
          if (r < M) {
            dst[(size_t)(hA * 64 + dA) * Mepad + r] = __float2bfloat16(acc[fm][0][j] + bA);
            dst[(size_t)(hB * 64 + dB) * Mepad + r] = __float2bfloat16(acc[fm][1][j] + bB);
          }
        }
    }
  }
}

// MFMA flash attention (bf16 output)
__global__ __launch_bounds__(256) void attn_mfma_kernel(
    const __hip_bfloat16* __restrict__ qb, const __hip_bfloat16* __restrict__ kb,
    const __hip_bfloat16* __restrict__ vt, int Mepad,
    const int* __restrict__ pc, const int* __restrict__ eb,
    int Mp, int Me, __hip_bfloat16* __restrict__ ob) {
  __shared__ __align__(16) __hip_bfloat16 pl[4][16][40];
  int h = blockIdx.y;
  int wv = threadIdx.x >> 6, lane = threadIdx.x & 63;
  int lq = lane & 15, lg = lane >> 4;
  int q0 = blockIdx.x * 64 + wv * 16;

  int lo[4], hi[4];
  #pragma unroll
  for (int r = 0; r < 4; ++r) {
    int q = q0 + lg * 4 + r;
    if (q < Mp) { int b = pc[4 * q]; lo[r] = eb[b]; hi[r] = eb[b + 1]; }
    else { lo[r] = 0x7fffffff; hi[r] = 0; }
  }
  int blo = min(min(lo[0], lo[1]), min(lo[2], lo[3]));
  int bhi = max(max(hi[0], hi[1]), max(hi[2], hi[3]));
  #pragma unroll
  for (int off = 1; off < 64; off <<= 1) {
    blo = min(blo, __shfl_xor(blo, off));
    bhi = max(bhi, __shfl_xor(bhi, off));
  }

  int qrow = min(q0 + lq, Mp - 1);
  const __hip_bfloat16* qp = qb + (size_t)qrow * 512 + h * 64 + lg * 8;
  bf16x8 aq0 = *reinterpret_cast<const bf16x8*>(qp);
  bf16x8 aq1 = *reinterpret_cast<const bf16x8*>(qp + 32);

  f32x4 zero = {0.f, 0.f, 0.f, 0.f};
  f32x4 oacc[4];
  oacc[0] = zero; oacc[1] = zero; oacc[2] = zero; oacc[3] = zero;

  for (int e0 = (blo & ~31); e0 < bhi; e0 += 32) {
    f32x4 sf[2];
    #pragma unroll
    for (int s = 0; s < 2; ++s) {
      int er = min(e0 + s * 16 + lq, Me - 1);
      const __hip_bfloat16* kp = kb + (size_t)er * 512 + h * 64 + lg * 8;
      bf16x8 bk0 = *reinterpret_cast<const bf16x8*>(kp);
      bf16x8 bk1 = *reinterpret_cast<const bf16x8*>(kp + 32);
      f32x4 z = zero;
      z = mfma16(aq0, bk0, z);
      z = mfma16(aq1, bk1, z);
      sf[s] = z;
    }
    int ea = e0 + lq, eb2 = e0 + 16 + lq;
    #pragma unroll
    for (int r = 0; r < 4; ++r) {
      bool m0 = (ea >= lo[r]) && (ea < hi[r]);
      bool m1 = (eb2 >= lo[r]) && (eb2 < hi[r]);
      float p0 = m0 ? __expf(sf[0][r]) : 0.f;
      float p1 = m1 ? __expf(sf[1][r]) : 0.f;
      pl[wv][lg * 4 + r][lq] = __float2bfloat16(p0);
      pl[wv][lg * 4 + r][16 + lq] = __float2bfloat16(p1);
    }
    asm volatile("s_waitcnt lgkmcnt(0)" ::: "memory");
    bf16x8 ap = *reinterpret_cast<const bf16x8*>(&pl[wv][lq][lg * 8]);
    #pragma unroll
    for (int dt = 0; dt < 4; ++dt) {
      const __hip_bfloat16* vp = vt + (size_t)(h * 64 + dt * 16 + lq) * Mepad + e0 + lg * 8;
      bf16x8 bv = *reinterpret_cast<const bf16x8*>(vp);
      oacc[dt] = mfma16(ap, bv, oacc[dt]);
    }
  }

  #pragma unroll
  for (int r = 0; r < 4; ++r) {
    float l = __shfl(oacc[3][r], (lane & 48));
    int q = q0 + lg * 4 + r;
    if (q < Mp && l > 0.f) {
      float inv = 1.0f / l;
      __hip_bfloat16* op = ob + (size_t)q * CDIM + h * HD;
      op[lq]      = __float2bfloat16(oacc[0][r] * inv);
      op[16 + lq] = __float2bfloat16(oacc[1][r] * inv);
      op[32 + lq] = __float2bfloat16(oacc[2][r] * inv);
    }
  }
}

__global__ void newf16_kernel(const float* __restrict__ feats, const float* __restrict__ o2,
                              const int* __restrict__ pinv, __hip_bfloat16* __restrict__ nf,
                              int N) {
  int v = blockIdx.x * 256 + threadIdx.x;
  if (v >= N * 48) return;
  int n = v / 48, c8 = (v - n * 48) * 8;
  const float* fp = feats + (size_t)n * CDIM + c8;
  const float* op = o2 + (size_t)pinv[n] * CDIM + c8;
  float4 a0 = *reinterpret_cast<const float4*>(fp);
  float4 a1 = *reinterpret_cast<const float4*>(fp + 4);
  float4 b0 = *reinterpret_cast<const float4*>(op);
  float4 b1 = *reinterpret_cast<const float4*>(op + 4);
  __hip_bfloat16 tmp[8] = {
    __float2bfloat16(a0.x + b0.x), __float2bfloat16(a0.y + b0.y),
    __float2bfloat16(a0.z + b0.z), __float2bfloat16(a0.w + b0.w),
    __float2bfloat16(a1.x + b1.x), __float2bfloat16(a1.y + b1.y),
    __float2bfloat16(a1.z + b1.z), __float2bfloat16(a1.w + b1.w)};
  *reinterpret_cast<bf16x8*>(nf + (size_t)v * 8) = *reinterpret_cast<const bf16x8*>(tmp);
}

// conv as MFMA GEMM: M=N rows, 32 cols, K split by tap groups (9 x 3 taps).
__global__ __launch_bounds__(256) void mconv_kernel(
    const __hip_bfloat16* __restrict__ nf, const int* __restrict__ nbr,
    const __hip_bfloat16* __restrict__ Wct, float* __restrict__ outp, int N) {
  __shared__ __align__(16) __hip_bfloat16 As[128][72];
  __shared__ __align__(16) __hip_bfloat16 Bs[32][72];
  __shared__ int jrow[128];
  const int n0 = blockIdx.x * 128;
  const int kg = blockIdx.y;
  const int t = threadIdx.x;
  const int lane = t & 63, w = t >> 6;
  const int lq = lane & 15, lg = lane >> 4;
  f32x4 acc[2][2];
  acc[0][0] = (f32x4){0.f,0.f,0.f,0.f}; acc[0][1] = acc[0][0];
  acc[1][0] = acc[0][0]; acc[1][1] = acc[0][0];
  const int arow = t >> 3, acol = (t & 7) * 8;

  for (int kk = kg * 3; kk < kg * 3 + 3; ++kk) {
    __syncthreads();
    if (t < 128) {
      int n = n0 + t;
      jrow[t] = (n < N) ? nbr[(size_t)n * 27 + kk] : -1;
    }
    __syncthreads();
    for (int c0 = 0; c0 < CDIM; c0 += 64) {
      #pragma unroll
      for (int i = 0; i < 4; ++i) {
        int r = arow + i * 32;
        int j = jrow[r];
        bf16x8 val = zero8();
        if (j >= 0) val = *reinterpret_cast<const bf16x8*>(nf + (size_t)j * CDIM + c0 + acol);
        *reinterpret_cast<bf16x8*>(&As[r][acol]) = val;
      }
      {
        int r = t >> 3;  // 0..31
        bf16x8 val = *reinterpret_cast<const bf16x8*>(Wct + (size_t)r * CONVK + kk * CDIM + c0 + acol);
        *reinterpret_cast<bf16x8*>(&Bs[r][acol]) = val;
      }
      __syncthreads();
      #pragma unroll
      for (int ks = 0; ks < 2; ++ks) {
        bf16x8 af[2], bfv[2];
        #pragma unroll
        for (int fm = 0; fm < 2; ++fm)
          af[fm] = *reinterpret_cast<const bf16x8*>(&As[w * 32 + fm * 16 + lq][ks * 32 + lg * 8]);
        #pragma unroll
        for (int fn = 0; fn < 2; ++fn)
          bfv[fn] = *reinterpret_cast<const bf16x8*>(&Bs[fn * 16 + lq][ks * 32 + lg * 8]);
        #pragma unroll
        for (int fm = 0; fm < 2; ++fm)
          #pragma unroll
          for (int fn = 0; fn < 2; ++fn)
            acc[fm][fn] = mfma16(af[fm], bfv[fn], acc[fm][fn]);
      }
      __syncthreads();
    }
  }
  #pragma unroll
  for (int fm = 0; fm < 2; ++fm)
    #pragma unroll
    for (int j = 0; j < 4; ++j) {
      int r = n0 + w * 32 + fm * 16 + lg * 4 + j;
      if (r < N) {
        #pragma unroll
        for (int fn = 0; fn < 2; ++fn)
          outp[((size_t)kg * N + r) * OUTD + fn * 16 + lq] = acc[fm][fn][j];
      }
    }
}

__global__ void conv_reduce_kernel(const float* __restrict__ outp,
                                   const float* __restrict__ bc,
                                   float* __restrict__ out, int N) {
  int v = blockIdx.x * 256 + threadIdx.x;
  if (v >= N * OUTD) return;
  int oo = v & (OUTD - 1);
  float s = bc[oo];
  #pragma unroll
  for (int kg = 0; kg < 9; ++kg) s += outp[(size_t)kg * N * OUTD + v];
  out[v] = s;
}

extern "C" void kernel_launch(void* const* d_in, const int* in_sizes, int n_in,
                              void* d_out, int out_size, void* d_ws, size_t ws_size,
                              hipStream_t stream) {
  const float* feats  = (const float*)d_in[0];
  const float* W_pool = (const float*)d_in[1];
  const float* b_pool = (const float*)d_in[2];
  const float* W_emb  = (const float*)d_in[3];
  const float* b_emb  = (const float*)d_in[4];
  const float* Wq = (const float*)d_in[5];  const float* bq = (const float*)d_in[6];
  const float* Wk = (const float*)d_in[7];  const float* bk = (const float*)d_in[8];
  const float* Wv = (const float*)d_in[9];  const float* bv = (const float*)d_in[10];
  const float* Wo = (const float*)d_in[11]; const float* bo = (const float*)d_in[12];
  const float* Wc = (const float*)d_in[13]; const float* bc = (const float*)d_in[14];
  const int* pool_inv    = (const int*)d_in[15];
  const int* pool_coords = (const int*)d_in[16];
  const int* emb_inv     = (const int*)d_in[17];
  const int* emb_coords  = (const int*)d_in[18];
  const int* nbr         = (const int*)d_in[19];
  const int* bsz         = (const int*)d_in[20];
  int N  = in_sizes[0] / CDIM;
  int Mp = in_sizes[16] / 4;
  int Me = in_sizes[18] / 4;
  int Mepad = ((Me >> 6) + 2) << 6;

  char* wsb = (char*)d_ws;
  size_t off = 0;
  auto alloc = [&](size_t bytes) { void* p = wsb + off; off += (bytes + 255) & ~(size_t)255; return p; };
  // lifetimes: encA -> q16 ; encB -> k16 ; pool16 -> ob16 ; feats16 -> newf16 ; o2 -> outp
  unsigned* encA = (unsigned*)alloc((size_t)Mp * CDIM * 4);
  unsigned* encB = (unsigned*)alloc((size_t)Me * CDIM * 4);
  __hip_bfloat16* pool16  = (__hip_bfloat16*)alloc((size_t)Mp * CDIM * 2);
  __hip_bfloat16* emb16   = (__hip_bfloat16*)alloc((size_t)Me * CDIM * 2);
  __hip_bfloat16* feats16 = (__hip_bfloat16*)alloc((size_t)N * CDIM * 2);
  __hip_bfloat16* vt      = (__hip_bfloat16*)alloc((size_t)512 * Mepad * 2);
  float* o2 = (float*)alloc((size_t)Mp * CDIM * 4 > (size_t)9 * N * OUTD * 4
                                ? (size_t)Mp * CDIM * 4 : (size_t)9 * N * OUTD * 4);
  __hip_bfloat16* Wt_pe = (__hip_bfloat16*)alloc((size_t)768 * CDIM * 2);
  __hip_bfloat16* Wt_kv = (__hip_bfloat16*)alloc((size_t)768 * CDIM * 2);
  __hip_bfloat16* Wt_q  = (__hip_bfloat16*)alloc((size_t)CDIM * CDIM * 2);
  __hip_bfloat16* Wt_o  = (__hip_bfloat16*)alloc((size_t)CDIM * CDIM * 2);
  __hip_bfloat16* Wct   = (__hip_bfloat16*)alloc((size_t)OUTD * CONVK * 2);
  int* smin = (int*)alloc(MAXB * 3 * 4);
  int* smax = (int*)alloc(MAXB * 3 * 4);
  int* eb   = (int*)alloc((MAXB + 1) * 4);

  __hip_bfloat16* q16  = (__hip_bfloat16*)encA;   // [Mp][512]
  __hip_bfloat16* k16  = (__hip_bfloat16*)encB;   // [Me][512]
  __hip_bfloat16* ob16 = pool16;                  // [Mp][384]
  __hip_bfloat16* newf16 = feats16;               // [N][384]
  float* outp = o2;                               // [9][N][32]

  hipMemsetAsync(encA, 0, (size_t)Mp * CDIM * 4, stream);
  hipMemsetAsync(encB, 0, (size_t)Me * CDIM * 4, stream);
  hipMemsetAsync(vt, 0, (size_t)512 * Mepad * 2, stream);
  init_small_kernel<<<1, 64, 0, stream>>>(smin, smax, eb);
  {
    int tot = Me + Mp;
    minmax_kernel<<<(tot + 255) / 256, 256, 0, stream>>>(emb_coords, Me, pool_coords, Mp, smin, smax);
    ebound_kernel<<<(Me + 255) / 256, 256, 0, stream>>>(emb_coords, Me, bsz, eb);
  }
  // weight conversions (transposed bf16)
  {
    int g384 = (CDIM * (CDIM / 8) + 255) / 256;
    wtrans_kernel<<<g384, 256, 0, stream>>>(W_pool, Wt_pe, CDIM, CDIM);
    wtrans_kernel<<<g384, 256, 0, stream>>>(W_emb, Wt_pe + (size_t)CDIM * CDIM, CDIM, CDIM);
    wtrans_kernel<<<g384, 256, 0, stream>>>(Wk, Wt_kv, CDIM, CDIM);
    wtrans_kernel<<<g384, 256, 0, stream>>>(Wv, Wt_kv + (size_t)CDIM * CDIM, CDIM, CDIM);
    wtrans_kernel<<<g384, 256, 0, stream>>>(Wq, Wt_q, CDIM, CDIM);
    wtrans_kernel<<<g384, 256, 0, stream>>>(Wo, Wt_o, CDIM, CDIM);
    wtrans_kernel<<<(OUTD * (CONVK / 8) + 255) / 256, 256, 0, stream>>>(Wc, Wct, CONVK, OUTD);
    tobf16_kernel<<<(N * 48 + 255) / 256, 256, 0, stream>>>(feats, feats16, N * 48);
  }
  vones_kernel<<<(NHEAD * Mepad + 255) / 256, 256, 0, stream>>>(vt, Mepad);

  // fused pool+emb scatter-max projection
  mgemm_kernel<0><<<dim3((N + 127) / 128, 12), 256, 0, stream>>>(
      feats16, N, Wt_pe, b_pool, b_emb, encA, encB, pool_inv, emb_inv, 0);
  pe_kernel<<<((Mp + Me) * CDIM + 255) / 256, 256, 0, stream>>>(
      encA, encB, pool16, emb16, pool_coords, Mp, emb_coords, Me, smin, smax);

  // BUGFIX (round 3): q16/k16 alias encA/encB whose stale enc bits are garbage
  // bf16; EPI2/EPI3 only write head lanes d<48, so pre-zero the whole buffers
  // (covers the d=48..63 pad lanes the attention MFMA reads).
  hipMemsetAsync(q16, 0, (size_t)Mp * 512 * 2, stream);
  hipMemsetAsync(k16, 0, (size_t)Me * 512 * 2, stream);

  // q / kv projections (write attention-ready layouts)
  mgemm_kernel<2><<<dim3((Mp + 127) / 128, 6), 256, 0, stream>>>(
      pool16, Mp, Wt_q, bq, nullptr, q16, nullptr, nullptr, nullptr, 0);
  mgemm_kernel<3><<<dim3((Me + 127) / 128, 12), 256, 0, stream>>>(
      emb16, Me, Wt_kv, bk, bv, k16, vt, nullptr, nullptr, Mepad);

  attn_mfma_kernel<<<dim3((Mp + 63) / 64, NHEAD), 256, 0, stream>>>(
      q16, k16, vt, Mepad, pool_coords, eb, Mp, Me, ob16);

  mgemm_kernel<1><<<dim3((Mp + 127) / 128, 6), 256, 0, stream>>>(
      ob16, Mp, Wt_o, bo, nullptr, o2, nullptr, nullptr, nullptr, 0);

  newf16_kernel<<<(N * 48 + 255) / 256, 256, 0, stream>>>(feats, o2, pool_inv, newf16, N);

  mconv_kernel<<<dim3((N + 127) / 128, 9), 256, 0, stream>>>(newf16, nbr, Wct, outp, N);
  conv_reduce_kernel<<<(N * OUTD + 255) / 256, 256, 0, stream>>>(outp, bc, (float*)d_out, N);
}

// Round 5
// 218.341 us; speedup vs baseline: 8.2050x; 1.1647x over previous
//
#include <hip/hip_runtime.h>
#include <hip/hip_bf16.h>
#include <math.h>

#define CDIM 384
#define NHEAD 8
#define HD 48
#define OUTD 32
#define MAXB 16
#define CONVK 10368  // 27*384

typedef __bf16 bf16x8 __attribute__((ext_vector_type(8)));
typedef float f32x4 __attribute__((ext_vector_type(4)));

__device__ __forceinline__ f32x4 mfma16(bf16x8 a, bf16x8 b, f32x4 c) {
  return __builtin_amdgcn_mfma_f32_16x16x32_bf16(a, b, c, 0, 0, 0);
}
__device__ __forceinline__ bf16x8 zero8() {
  bf16x8 z = {(__bf16)0.f, (__bf16)0.f, (__bf16)0.f, (__bf16)0.f,
              (__bf16)0.f, (__bf16)0.f, (__bf16)0.f, (__bf16)0.f};
  return z;
}

// ---- order-preserving float<->uint encoding for atomicMax segment max ----
__device__ __forceinline__ unsigned enc_f(float f) {
  unsigned u = __float_as_uint(f);
  return (u & 0x80000000u) ? ~u : (u | 0x80000000u);
}
__device__ __forceinline__ float dec_f(unsigned u) {
  unsigned v = (u & 0x80000000u) ? (u ^ 0x80000000u) : ~u;
  return __uint_as_float(v);
}

__global__ void init_small_kernel(int* smin, int* smax, int* eb) {
  int t = threadIdx.x;
  if (t < MAXB * 3) { smin[t] = 0x7fffffff; smax[t] = (int)0x80000000; }
  if (t <= MAXB) eb[t] = 0;
}

__global__ void minmax_kernel(const int* __restrict__ ec, int Me,
                              const int* __restrict__ pc, int Mp,
                              int* smin, int* smax) {
  __shared__ int lmin[MAXB * 3], lmax[MAXB * 3];
  int t = threadIdx.x;
  if (t < MAXB * 3) { lmin[t] = 0x7fffffff; lmax[t] = (int)0x80000000; }
  __syncthreads();
  int i = blockIdx.x * blockDim.x + t;
  int tot = Me + Mp;
  if (i < tot) {
    const int* r = (i < Me) ? (ec + 4 * i) : (pc + 4 * (i - Me));
    int b = r[0];
    #pragma unroll
    for (int d = 0; d < 3; ++d) {
      atomicMin(&lmin[b * 3 + d], r[1 + d]);
      atomicMax(&lmax[b * 3 + d], r[1 + d]);
    }
  }
  __syncthreads();
  if (t < MAXB * 3) {
    if (lmin[t] != 0x7fffffff) atomicMin(&smin[t], lmin[t]);
    if (lmax[t] != (int)0x80000000) atomicMax(&smax[t], lmax[t]);
  }
}

__global__ void ebound_kernel(const int* __restrict__ ec, int Me,
                              const int* __restrict__ bsz, int* eb) {
  int e = blockIdx.x * blockDim.x + threadIdx.x;
  if (e == 0) { eb[0] = 0; eb[bsz[0]] = Me; }
  if (e > 0 && e < Me) {
    int b0 = ec[4 * (e - 1)], b1 = ec[4 * e];
    for (int bb = b0 + 1; bb <= b1; ++bb) eb[bb] = e;
  }
}

// fp32 [K][Nc] -> bf16 [Nc][K] (weights; small, one-shot; reads hit L2)
__global__ void wtrans_kernel(const float* __restrict__ src, __hip_bfloat16* __restrict__ dst,
                              int K, int Nc) {
  int v = blockIdx.x * 256 + threadIdx.x;
  int k8c = K >> 3;
  if (v >= Nc * k8c) return;
  int n = v / k8c;
  int k8 = (v - n * k8c) * 8;
  __hip_bfloat16 tmp[8];
  #pragma unroll
  for (int u = 0; u < 8; ++u) tmp[u] = __float2bfloat16(src[(size_t)(k8 + u) * Nc + n]);
  *reinterpret_cast<bf16x8*>(dst + (size_t)n * K + k8) = *reinterpret_cast<const bf16x8*>(tmp);
}

__global__ void tobf16_kernel(const float* __restrict__ src, __hip_bfloat16* __restrict__ dst,
                              int total8) {
  int v = blockIdx.x * 256 + threadIdx.x;
  if (v >= total8) return;
  float4 a0 = *reinterpret_cast<const float4*>(src + (size_t)v * 8);
  float4 a1 = *reinterpret_cast<const float4*>(src + (size_t)v * 8 + 4);
  __hip_bfloat16 tmp[8] = {
    __float2bfloat16(a0.x), __float2bfloat16(a0.y), __float2bfloat16(a0.z), __float2bfloat16(a0.w),
    __float2bfloat16(a1.x), __float2bfloat16(a1.y), __float2bfloat16(a1.z), __float2bfloat16(a1.w)};
  *reinterpret_cast<bf16x8*>(dst + (size_t)v * 8) = *reinterpret_cast<const bf16x8*>(tmp);
}

// decode segment-max, add sine PE, emit bf16 activations
__global__ void pe_kernel(const unsigned* __restrict__ encP, const unsigned* __restrict__ encE,
                          __hip_bfloat16* __restrict__ pool16, __hip_bfloat16* __restrict__ emb16,
                          const int* __restrict__ pc, int Mp,
                          const int* __restrict__ ec, int Me,
                          const int* __restrict__ smin, const int* __restrict__ smax) {
  int gid = blockIdx.x * blockDim.x + threadIdx.x;
  int total = (Mp + Me) * CDIM;
  if (gid >= total) return;
  int row = gid / CDIM, c = gid - row * CDIM;
  const int* coords;
  const unsigned* src;
  __hip_bfloat16* dst;
  int lrow;
  if (row < Me) { lrow = row; coords = ec + 4 * row; src = encE; dst = emb16; }
  else { lrow = row - Me; coords = pc + 4 * lrow; src = encP; dst = pool16; }
  int b = coords[0];
  int dim = c >> 7;
  int i = c & 127;
  int j = i >> 1;
  float x = (float)coords[1 + dim];
  float mn = (float)smin[b * 3 + dim];
  float mx = (float)smax[b * 3 + dim];
  float nrm = (x - mn) / (mx - mn + 1e-6f);
  float freq = exp2f(-(float)j * 0.20762050593046014f);  // 10000^(-j/64)
  float arg = nrm * 6.283185307179586f * freq;
  float pe = (i & 1) ? cosf(arg) : sinf(arg);
  float val = dec_f(src[(size_t)lrow * CDIM + c]) + pe;
  dst[(size_t)lrow * CDIM + c] = __float2bfloat16(val);
}

__global__ void vones_kernel(__hip_bfloat16* __restrict__ vt, int Mepad) {
  int v = blockIdx.x * 256 + threadIdx.x;
  if (v >= NHEAD * Mepad) return;
  int h = v / Mepad, e = v - h * Mepad;
  vt[(size_t)(h * 64 + HD) * Mepad + e] = __float2bfloat16(1.0f);
}

// Unified bf16 MFMA GEMM: C[M x Ncols] = A[M x 384](bf16) @ Wt^T + bias.
// Wt is [Ncols][384] bf16 (pre-transposed). BM=128 BN=64 BK=64, 4 waves.
// EPI 0: dual scatter-max (cols<384 -> d0/inv0/bias0, else d1/inv1/bias1)
// EPI 1: fp32 += bias -> d0 [M][384]
// EPI 2: bf16 q-layout [M][512] (head-padded 48->64), * 1/sqrt(48)
//        NOTE: pad lanes d=48..63 must be pre-zeroed by the caller (memset).
// EPI 3: cols<384 -> k16 [M][512] (pads pre-zeroed); cols>=384 -> vt transposed
template <int EPI>
__global__ __launch_bounds__(256) void mgemm_kernel(
    const __hip_bfloat16* __restrict__ A, int M,
    const __hip_bfloat16* __restrict__ Wt,
    const float* __restrict__ bias0, const float* __restrict__ bias1,
    void* __restrict__ d0, void* __restrict__ d1,
    const int* __restrict__ inv0, const int* __restrict__ inv1,
    int Mepad) {
  __shared__ __align__(16) __hip_bfloat16 As[128][72];
  __shared__ __align__(16) __hip_bfloat16 Bs[64][72];
  const int m0 = blockIdx.x * 128;
  const int n0 = blockIdx.y * 64;
  const int t = threadIdx.x;
  const int lane = t & 63, w = t >> 6;
  const int wr = w >> 1, wc = w & 1;
  const int lq = lane & 15, lg = lane >> 4;

  f32x4 acc[4][2];
  #pragma unroll
  for (int i = 0; i < 4; ++i) {
    acc[i][0] = (f32x4){0.f, 0.f, 0.f, 0.f};
    acc[i][1] = (f32x4){0.f, 0.f, 0.f, 0.f};
  }
  const int arow = t >> 3;         // 0..31
  const int acol = (t & 7) * 8;    // 0..56

  for (int k0 = 0; k0 < CDIM; k0 += 64) {
    #pragma unroll
    for (int i = 0; i < 4; ++i) {
      int r = arow + i * 32;
      int gr = m0 + r;
      bf16x8 val = zero8();
      if (gr < M) val = *reinterpret_cast<const bf16x8*>(A + (size_t)gr * CDIM + k0 + acol);
      *reinterpret_cast<bf16x8*>(&As[r][acol]) = val;
    }
    #pragma unroll
    for (int i = 0; i < 2; ++i) {
      int r = arow + i * 32;
      bf16x8 val = *reinterpret_cast<const bf16x8*>(Wt + (size_t)(n0 + r) * CDIM + k0 + acol);
      *reinterpret_cast<bf16x8*>(&Bs[r][acol]) = val;
    }
    __syncthreads();
    #pragma unroll
    for (int ks = 0; ks < 2; ++ks) {
      bf16x8 af[4], bfv[2];
      #pragma unroll
      for (int fm = 0; fm < 4; ++fm)
        af[fm] = *reinterpret_cast<const bf16x8*>(&As[wr * 64 + fm * 16 + lq][ks * 32 + lg * 8]);
      #pragma unroll
      for (int fn = 0; fn < 2; ++fn)
        bfv[fn] = *reinterpret_cast<const bf16x8*>(&Bs[wc * 32 + fn * 16 + lq][ks * 32 + lg * 8]);
      #pragma unroll
      for (int fm = 0; fm < 4; ++fm)
        #pragma unroll
        for (int fn = 0; fn < 2; ++fn)
          acc[fm][fn] = mfma16(af[fm], bfv[fn], acc[fm][fn]);
    }
    __syncthreads();
  }

  // ---- epilogue ----
  const bool sec = (n0 >= CDIM);        // block-uniform (64 | 384)
  const int nb = n0 - (sec ? CDIM : 0) + wc * 32;
  const int nA = nb + lq, nB = nb + 16 + lq;   // the lane's two columns

  if (EPI == 0) {
    const float* bias = sec ? bias1 : bias0;
    unsigned* dst = (unsigned*)(sec ? d1 : d0);
    const int* inv = sec ? inv1 : inv0;
    float bA = bias[nA], bB = bias[nB];
    #pragma unroll
    for (int fm = 0; fm < 4; ++fm)
      #pragma unroll
      for (int j = 0; j < 4; ++j) {
        int r = m0 + wr * 64 + fm * 16 + lg * 4 + j;
        if (r < M) {
          int seg = inv[r];
          atomicMax(&dst[(size_t)seg * CDIM + nA], enc_f(acc[fm][0][j] + bA));
          atomicMax(&dst[(size_t)seg * CDIM + nB], enc_f(acc[fm][1][j] + bB));
        }
      }
  } else if (EPI == 1) {
    float bA = bias0[nA], bB = bias0[nB];
    float* dst = (float*)d0;
    #pragma unroll
    for (int fm = 0; fm < 4; ++fm)
      #pragma unroll
      for (int j = 0; j < 4; ++j) {
        int r = m0 + wr * 64 + fm * 16 + lg * 4 + j;
        if (r < M) {
          dst[(size_t)r * CDIM + nA] = acc[fm][0][j] + bA;
          dst[(size_t)r * CDIM + nB] = acc[fm][1][j] + bB;
        }
      }
  } else if (EPI == 2) {
    const float scale = 0.14433756729740643f;
    float bA = bias0[nA], bB = bias0[nB];
    int hA = nA / HD, dA = nA - hA * HD;
    int hB = nB / HD, dB = nB - hB * HD;
    __hip_bfloat16* dst = (__hip_bfloat16*)d0;
    #pragma unroll
    for (int fm = 0; fm < 4; ++fm)
      #pragma unroll
      for (int j = 0; j < 4; ++j) {
        int r = m0 + wr * 64 + fm * 16 + lg * 4 + j;
        if (r < M) {
          dst[(size_t)r * 512 + hA * 64 + dA] = __float2bfloat16((acc[fm][0][j] + bA) * scale);
          dst[(size_t)r * 512 + hB * 64 + dB] = __float2bfloat16((acc[fm][1][j] + bB) * scale);
        }
      }
  } else {  // EPI 3
    if (!sec) {
      float bA = bias0[nA], bB = bias0[nB];
      int hA = nA / HD, dA = nA - hA * HD;
      int hB = nB / HD, dB = nB - hB * HD;
      __hip_bfloat16* dst = (__hip_bfloat16*)d0;
      #pragma unroll
      for (int fm = 0; fm < 4; ++fm)
        #pragma unroll
        for (int j = 0; j < 4; ++j) {
          int r = m0 + wr * 64 + fm * 16 + lg * 4 + j;
          if (r < M) {
            dst[(size_t)r * 512 + hA * 64 + dA] = __float2bfloat16(acc[fm][0][j] + bA);
            dst[(size_t)r * 512 + hB * 64 + dB] = __float2bfloat16(acc[fm][1][j] + bB);
          }
        }
    } else {
      float bA = bias1[nA], bB = bias1[nB];
      int hA = nA / HD, dA = nA - hA * HD;
      int hB = nB / HD, dB = nB - hB * HD;
      __hip_bfloat16* dst = (__hip_bfloat16*)d1;
      #pragma unroll
      for (int fm = 0; fm < 4; ++fm)
        #pragma unroll
        for (int j = 0; j < 4; ++j) {
          int r = m0 + wr * 64 + fm * 16 + lg * 4 + j;
          if (r < M) {
            dst[(size_t)(hA * 64 + dA) * Mepad + r] = __float2bfloat16(acc[fm][0][j] + bA);
            dst[(size_t)(hB * 64 + dB) * Mepad + r] = __float2bfloat16(acc[fm][1][j] + bB);
          }
        }
    }
  }
}

// MFMA flash attention, LDS-staged K/V tiles (round 5).
// Block = 64 queries x one head, 4 waves (16 q each). Per 32-wide e-tile the
// 256 threads cooperatively stage K[32][64] and V^T[64][32] into LDS with
// coalesced 16B loads (rows are contiguous 128B/64B runs), then all waves
// read MFMA fragments via ds_read_b128. Kills the 1KB/2KB-strided per-lane
// global loads that made round 4 L1-transaction-bound.
__global__ __launch_bounds__(256) void attn_mfma_kernel(
    const __hip_bfloat16* __restrict__ qb, const __hip_bfloat16* __restrict__ kb,
    const __hip_bfloat16* __restrict__ vt, int Mepad,
    const int* __restrict__ pc, const int* __restrict__ eb,
    int Mp, int Me, __hip_bfloat16* __restrict__ ob) {
  __shared__ __align__(16) __hip_bfloat16 Ks[32][72];   // [e][d], pad->2-way-free
  __shared__ __align__(16) __hip_bfloat16 Vs[64][40];   // [d][e], pad->2-way-free
  __shared__ __align__(16) __hip_bfloat16 pl[4][16][40];
  __shared__ int s_lo[4], s_hi[4];
  const int h = blockIdx.y;
  const int t = threadIdx.x;
  const int wv = t >> 6, lane = t & 63;
  const int lq = lane & 15, lg = lane >> 4;
  const int q0 = blockIdx.x * 64 + wv * 16;

  int lo[4], hi[4];
  #pragma unroll
  for (int r = 0; r < 4; ++r) {
    int q = q0 + lg * 4 + r;
    if (q < Mp) { int b = pc[4 * q]; lo[r] = eb[b]; hi[r] = eb[b + 1]; }
    else { lo[r] = 0x7fffffff; hi[r] = 0; }
  }
  int wlo = min(min(lo[0], lo[1]), min(lo[2], lo[3]));
  int whi = max(max(hi[0], hi[1]), max(hi[2], hi[3]));
  #pragma unroll
  for (int off = 1; off < 64; off <<= 1) {
    wlo = min(wlo, __shfl_xor(wlo, off));
    whi = max(whi, __shfl_xor(whi, off));
  }
  if (lane == 0) { s_lo[wv] = wlo; s_hi[wv] = whi; }
  __syncthreads();
  int blo = min(min(s_lo[0], s_lo[1]), min(s_lo[2], s_lo[3]));
  int bhi = max(max(s_hi[0], s_hi[1]), max(s_hi[2], s_hi[3]));
  blo &= ~31;

  int qrow = min(q0 + lq, Mp - 1);
  const __hip_bfloat16* qp = qb + (size_t)qrow * 512 + h * 64 + lg * 8;
  bf16x8 aq0 = *reinterpret_cast<const bf16x8*>(qp);
  bf16x8 aq1 = *reinterpret_cast<const bf16x8*>(qp + 32);

  // staging coords (block-wide)
  const int ktr = t >> 3, ktc = (t & 7) * 8;   // K: 32 rows x 64 cols
  const int vtr = t >> 2, vtc = (t & 3) * 8;   // V^T: 64 rows x 32 cols
  const __hip_bfloat16* vrow = vt + (size_t)(h * 64 + vtr) * Mepad + vtc;

  f32x4 zero = {0.f, 0.f, 0.f, 0.f};
  f32x4 oacc[4];
  oacc[0] = zero; oacc[1] = zero; oacc[2] = zero; oacc[3] = zero;

  for (int e0 = blo; e0 < bhi; e0 += 32) {
    // cooperative staging (coalesced)
    int er = e0 + ktr;
    bf16x8 kv = zero8();
    if (er < Me) kv = *reinterpret_cast<const bf16x8*>(kb + (size_t)er * 512 + h * 64 + ktc);
    bf16x8 vv = *reinterpret_cast<const bf16x8*>(vrow + e0);  // Mepad-padded, in-bounds
    __syncthreads();   // previous iteration's reads done
    *reinterpret_cast<bf16x8*>(&Ks[ktr][ktc]) = kv;
    *reinterpret_cast<bf16x8*>(&Vs[vtr][vtc]) = vv;
    __syncthreads();   // tiles visible

    f32x4 sf[2];
    #pragma unroll
    for (int s = 0; s < 2; ++s) {
      bf16x8 bk0 = *reinterpret_cast<const bf16x8*>(&Ks[s * 16 + lq][lg * 8]);
      bf16x8 bk1 = *reinterpret_cast<const bf16x8*>(&Ks[s * 16 + lq][32 + lg * 8]);
      f32x4 z = zero;
      z = mfma16(aq0, bk0, z);
      z = mfma16(aq1, bk1, z);
      sf[s] = z;
    }
    int ea = e0 + lq, eb2 = e0 + 16 + lq;
    #pragma unroll
    for (int r = 0; r < 4; ++r) {
      bool m0 = (ea >= lo[r]) && (ea < hi[r]);
      bool m1 = (eb2 >= lo[r]) && (eb2 < hi[r]);
      float p0 = m0 ? __expf(sf[0][r]) : 0.f;
      float p1 = m1 ? __expf(sf[1][r]) : 0.f;
      pl[wv][lg * 4 + r][lq] = __float2bfloat16(p0);
      pl[wv][lg * 4 + r][16 + lq] = __float2bfloat16(p1);
    }
    asm volatile("s_waitcnt lgkmcnt(0)" ::: "memory");
    __builtin_amdgcn_sched_barrier(0);  // rule #18: don't hoist MFMA past the wait
    bf16x8 ap = *reinterpret_cast<const bf16x8*>(&pl[wv][lq][lg * 8]);
    #pragma unroll
    for (int dt = 0; dt < 4; ++dt) {
      bf16x8 bv = *reinterpret_cast<const bf16x8*>(&Vs[dt * 16 + lq][lg * 8]);
      oacc[dt] = mfma16(ap, bv, oacc[dt]);
    }
  }

  #pragma unroll
  for (int r = 0; r < 4; ++r) {
    float l = __shfl(oacc[3][r], (lane & 48));
    int q = q0 + lg * 4 + r;
    if (q < Mp && l > 0.f) {
      float inv = 1.0f / l;
      __hip_bfloat16* op = ob + (size_t)q * CDIM + h * HD;
      op[lq]      = __float2bfloat16(oacc[0][r] * inv);
      op[16 + lq] = __float2bfloat16(oacc[1][r] * inv);
      op[32 + lq] = __float2bfloat16(oacc[2][r] * inv);
    }
  }
}

__global__ void newf16_kernel(const float* __restrict__ feats, const float* __restrict__ o2,
                              const int* __restrict__ pinv, __hip_bfloat16* __restrict__ nf,
                              int N) {
  int v = blockIdx.x * 256 + threadIdx.x;
  if (v >= N * 48) return;
  int n = v / 48, c8 = (v - n * 48) * 8;
  const float* fp = feats + (size_t)n * CDIM + c8;
  const float* op = o2 + (size_t)pinv[n] * CDIM + c8;
  float4 a0 = *reinterpret_cast<const float4*>(fp);
  float4 a1 = *reinterpret_cast<const float4*>(fp + 4);
  float4 b0 = *reinterpret_cast<const float4*>(op);
  float4 b1 = *reinterpret_cast<const float4*>(op + 4);
  __hip_bfloat16 tmp[8] = {
    __float2bfloat16(a0.x + b0.x), __float2bfloat16(a0.y + b0.y),
    __float2bfloat16(a0.z + b0.z), __float2bfloat16(a0.w + b0.w),
    __float2bfloat16(a1.x + b1.x), __float2bfloat16(a1.y + b1.y),
    __float2bfloat16(a1.z + b1.z), __float2bfloat16(a1.w + b1.w)};
  *reinterpret_cast<bf16x8*>(nf + (size_t)v * 8) = *reinterpret_cast<const bf16x8*>(tmp);
}

// conv as MFMA GEMM: M=N rows, 32 cols, K split by tap groups (9 x 3 taps).
__global__ __launch_bounds__(256) void mconv_kernel(
    const __hip_bfloat16* __restrict__ nf, const int* __restrict__ nbr,
    const __hip_bfloat16* __restrict__ Wct, float* __restrict__ outp, int N) {
  __shared__ __align__(16) __hip_bfloat16 As[128][72];
  __shared__ __align__(16) __hip_bfloat16 Bs[32][72];
  __shared__ int jrow[128];
  const int n0 = blockIdx.x * 128;
  const int kg = blockIdx.y;
  const int t = threadIdx.x;
  const int lane = t & 63, w = t >> 6;
  const int lq = lane & 15, lg = lane >> 4;
  f32x4 acc[2][2];
  acc[0][0] = (f32x4){0.f,0.f,0.f,0.f}; acc[0][1] = acc[0][0];
  acc[1][0] = acc[0][0]; acc[1][1] = acc[0][0];
  const int arow = t >> 3, acol = (t & 7) * 8;

  for (int kk = kg * 3; kk < kg * 3 + 3; ++kk) {
    __syncthreads();
    if (t < 128) {
      int n = n0 + t;
      jrow[t] = (n < N) ? nbr[(size_t)n * 27 + kk] : -1;
    }
    __syncthreads();
    for (int c0 = 0; c0 < CDIM; c0 += 64) {
      #pragma unroll
      for (int i = 0; i < 4; ++i) {
        int r = arow + i * 32;
        int j = jrow[r];
        bf16x8 val = zero8();
        if (j >= 0) val = *reinterpret_cast<const bf16x8*>(nf + (size_t)j * CDIM + c0 + acol);
        *reinterpret_cast<bf16x8*>(&As[r][acol]) = val;
      }
      {
        int r = t >> 3;  // 0..31
        bf16x8 val = *reinterpret_cast<const bf16x8*>(Wct + (size_t)r * CONVK + kk * CDIM + c0 + acol);
        *reinterpret_cast<bf16x8*>(&Bs[r][acol]) = val;
      }
      __syncthreads();
      #pragma unroll
      for (int ks = 0; ks < 2; ++ks) {
        bf16x8 af[2], bfv[2];
        #pragma unroll
        for (int fm = 0; fm < 2; ++fm)
          af[fm] = *reinterpret_cast<const bf16x8*>(&As[w * 32 + fm * 16 + lq][ks * 32 + lg * 8]);
        #pragma unroll
        for (int fn = 0; fn < 2; ++fn)
          bfv[fn] = *reinterpret_cast<const bf16x8*>(&Bs[fn * 16 + lq][ks * 32 + lg * 8]);
        #pragma unroll
        for (int fm = 0; fm < 2; ++fm)
          #pragma unroll
          for (int fn = 0; fn < 2; ++fn)
            acc[fm][fn] = mfma16(af[fm], bfv[fn], acc[fm][fn]);
      }
      __syncthreads();
    }
  }
  #pragma unroll
  for (int fm = 0; fm < 2; ++fm)
    #pragma unroll
    for (int j = 0; j < 4; ++j) {
      int r = n0 + w * 32 + fm * 16 + lg * 4 + j;
      if (r < N) {
        #pragma unroll
        for (int fn = 0; fn < 2; ++fn)
          outp[((size_t)kg * N + r) * OUTD + fn * 16 + lq] = acc[fm][fn][j];
      }
    }
}

__global__ void conv_reduce_kernel(const float* __restrict__ outp,
                                   const float* __restrict__ bc,
                                   float* __restrict__ out, int N) {
  int v = blockIdx.x * 256 + threadIdx.x;
  if (v >= N * OUTD) return;
  int oo = v & (OUTD - 1);
  float s = bc[oo];
  #pragma unroll
  for (int kg = 0; kg < 9; ++kg) s += outp[(size_t)kg * N * OUTD + v];
  out[v] = s;
}

extern "C" void kernel_launch(void* const* d_in, const int* in_sizes, int n_in,
                              void* d_out, int out_size, void* d_ws, size_t ws_size,
                              hipStream_t stream) {
  const float* feats  = (const float*)d_in[0];
  const float* W_pool = (const float*)d_in[1];
  const float* b_pool = (const float*)d_in[2];
  const float* W_emb  = (const float*)d_in[3];
  const float* b_emb  = (const float*)d_in[4];
  const float* Wq = (const float*)d_in[5];  const float* bq = (const float*)d_in[6];
  const float* Wk = (const float*)d_in[7];  const float* bk = (const float*)d_in[8];
  const float* Wv = (const float*)d_in[9];  const float* bv = (const float*)d_in[10];
  const float* Wo = (const float*)d_in[11]; const float* bo = (const float*)d_in[12];
  const float* Wc = (const float*)d_in[13]; const float* bc = (const float*)d_in[14];
  const int* pool_inv    = (const int*)d_in[15];
  const int* pool_coords = (const int*)d_in[16];
  const int* emb_inv     = (const int*)d_in[17];
  const int* emb_coords  = (const int*)d_in[18];
  const int* nbr         = (const int*)d_in[19];
  const int* bsz         = (const int*)d_in[20];
  int N  = in_sizes[0] / CDIM;
  int Mp = in_sizes[16] / 4;
  int Me = in_sizes[18] / 4;
  int Mepad = ((Me >> 6) + 2) << 6;

  char* wsb = (char*)d_ws;
  size_t off = 0;
  auto alloc = [&](size_t bytes) { void* p = wsb + off; off += (bytes + 255) & ~(size_t)255; return p; };
  // lifetimes: encA -> q16 ; encB -> k16 ; pool16 -> ob16 ; feats16 -> newf16 ; o2 -> outp
  unsigned* encA = (unsigned*)alloc((size_t)Mp * CDIM * 4);
  unsigned* encB = (unsigned*)alloc((size_t)Me * CDIM * 4);
  __hip_bfloat16* pool16  = (__hip_bfloat16*)alloc((size_t)Mp * CDIM * 2);
  __hip_bfloat16* emb16   = (__hip_bfloat16*)alloc((size_t)Me * CDIM * 2);
  __hip_bfloat16* feats16 = (__hip_bfloat16*)alloc((size_t)N * CDIM * 2);
  __hip_bfloat16* vt      = (__hip_bfloat16*)alloc((size_t)512 * Mepad * 2);
  float* o2 = (float*)alloc((size_t)Mp * CDIM * 4 > (size_t)9 * N * OUTD * 4
                                ? (size_t)Mp * CDIM * 4 : (size_t)9 * N * OUTD * 4);
  __hip_bfloat16* Wt_pe = (__hip_bfloat16*)alloc((size_t)768 * CDIM * 2);
  __hip_bfloat16* Wt_kv = (__hip_bfloat16*)alloc((size_t)768 * CDIM * 2);
  __hip_bfloat16* Wt_q  = (__hip_bfloat16*)alloc((size_t)CDIM * CDIM * 2);
  __hip_bfloat16* Wt_o  = (__hip_bfloat16*)alloc((size_t)CDIM * CDIM * 2);
  __hip_bfloat16* Wct   = (__hip_bfloat16*)alloc((size_t)OUTD * CONVK * 2);
  int* smin = (int*)alloc(MAXB * 3 * 4);
  int* smax = (int*)alloc(MAXB * 3 * 4);
  int* eb   = (int*)alloc((MAXB + 1) * 4);

  __hip_bfloat16* q16  = (__hip_bfloat16*)encA;   // [Mp][512]
  __hip_bfloat16* k16  = (__hip_bfloat16*)encB;   // [Me][512]
  __hip_bfloat16* ob16 = pool16;                  // [Mp][384]
  __hip_bfloat16* newf16 = feats16;               // [N][384]
  float* outp = o2;                               // [9][N][32]

  hipMemsetAsync(encA, 0, (size_t)Mp * CDIM * 4, stream);
  hipMemsetAsync(encB, 0, (size_t)Me * CDIM * 4, stream);
  hipMemsetAsync(vt, 0, (size_t)512 * Mepad * 2, stream);
  init_small_kernel<<<1, 64, 0, stream>>>(smin, smax, eb);
  {
    int tot = Me + Mp;
    minmax_kernel<<<(tot + 255) / 256, 256, 0, stream>>>(emb_coords, Me, pool_coords, Mp, smin, smax);
    ebound_kernel<<<(Me + 255) / 256, 256, 0, stream>>>(emb_coords, Me, bsz, eb);
  }
  // weight conversions (transposed bf16)
  {
    int g384 = (CDIM * (CDIM / 8) + 255) / 256;
    wtrans_kernel<<<g384, 256, 0, stream>>>(W_pool, Wt_pe, CDIM, CDIM);
    wtrans_kernel<<<g384, 256, 0, stream>>>(W_emb, Wt_pe + (size_t)CDIM * CDIM, CDIM, CDIM);
    wtrans_kernel<<<g384, 256, 0, stream>>>(Wk, Wt_kv, CDIM, CDIM);
    wtrans_kernel<<<g384, 256, 0, stream>>>(Wv, Wt_kv + (size_t)CDIM * CDIM, CDIM, CDIM);
    wtrans_kernel<<<g384, 256, 0, stream>>>(Wq, Wt_q, CDIM, CDIM);
    wtrans_kernel<<<g384, 256, 0, stream>>>(Wo, Wt_o, CDIM, CDIM);
    wtrans_kernel<<<(OUTD * (CONVK / 8) + 255) / 256, 256, 0, stream>>>(Wc, Wct, CONVK, OUTD);
    tobf16_kernel<<<(N * 48 + 255) / 256, 256, 0, stream>>>(feats, feats16, N * 48);
  }
  vones_kernel<<<(NHEAD * Mepad + 255) / 256, 256, 0, stream>>>(vt, Mepad);

  // fused pool+emb scatter-max projection
  mgemm_kernel<0><<<dim3((N + 127) / 128, 12), 256, 0, stream>>>(
      feats16, N, Wt_pe, b_pool, b_emb, encA, encB, pool_inv, emb_inv, 0);
  pe_kernel<<<((Mp + Me) * CDIM + 255) / 256, 256, 0, stream>>>(
      encA, encB, pool16, emb16, pool_coords, Mp, emb_coords, Me, smin, smax);

  // q16/k16 alias encA/encB (stale enc bits = garbage bf16); EPI2/EPI3 only
  // write head lanes d<48, so pre-zero the buffers (covers the pad lanes).
  hipMemsetAsync(q16, 0, (size_t)Mp * 512 * 2, stream);
  hipMemsetAsync(k16, 0, (size_t)Me * 512 * 2, stream);

  // q / kv projections (write attention-ready layouts)
  mgemm_kernel<2><<<dim3((Mp + 127) / 128, 6), 256, 0, stream>>>(
      pool16, Mp, Wt_q, bq, nullptr, q16, nullptr, nullptr, nullptr, 0);
  mgemm_kernel<3><<<dim3((Me + 127) / 128, 12), 256, 0, stream>>>(
      emb16, Me, Wt_kv, bk, bv, k16, vt, nullptr, nullptr, Mepad);

  attn_mfma_kernel<<<dim3((Mp + 63) / 64, NHEAD), 256, 0, stream>>>(
      q16, k16, vt, Mepad, pool_coords, eb, Mp, Me, ob16);

  mgemm_kernel<1><<<dim3((Mp + 127) / 128, 6), 256, 0, stream>>>(
      ob16, Mp, Wt_o, bo, nullptr, o2, nullptr, nullptr, nullptr, 0);

  newf16_kernel<<<(N * 48 + 255) / 256, 256, 0, stream>>>(feats, o2, pool_inv, newf16, N);

  mconv_kernel<<<dim3((N + 127) / 128, 9), 256, 0, stream>>>(newf16, nbr, Wct, outp, N);
  conv_reduce_kernel<<<(N * OUTD + 255) / 256, 256, 0, stream>>>(outp, bc, (float*)d_out, N);
}

// Round 6
// 194.640 us; speedup vs baseline: 9.2041x; 1.1218x over previous
//
#include <hip/hip_runtime.h>
#include <hip/hip_bf16.h>
#include <math.h>

#define CDIM 384
#define NHEAD 8
#define HD 48
#define OUTD 32
#define MAXB 16
#define CONVK 10368  // 27*384

typedef __bf16 bf16x8 __attribute__((ext_vector_type(8)));
typedef float f32x4 __attribute__((ext_vector_type(4)));

__device__ __forceinline__ f32x4 mfma16(bf16x8 a, bf16x8 b, f32x4 c) {
  return __builtin_amdgcn_mfma_f32_16x16x32_bf16(a, b, c, 0, 0, 0);
}
__device__ __forceinline__ bf16x8 zero8() {
  bf16x8 z = {(__bf16)0.f, (__bf16)0.f, (__bf16)0.f, (__bf16)0.f,
              (__bf16)0.f, (__bf16)0.f, (__bf16)0.f, (__bf16)0.f};
  return z;
}

// ---- order-preserving float<->uint encoding for atomicMax segment max ----
__device__ __forceinline__ unsigned enc_f(float f) {
  unsigned u = __float_as_uint(f);
  return (u & 0x80000000u) ? ~u : (u | 0x80000000u);
}
__device__ __forceinline__ float dec_f(unsigned u) {
  unsigned v = (u & 0x80000000u) ? (u ^ 0x80000000u) : ~u;
  return __uint_as_float(v);
}

__global__ void init_small_kernel(int* smin, int* smax, int* eb) {
  int t = threadIdx.x;
  if (t < MAXB * 3) { smin[t] = 0x7fffffff; smax[t] = (int)0x80000000; }
  if (t <= MAXB) eb[t] = 0;
}

__global__ void minmax_kernel(const int* __restrict__ ec, int Me,
                              const int* __restrict__ pc, int Mp,
                              int* smin, int* smax) {
  __shared__ int lmin[MAXB * 3], lmax[MAXB * 3];
  int t = threadIdx.x;
  if (t < MAXB * 3) { lmin[t] = 0x7fffffff; lmax[t] = (int)0x80000000; }
  __syncthreads();
  int i = blockIdx.x * blockDim.x + t;
  int tot = Me + Mp;
  if (i < tot) {
    const int* r = (i < Me) ? (ec + 4 * i) : (pc + 4 * (i - Me));
    int b = r[0];
    #pragma unroll
    for (int d = 0; d < 3; ++d) {
      atomicMin(&lmin[b * 3 + d], r[1 + d]);
      atomicMax(&lmax[b * 3 + d], r[1 + d]);
    }
  }
  __syncthreads();
  if (t < MAXB * 3) {
    if (lmin[t] != 0x7fffffff) atomicMin(&smin[t], lmin[t]);
    if (lmax[t] != (int)0x80000000) atomicMax(&smax[t], lmax[t]);
  }
}

__global__ void ebound_kernel(const int* __restrict__ ec, int Me,
                              const int* __restrict__ bsz, int* eb) {
  int e = blockIdx.x * blockDim.x + threadIdx.x;
  if (e == 0) { eb[0] = 0; eb[bsz[0]] = Me; }
  if (e > 0 && e < Me) {
    int b0 = ec[4 * (e - 1)], b1 = ec[4 * e];
    for (int bb = b0 + 1; bb <= b1; ++bb) eb[bb] = e;
  }
}

// fused one-shot conversions: feats->bf16, 6x W^T, Wc^T, vones.
// flat grid; host passes segment block counts.
__global__ __launch_bounds__(256) void prep_kernel(
    const float* __restrict__ feats, __hip_bfloat16* __restrict__ feats16, int N,
    const float* __restrict__ W_pool, const float* __restrict__ W_emb,
    const float* __restrict__ Wk, const float* __restrict__ Wv,
    const float* __restrict__ Wq, const float* __restrict__ Wo,
    __hip_bfloat16* __restrict__ Wt_pe, __hip_bfloat16* __restrict__ Wt_kv,
    __hip_bfloat16* __restrict__ Wt_q, __hip_bfloat16* __restrict__ Wt_o,
    const float* __restrict__ Wc, __hip_bfloat16* __restrict__ Wct,
    __hip_bfloat16* __restrict__ vt, int Mepad,
    int nbF, int nbW, int nbC) {
  int b = blockIdx.x;
  int t = threadIdx.x;
  if (b < nbF) {  // feats -> bf16, 8 elems/thread
    int v = b * 256 + t;
    if (v < N * 48) {
      float4 a0 = *reinterpret_cast<const float4*>(feats + (size_t)v * 8);
      float4 a1 = *reinterpret_cast<const float4*>(feats + (size_t)v * 8 + 4);
      __hip_bfloat16 tmp[8] = {
        __float2bfloat16(a0.x), __float2bfloat16(a0.y), __float2bfloat16(a0.z), __float2bfloat16(a0.w),
        __float2bfloat16(a1.x), __float2bfloat16(a1.y), __float2bfloat16(a1.z), __float2bfloat16(a1.w)};
      *reinterpret_cast<bf16x8*>(feats16 + (size_t)v * 8) = *reinterpret_cast<const bf16x8*>(tmp);
    }
    return;
  }
  b -= nbF;
  if (b < 6 * nbW) {  // 384x384 weight transposes
    int m = b / nbW;
    int v = (b - m * nbW) * 256 + t;
    if (v >= CDIM * 48) return;
    const float* src;
    __hip_bfloat16* dst;
    switch (m) {
      case 0: src = W_pool; dst = Wt_pe; break;
      case 1: src = W_emb;  dst = Wt_pe + (size_t)CDIM * CDIM; break;
      case 2: src = Wk;     dst = Wt_kv; break;
      case 3: src = Wv;     dst = Wt_kv + (size_t)CDIM * CDIM; break;
      case 4: src = Wq;     dst = Wt_q; break;
      default: src = Wo;    dst = Wt_o; break;
    }
    int n = v / 48, k8 = (v - n * 48) * 8;
    __hip_bfloat16 tmp[8];
    #pragma unroll
    for (int u = 0; u < 8; ++u) tmp[u] = __float2bfloat16(src[(size_t)(k8 + u) * CDIM + n]);
    *reinterpret_cast<bf16x8*>(dst + (size_t)n * CDIM + k8) = *reinterpret_cast<const bf16x8*>(tmp);
    return;
  }
  b -= 6 * nbW;
  if (b < nbC) {  // Wc [10368][32] -> Wct [32][10368]
    int v = b * 256 + t;
    if (v >= OUTD * (CONVK / 8)) return;
    int n = v / (CONVK / 8), k8 = (v - n * (CONVK / 8)) * 8;
    __hip_bfloat16 tmp[8];
    #pragma unroll
    for (int u = 0; u < 8; ++u) tmp[u] = __float2bfloat16(Wc[(size_t)(k8 + u) * OUTD + n]);
    *reinterpret_cast<bf16x8*>(Wct + (size_t)n * CONVK + k8) = *reinterpret_cast<const bf16x8*>(tmp);
    return;
  }
  b -= nbC;
  {  // vones: vt row d=HD per head = 1.0
    int v = b * 256 + t;
    if (v < NHEAD * Mepad) {
      int h = v / Mepad, e = v - h * Mepad;
      vt[(size_t)(h * 64 + HD) * Mepad + e] = __float2bfloat16(1.0f);
    }
  }
}

// decode segment-max, add sine PE, emit bf16 activations
__global__ void pe_kernel(const unsigned* __restrict__ encP, const unsigned* __restrict__ encE,
                          __hip_bfloat16* __restrict__ pool16, __hip_bfloat16* __restrict__ emb16,
                          const int* __restrict__ pc, int Mp,
                          const int* __restrict__ ec, int Me,
                          const int* __restrict__ smin, const int* __restrict__ smax) {
  int gid = blockIdx.x * blockDim.x + threadIdx.x;
  int total = (Mp + Me) * CDIM;
  if (gid >= total) return;
  int row = gid / CDIM, c = gid - row * CDIM;
  const int* coords;
  const unsigned* src;
  __hip_bfloat16* dst;
  int lrow;
  if (row < Me) { lrow = row; coords = ec + 4 * row; src = encE; dst = emb16; }
  else { lrow = row - Me; coords = pc + 4 * lrow; src = encP; dst = pool16; }
  int b = coords[0];
  int dim = c >> 7;
  int i = c & 127;
  int j = i >> 1;
  float x = (float)coords[1 + dim];
  float mn = (float)smin[b * 3 + dim];
  float mx = (float)smax[b * 3 + dim];
  float nrm = (x - mn) / (mx - mn + 1e-6f);
  float freq = exp2f(-(float)j * 0.20762050593046014f);  // 10000^(-j/64)
  float arg = nrm * 6.283185307179586f * freq;
  float pe = (i & 1) ? cosf(arg) : sinf(arg);
  float val = dec_f(src[(size_t)lrow * CDIM + c]) + pe;
  dst[(size_t)lrow * CDIM + c] = __float2bfloat16(val);
}

// Unified bf16 MFMA GEMM (unchanged from round 5)
template <int EPI>
__global__ __launch_bounds__(256) void mgemm_kernel(
    const __hip_bfloat16* __restrict__ A, int M,
    const __hip_bfloat16* __restrict__ Wt,
    const float* __restrict__ bias0, const float* __restrict__ bias1,
    void* __restrict__ d0, void* __restrict__ d1,
    const int* __restrict__ inv0, const int* __restrict__ inv1,
    int Mepad) {
  __shared__ __align__(16) __hip_bfloat16 As[128][72];
  __shared__ __align__(16) __hip_bfloat16 Bs[64][72];
  const int m0 = blockIdx.x * 128;
  const int n0 = blockIdx.y * 64;
  const int t = threadIdx.x;
  const int lane = t & 63, w = t >> 6;
  const int wr = w >> 1, wc = w & 1;
  const int lq = lane & 15, lg = lane >> 4;

  f32x4 acc[4][2];
  #pragma unroll
  for (int i = 0; i < 4; ++i) {
    acc[i][0] = (f32x4){0.f, 0.f, 0.f, 0.f};
    acc[i][1] = (f32x4){0.f, 0.f, 0.f, 0.f};
  }
  const int arow = t >> 3;
  const int acol = (t & 7) * 8;

  for (int k0 = 0; k0 < CDIM; k0 += 64) {
    #pragma unroll
    for (int i = 0; i < 4; ++i) {
      int r = arow + i * 32;
      int gr = m0 + r;
      bf16x8 val = zero8();
      if (gr < M) val = *reinterpret_cast<const bf16x8*>(A + (size_t)gr * CDIM + k0 + acol);
      *reinterpret_cast<bf16x8*>(&As[r][acol]) = val;
    }
    #pragma unroll
    for (int i = 0; i < 2; ++i) {
      int r = arow + i * 32;
      bf16x8 val = *reinterpret_cast<const bf16x8*>(Wt + (size_t)(n0 + r) * CDIM + k0 + acol);
      *reinterpret_cast<bf16x8*>(&Bs[r][acol]) = val;
    }
    __syncthreads();
    #pragma unroll
    for (int ks = 0; ks < 2; ++ks) {
      bf16x8 af[4], bfv[2];
      #pragma unroll
      for (int fm = 0; fm < 4; ++fm)
        af[fm] = *reinterpret_cast<const bf16x8*>(&As[wr * 64 + fm * 16 + lq][ks * 32 + lg * 8]);
      #pragma unroll
      for (int fn = 0; fn < 2; ++fn)
        bfv[fn] = *reinterpret_cast<const bf16x8*>(&Bs[wc * 32 + fn * 16 + lq][ks * 32 + lg * 8]);
      #pragma unroll
      for (int fm = 0; fm < 4; ++fm)
        #pragma unroll
        for (int fn = 0; fn < 2; ++fn)
          acc[fm][fn] = mfma16(af[fm], bfv[fn], acc[fm][fn]);
    }
    __syncthreads();
  }

  const bool sec = (n0 >= CDIM);
  const int nb = n0 - (sec ? CDIM : 0) + wc * 32;
  const int nA = nb + lq, nB = nb + 16 + lq;

  if (EPI == 0) {
    const float* bias = sec ? bias1 : bias0;
    unsigned* dst = (unsigned*)(sec ? d1 : d0);
    const int* inv = sec ? inv1 : inv0;
    float bA = bias[nA], bB = bias[nB];
    #pragma unroll
    for (int fm = 0; fm < 4; ++fm)
      #pragma unroll
      for (int j = 0; j < 4; ++j) {
        int r = m0 + wr * 64 + fm * 16 + lg * 4 + j;
        if (r < M) {
          int seg = inv[r];
          atomicMax(&dst[(size_t)seg * CDIM + nA], enc_f(acc[fm][0][j] + bA));
          atomicMax(&dst[(size_t)seg * CDIM + nB], enc_f(acc[fm][1][j] + bB));
        }
      }
  } else if (EPI == 1) {
    float bA = bias0[nA], bB = bias0[nB];
    float* dst = (float*)d0;
    #pragma unroll
    for (int fm = 0; fm < 4; ++fm)
      #pragma unroll
      for (int j = 0; j < 4; ++j) {
        int r = m0 + wr * 64 + fm * 16 + lg * 4 + j;
        if (r < M) {
          dst[(size_t)r * CDIM + nA] = acc[fm][0][j] + bA;
          dst[(size_t)r * CDIM + nB] = acc[fm][1][j] + bB;
        }
      }
  } else if (EPI == 2) {
    const float scale = 0.14433756729740643f;
    float bA = bias0[nA], bB = bias0[nB];
    int hA = nA / HD, dA = nA - hA * HD;
    int hB = nB / HD, dB = nB - hB * HD;
    __hip_bfloat16* dst = (__hip_bfloat16*)d0;
    #pragma unroll
    for (int fm = 0; fm < 4; ++fm)
      #pragma unroll
      for (int j = 0; j < 4; ++j) {
        int r = m0 + wr * 64 + fm * 16 + lg * 4 + j;
        if (r < M) {
          dst[(size_t)r * 512 + hA * 64 + dA] = __float2bfloat16((acc[fm][0][j] + bA) * scale);
          dst[(size_t)r * 512 + hB * 64 + dB] = __float2bfloat16((acc[fm][1][j] + bB) * scale);
        }
      }
  } else {  // EPI 3
    if (!sec) {
      float bA = bias0[nA], bB = bias0[nB];
      int hA = nA / HD, dA = nA - hA * HD;
      int hB = nB / HD, dB = nB - hB * HD;
      __hip_bfloat16* dst = (__hip_bfloat16*)d0;
      #pragma unroll
      for (int fm = 0; fm < 4; ++fm)
        #pragma unroll
        for (int j = 0; j < 4; ++j) {
          int r = m0 + wr * 64 + fm * 16 + lg * 4 + j;
          if (r < M) {
            dst[(size_t)r * 512 + hA * 64 + dA] = __float2bfloat16(acc[fm][0][j] + bA);
            dst[(size_t)r * 512 + hB * 64 + dB] = __float2bfloat16(acc[fm][1][j] + bB);
          }
        }
    } else {
      float bA = bias1[nA], bB = bias1[nB];
      int hA = nA / HD, dA = nA - hA * HD;
      int hB = nB / HD, dB = nB - hB * HD;
      __hip_bfloat16* dst = (__hip_bfloat16*)d1;
      #pragma unroll
      for (int fm = 0; fm < 4; ++fm)
        #pragma unroll
        for (int j = 0; j < 4; ++j) {
          int r = m0 + wr * 64 + fm * 16 + lg * 4 + j;
          if (r < M) {
            dst[(size_t)(hA * 64 + dA) * Mepad + r] = __float2bfloat16(acc[fm][0][j] + bA);
            dst[(size_t)(hB * 64 + dB) * Mepad + r] = __float2bfloat16(acc[fm][1][j] + bB);
          }
        }
    }
  }
}

// MFMA flash attention, round 6: 64-wide e-tiles + register prefetch.
// Block = 64 queries x one head, 4 waves. Per iter: stage K[64][64] + V^T[64][64]
// from regs (loaded LAST iter -> HBM latency hidden under compute), 16 MFMA.
__global__ __launch_bounds__(256) void attn_mfma_kernel(
    const __hip_bfloat16* __restrict__ qb, const __hip_bfloat16* __restrict__ kb,
    const __hip_bfloat16* __restrict__ vt, int Mepad,
    const int* __restrict__ pc, const int* __restrict__ eb,
    int Mp, int Me, __hip_bfloat16* __restrict__ ob) {
  __shared__ __align__(16) __hip_bfloat16 Ks[64][72];
  __shared__ __align__(16) __hip_bfloat16 Vs[64][72];
  __shared__ __align__(16) __hip_bfloat16 pl[4][16][72];
  __shared__ int s_lo[4], s_hi[4];
  const int h = blockIdx.y;
  const int t = threadIdx.x;
  const int wv = t >> 6, lane = t & 63;
  const int lq = lane & 15, lg = lane >> 4;
  const int q0 = blockIdx.x * 64 + wv * 16;

  int lo[4], hi[4];
  #pragma unroll
  for (int r = 0; r < 4; ++r) {
    int q = q0 + lg * 4 + r;
    if (q < Mp) { int b = pc[4 * q]; lo[r] = eb[b]; hi[r] = eb[b + 1]; }
    else { lo[r] = 0x7fffffff; hi[r] = 0; }
  }
  int wlo = min(min(lo[0], lo[1]), min(lo[2], lo[3]));
  int whi = max(max(hi[0], hi[1]), max(hi[2], hi[3]));
  #pragma unroll
  for (int off = 1; off < 64; off <<= 1) {
    wlo = min(wlo, __shfl_xor(wlo, off));
    whi = max(whi, __shfl_xor(whi, off));
  }
  if (lane == 0) { s_lo[wv] = wlo; s_hi[wv] = whi; }
  __syncthreads();
  int blo = min(min(s_lo[0], s_lo[1]), min(s_lo[2], s_lo[3]));
  int bhi = max(max(s_hi[0], s_hi[1]), max(s_hi[2], s_hi[3]));
  blo &= ~63;

  int qrow = min(q0 + lq, Mp - 1);
  const __hip_bfloat16* qp = qb + (size_t)qrow * 512 + h * 64 + lg * 8;
  bf16x8 aq0 = *reinterpret_cast<const bf16x8*>(qp);
  bf16x8 aq1 = *reinterpret_cast<const bf16x8*>(qp + 32);

  // staging coords: K tile 64 rows x 64 cols, 32B/thread (2x bf16x8)
  const int str = t >> 2;             // 0..63
  const int stc = (t & 3) * 16;       // 0,16,32,48
  const __hip_bfloat16* vrow = vt + (size_t)(h * 64 + str) * Mepad + stc;

  f32x4 zero = {0.f, 0.f, 0.f, 0.f};
  f32x4 oacc[4];
  oacc[0] = zero; oacc[1] = zero; oacc[2] = zero; oacc[3] = zero;

  bf16x8 k0, k1, v0, v1;
  auto load_tile = [&](int e0) {
    int er = e0 + str;
    k0 = zero8(); k1 = zero8();
    if (er < Me) {
      const __hip_bfloat16* kp = kb + (size_t)er * 512 + h * 64 + stc;
      k0 = *reinterpret_cast<const bf16x8*>(kp);
      k1 = *reinterpret_cast<const bf16x8*>(kp + 8);
    }
    v0 = *reinterpret_cast<const bf16x8*>(vrow + e0);      // Mepad-padded
    v1 = *reinterpret_cast<const bf16x8*>(vrow + e0 + 8);
  };
  load_tile(blo);

  for (int e0 = blo; e0 < bhi; e0 += 64) {
    __syncthreads();   // previous tile's reads complete before overwrite
    *reinterpret_cast<bf16x8*>(&Ks[str][stc]) = k0;
    *reinterpret_cast<bf16x8*>(&Ks[str][stc + 8]) = k1;
    *reinterpret_cast<bf16x8*>(&Vs[str][stc]) = v0;
    *reinterpret_cast<bf16x8*>(&Vs[str][stc + 8]) = v1;
    __syncthreads();   // tile visible
    if (e0 + 64 < bhi) load_tile(e0 + 64);   // prefetch overlaps compute below

    f32x4 sf[4];
    #pragma unroll
    for (int s = 0; s < 4; ++s) {
      bf16x8 bk0 = *reinterpret_cast<const bf16x8*>(&Ks[s * 16 + lq][lg * 8]);
      bf16x8 bk1 = *reinterpret_cast<const bf16x8*>(&Ks[s * 16 + lq][32 + lg * 8]);
      f32x4 z = zero;
      z = mfma16(aq0, bk0, z);
      z = mfma16(aq1, bk1, z);
      sf[s] = z;
    }
    #pragma unroll
    for (int s = 0; s < 4; ++s) {
      int e = e0 + s * 16 + lq;
      #pragma unroll
      for (int r = 0; r < 4; ++r) {
        bool m = (e >= lo[r]) && (e < hi[r]);
        float p = m ? __expf(sf[s][r]) : 0.f;
        pl[wv][lg * 4 + r][s * 16 + lq] = __float2bfloat16(p);
      }
    }
    asm volatile("s_waitcnt lgkmcnt(0)" ::: "memory");
    __builtin_amdgcn_sched_barrier(0);  // rule #18
    #pragma unroll
    for (int ks = 0; ks < 2; ++ks) {
      bf16x8 ap = *reinterpret_cast<const bf16x8*>(&pl[wv][lq][ks * 32 + lg * 8]);
      #pragma unroll
      for (int dt = 0; dt < 4; ++dt) {
        bf16x8 bv = *reinterpret_cast<const bf16x8*>(&Vs[dt * 16 + lq][ks * 32 + lg * 8]);
        oacc[dt] = mfma16(ap, bv, oacc[dt]);
      }
    }
  }

  #pragma unroll
  for (int r = 0; r < 4; ++r) {
    float l = __shfl(oacc[3][r], (lane & 48));
    int q = q0 + lg * 4 + r;
    if (q < Mp && l > 0.f) {
      float inv = 1.0f / l;
      __hip_bfloat16* op = ob + (size_t)q * CDIM + h * HD;
      op[lq]      = __float2bfloat16(oacc[0][r] * inv);
      op[16 + lq] = __float2bfloat16(oacc[1][r] * inv);
      op[32 + lq] = __float2bfloat16(oacc[2][r] * inv);
    }
  }
}

__global__ void newf16_kernel(const float* __restrict__ feats, const float* __restrict__ o2,
                              const int* __restrict__ pinv, __hip_bfloat16* __restrict__ nf,
                              int N) {
  int v = blockIdx.x * 256 + threadIdx.x;
  if (v >= N * 48) return;
  int n = v / 48, c8 = (v - n * 48) * 8;
  const float* fp = feats + (size_t)n * CDIM + c8;
  const float* op = o2 + (size_t)pinv[n] * CDIM + c8;
  float4 a0 = *reinterpret_cast<const float4*>(fp);
  float4 a1 = *reinterpret_cast<const float4*>(fp + 4);
  float4 b0 = *reinterpret_cast<const float4*>(op);
  float4 b1 = *reinterpret_cast<const float4*>(op + 4);
  __hip_bfloat16 tmp[8] = {
    __float2bfloat16(a0.x + b0.x), __float2bfloat16(a0.y + b0.y),
    __float2bfloat16(a0.z + b0.z), __float2bfloat16(a0.w + b0.w),
    __float2bfloat16(a1.x + b1.x), __float2bfloat16(a1.y + b1.y),
    __float2bfloat16(a1.z + b1.z), __float2bfloat16(a1.w + b1.w)};
  *reinterpret_cast<bf16x8*>(nf + (size_t)v * 8) = *reinterpret_cast<const bf16x8*>(tmp);
}

// conv as MFMA GEMM: M=N rows, 32 cols, K split by tap groups (9 x 3 taps).
__global__ __launch_bounds__(256) void mconv_kernel(
    const __hip_bfloat16* __restrict__ nf, const int* __restrict__ nbr,
    const __hip_bfloat16* __restrict__ Wct, float* __restrict__ outp, int N) {
  __shared__ __align__(16) __hip_bfloat16 As[128][72];
  __shared__ __align__(16) __hip_bfloat16 Bs[32][72];
  __shared__ int jrow[128];
  const int n0 = blockIdx.x * 128;
  const int kg = blockIdx.y;
  const int t = threadIdx.x;
  const int lane = t & 63, w = t >> 6;
  const int lq = lane & 15, lg = lane >> 4;
  f32x4 acc[2][2];
  acc[0][0] = (f32x4){0.f,0.f,0.f,0.f}; acc[0][1] = acc[0][0];
  acc[1][0] = acc[0][0]; acc[1][1] = acc[0][0];
  const int arow = t >> 3, acol = (t & 7) * 8;

  for (int kk = kg * 3; kk < kg * 3 + 3; ++kk) {
    __syncthreads();
    if (t < 128) {
      int n = n0 + t;
      jrow[t] = (n < N) ? nbr[(size_t)n * 27 + kk] : -1;
    }
    __syncthreads();
    for (int c0 = 0; c0 < CDIM; c0 += 64) {
      #pragma unroll
      for (int i = 0; i < 4; ++i) {
        int r = arow + i * 32;
        int j = jrow[r];
        bf16x8 val = zero8();
        if (j >= 0) val = *reinterpret_cast<const bf16x8*>(nf + (size_t)j * CDIM + c0 + acol);
        *reinterpret_cast<bf16x8*>(&As[r][acol]) = val;
      }
      {
        int r = t >> 3;
        bf16x8 val = *reinterpret_cast<const bf16x8*>(Wct + (size_t)r * CONVK + kk * CDIM + c0 + acol);
        *reinterpret_cast<bf16x8*>(&Bs[r][acol]) = val;
      }
      __syncthreads();
      #pragma unroll
      for (int ks = 0; ks < 2; ++ks) {
        bf16x8 af[2], bfv[2];
        #pragma unroll
        for (int fm = 0; fm < 2; ++fm)
          af[fm] = *reinterpret_cast<const bf16x8*>(&As[w * 32 + fm * 16 + lq][ks * 32 + lg * 8]);
        #pragma unroll
        for (int fn = 0; fn < 2; ++fn)
          bfv[fn] = *reinterpret_cast<const bf16x8*>(&Bs[fn * 16 + lq][ks * 32 + lg * 8]);
        #pragma unroll
        for (int fm = 0; fm < 2; ++fm)
          #pragma unroll
          for (int fn = 0; fn < 2; ++fn)
            acc[fm][fn] = mfma16(af[fm], bfv[fn], acc[fm][fn]);
      }
      __syncthreads();
    }
  }
  #pragma unroll
  for (int fm = 0; fm < 2; ++fm)
    #pragma unroll
    for (int j = 0; j < 4; ++j) {
      int r = n0 + w * 32 + fm * 16 + lg * 4 + j;
      if (r < N) {
        #pragma unroll
        for (int fn = 0; fn < 2; ++fn)
          outp[((size_t)kg * N + r) * OUTD + fn * 16 + lq] = acc[fm][fn][j];
      }
    }
}

__global__ void conv_reduce_kernel(const float* __restrict__ outp,
                                   const float* __restrict__ bc,
                                   float* __restrict__ out, int N) {
  int v = blockIdx.x * 256 + threadIdx.x;
  if (v >= N * OUTD) return;
  int oo = v & (OUTD - 1);
  float s = bc[oo];
  #pragma unroll
  for (int kg = 0; kg < 9; ++kg) s += outp[(size_t)kg * N * OUTD + v];
  out[v] = s;
}

extern "C" void kernel_launch(void* const* d_in, const int* in_sizes, int n_in,
                              void* d_out, int out_size, void* d_ws, size_t ws_size,
                              hipStream_t stream) {
  const float* feats  = (const float*)d_in[0];
  const float* W_pool = (const float*)d_in[1];
  const float* b_pool = (const float*)d_in[2];
  const float* W_emb  = (const float*)d_in[3];
  const float* b_emb  = (const float*)d_in[4];
  const float* Wq = (const float*)d_in[5];  const float* bq = (const float*)d_in[6];
  const float* Wk = (const float*)d_in[7];  const float* bk = (const float*)d_in[8];
  const float* Wv = (const float*)d_in[9];  const float* bv = (const float*)d_in[10];
  const float* Wo = (const float*)d_in[11]; const float* bo = (const float*)d_in[12];
  const float* Wc = (const float*)d_in[13]; const float* bc = (const float*)d_in[14];
  const int* pool_inv    = (const int*)d_in[15];
  const int* pool_coords = (const int*)d_in[16];
  const int* emb_inv     = (const int*)d_in[17];
  const int* emb_coords  = (const int*)d_in[18];
  const int* nbr         = (const int*)d_in[19];
  const int* bsz         = (const int*)d_in[20];
  int N  = in_sizes[0] / CDIM;
  int Mp = in_sizes[16] / 4;
  int Me = in_sizes[18] / 4;
  int Mepad = ((Me >> 6) + 2) << 6;

  char* wsb = (char*)d_ws;
  size_t off = 0;
  auto alloc = [&](size_t bytes) { void* p = wsb + off; off += (bytes + 255) & ~(size_t)255; return p; };
  // encA, encB, vt adjacent -> single startup memset over the whole span.
  unsigned* encA = (unsigned*)alloc((size_t)Mp * CDIM * 4);
  unsigned* encB = (unsigned*)alloc((size_t)Me * CDIM * 4);
  __hip_bfloat16* vt = (__hip_bfloat16*)alloc((size_t)512 * Mepad * 2);
  size_t zspan1 = off;   // bytes to zero at start
  __hip_bfloat16* pool16  = (__hip_bfloat16*)alloc((size_t)Mp * CDIM * 2);
  __hip_bfloat16* emb16   = (__hip_bfloat16*)alloc((size_t)Me * CDIM * 2);
  __hip_bfloat16* feats16 = (__hip_bfloat16*)alloc((size_t)N * CDIM * 2);
  float* o2 = (float*)alloc((size_t)Mp * CDIM * 4 > (size_t)9 * N * OUTD * 4
                                ? (size_t)Mp * CDIM * 4 : (size_t)9 * N * OUTD * 4);
  __hip_bfloat16* Wt_pe = (__hip_bfloat16*)alloc((size_t)768 * CDIM * 2);
  __hip_bfloat16* Wt_kv = (__hip_bfloat16*)alloc((size_t)768 * CDIM * 2);
  __hip_bfloat16* Wt_q  = (__hip_bfloat16*)alloc((size_t)CDIM * CDIM * 2);
  __hip_bfloat16* Wt_o  = (__hip_bfloat16*)alloc((size_t)CDIM * CDIM * 2);
  __hip_bfloat16* Wct   = (__hip_bfloat16*)alloc((size_t)OUTD * CONVK * 2);
  int* smin = (int*)alloc(MAXB * 3 * 4);
  int* smax = (int*)alloc(MAXB * 3 * 4);
  int* eb   = (int*)alloc((MAXB + 1) * 4);

  __hip_bfloat16* q16  = (__hip_bfloat16*)encA;   // [Mp][512]
  __hip_bfloat16* k16  = (__hip_bfloat16*)encB;   // [Me][512]
  __hip_bfloat16* ob16 = pool16;                  // [Mp][384]
  __hip_bfloat16* newf16 = feats16;               // [N][384]
  float* outp = o2;                               // [9][N][32]

  // single startup memset: encA + encB + vt (incl. alignment gaps)
  hipMemsetAsync(wsb, 0, zspan1, stream);
  init_small_kernel<<<1, 64, 0, stream>>>(smin, smax, eb);
  {
    int tot = Me + Mp;
    minmax_kernel<<<(tot + 255) / 256, 256, 0, stream>>>(emb_coords, Me, pool_coords, Mp, smin, smax);
    ebound_kernel<<<(Me + 255) / 256, 256, 0, stream>>>(emb_coords, Me, bsz, eb);
  }
  // fused one-shot conversions
  int nbF = (N * 48 + 255) / 256;
  int nbW = (CDIM * 48 + 255) / 256;
  int nbC = (OUTD * (CONVK / 8) + 255) / 256;
  int nbV = (NHEAD * Mepad + 255) / 256;
  prep_kernel<<<nbF + 6 * nbW + nbC + nbV, 256, 0, stream>>>(
      feats, feats16, N, W_pool, W_emb, Wk, Wv, Wq, Wo,
      Wt_pe, Wt_kv, Wt_q, Wt_o, Wc, Wct, vt, Mepad, nbF, nbW, nbC);

  // fused pool+emb scatter-max projection
  mgemm_kernel<0><<<dim3((N + 127) / 128, 12), 256, 0, stream>>>(
      feats16, N, Wt_pe, b_pool, b_emb, encA, encB, pool_inv, emb_inv, 0);
  pe_kernel<<<((Mp + Me) * CDIM + 255) / 256, 256, 0, stream>>>(
      encA, encB, pool16, emb16, pool_coords, Mp, emb_coords, Me, smin, smax);

  // q16/k16 alias encA/encB (stale enc bits = garbage bf16); EPI2/EPI3 only
  // write head lanes d<48 -> single spanning memset zeroes both incl. pads.
  hipMemsetAsync(encA, 0, (size_t)((char*)encB - (char*)encA) + (size_t)Me * 1024, stream);

  // q / kv projections (write attention-ready layouts)
  mgemm_kernel<2><<<dim3((Mp + 127) / 128, 6), 256, 0, stream>>>(
      pool16, Mp, Wt_q, bq, nullptr, q16, nullptr, nullptr, nullptr, 0);
  mgemm_kernel<3><<<dim3((Me + 127) / 128, 12), 256, 0, stream>>>(
      emb16, Me, Wt_kv, bk, bv, k16, vt, nullptr, nullptr, Mepad);

  attn_mfma_kernel<<<dim3((Mp + 63) / 64, NHEAD), 256, 0, stream>>>(
      q16, k16, vt, Mepad, pool_coords, eb, Mp, Me, ob16);

  mgemm_kernel<1><<<dim3((Mp + 127) / 128, 6), 256, 0, stream>>>(
      ob16, Mp, Wt_o, bo, nullptr, o2, nullptr, nullptr, nullptr, 0);

  newf16_kernel<<<(N * 48 + 255) / 256, 256, 0, stream>>>(feats, o2, pool_inv, newf16, N);

  mconv_kernel<<<dim3((N + 127) / 128, 9), 256, 0, stream>>>(newf16, nbr, Wct, outp, N);
  conv_reduce_kernel<<<(N * OUTD + 255) / 256, 256, 0, stream>>>(outp, bc, (float*)d_out, N);
}

// Round 7
// 193.056 us; speedup vs baseline: 9.2796x; 1.0082x over previous
//
#include <hip/hip_runtime.h>
#include <hip/hip_bf16.h>
#include <math.h>

#define CDIM 384
#define NHEAD 8
#define HD 48
#define OUTD 32
#define MAXB 16
#define CONVK 10368  // 27*384

typedef __bf16 bf16x8 __attribute__((ext_vector_type(8)));
typedef float f32x4 __attribute__((ext_vector_type(4)));

__device__ __forceinline__ f32x4 mfma16(bf16x8 a, bf16x8 b, f32x4 c) {
  return __builtin_amdgcn_mfma_f32_16x16x32_bf16(a, b, c, 0, 0, 0);
}
__device__ __forceinline__ bf16x8 zero8() {
  bf16x8 z = {(__bf16)0.f, (__bf16)0.f, (__bf16)0.f, (__bf16)0.f,
              (__bf16)0.f, (__bf16)0.f, (__bf16)0.f, (__bf16)0.f};
  return z;
}

// ---- order-preserving float<->uint encoding for atomicMax segment max ----
__device__ __forceinline__ unsigned enc_f(float f) {
  unsigned u = __float_as_uint(f);
  return (u & 0x80000000u) ? ~u : (u | 0x80000000u);
}
__device__ __forceinline__ float dec_f(unsigned u) {
  unsigned v = (u & 0x80000000u) ? (u ^ 0x80000000u) : ~u;
  return __uint_as_float(v);
}

__global__ void init_small_kernel(int* smin, int* smax, int* eb) {
  int t = threadIdx.x;
  if (t < MAXB * 3) { smin[t] = 0x7fffffff; smax[t] = (int)0x80000000; }
  if (t <= MAXB) eb[t] = 0;
}

__global__ void minmax_kernel(const int* __restrict__ ec, int Me,
                              const int* __restrict__ pc, int Mp,
                              int* smin, int* smax) {
  __shared__ int lmin[MAXB * 3], lmax[MAXB * 3];
  int t = threadIdx.x;
  if (t < MAXB * 3) { lmin[t] = 0x7fffffff; lmax[t] = (int)0x80000000; }
  __syncthreads();
  int i = blockIdx.x * blockDim.x + t;
  int tot = Me + Mp;
  if (i < tot) {
    const int* r = (i < Me) ? (ec + 4 * i) : (pc + 4 * (i - Me));
    int b = r[0];
    #pragma unroll
    for (int d = 0; d < 3; ++d) {
      atomicMin(&lmin[b * 3 + d], r[1 + d]);
      atomicMax(&lmax[b * 3 + d], r[1 + d]);
    }
  }
  __syncthreads();
  if (t < MAXB * 3) {
    if (lmin[t] != 0x7fffffff) atomicMin(&smin[t], lmin[t]);
    if (lmax[t] != (int)0x80000000) atomicMax(&smax[t], lmax[t]);
  }
}

__global__ void ebound_kernel(const int* __restrict__ ec, int Me,
                              const int* __restrict__ bsz, int* eb) {
  int e = blockIdx.x * blockDim.x + threadIdx.x;
  if (e == 0) { eb[0] = 0; eb[bsz[0]] = Me; }
  if (e > 0 && e < Me) {
    int b0 = ec[4 * (e - 1)], b1 = ec[4 * e];
    for (int bb = b0 + 1; bb <= b1; ++bb) eb[bb] = e;
  }
}

// fused one-shot conversions: feats->bf16, 6x W^T, Wc^T, vones.
// Round 7: n is the FAST index in the transpose segments -> each of the 8
// strided source reads is wave-coalesced (256B); scattered 16B writes are
// latency-free.
__global__ __launch_bounds__(256) void prep_kernel(
    const float* __restrict__ feats, __hip_bfloat16* __restrict__ feats16, int N,
    const float* __restrict__ W_pool, const float* __restrict__ W_emb,
    const float* __restrict__ Wk, const float* __restrict__ Wv,
    const float* __restrict__ Wq, const float* __restrict__ Wo,
    __hip_bfloat16* __restrict__ Wt_pe, __hip_bfloat16* __restrict__ Wt_kv,
    __hip_bfloat16* __restrict__ Wt_q, __hip_bfloat16* __restrict__ Wt_o,
    const float* __restrict__ Wc, __hip_bfloat16* __restrict__ Wct,
    __hip_bfloat16* __restrict__ vt, int Mepad,
    int nbF, int nbW, int nbC) {
  int b = blockIdx.x;
  int t = threadIdx.x;
  if (b < nbF) {  // feats -> bf16, 8 elems/thread
    int v = b * 256 + t;
    if (v < N * 48) {
      float4 a0 = *reinterpret_cast<const float4*>(feats + (size_t)v * 8);
      float4 a1 = *reinterpret_cast<const float4*>(feats + (size_t)v * 8 + 4);
      __hip_bfloat16 tmp[8] = {
        __float2bfloat16(a0.x), __float2bfloat16(a0.y), __float2bfloat16(a0.z), __float2bfloat16(a0.w),
        __float2bfloat16(a1.x), __float2bfloat16(a1.y), __float2bfloat16(a1.z), __float2bfloat16(a1.w)};
      *reinterpret_cast<bf16x8*>(feats16 + (size_t)v * 8) = *reinterpret_cast<const bf16x8*>(tmp);
    }
    return;
  }
  b -= nbF;
  if (b < 6 * nbW) {  // 384x384 weight transposes (coalesced reads)
    int m = b / nbW;
    int v = (b - m * nbW) * 256 + t;
    if (v >= CDIM * 48) return;
    const float* src;
    __hip_bfloat16* dst;
    switch (m) {
      case 0: src = W_pool; dst = Wt_pe; break;
      case 1: src = W_emb;  dst = Wt_pe + (size_t)CDIM * CDIM; break;
      case 2: src = Wk;     dst = Wt_kv; break;
      case 3: src = Wv;     dst = Wt_kv + (size_t)CDIM * CDIM; break;
      case 4: src = Wq;     dst = Wt_q; break;
      default: src = Wo;    dst = Wt_o; break;
    }
    int k8i = v / CDIM;            // 0..47 (slow)
    int n = v - k8i * CDIM;        // 0..383 (fast -> coalesced)
    int k8 = k8i * 8;
    __hip_bfloat16 tmp[8];
    #pragma unroll
    for (int u = 0; u < 8; ++u) tmp[u] = __float2bfloat16(src[(size_t)(k8 + u) * CDIM + n]);
    *reinterpret_cast<bf16x8*>(dst + (size_t)n * CDIM + k8) = *reinterpret_cast<const bf16x8*>(tmp);
    return;
  }
  b -= 6 * nbW;
  if (b < nbC) {  // Wc [10368][32] -> Wct [32][10368] (coalesced reads)
    int v = b * 256 + t;
    if (v >= OUTD * (CONVK / 8)) return;
    int k8i = v >> 5;              // slow
    int n = v & 31;                // fast -> coalesced
    int k8 = k8i * 8;
    __hip_bfloat16 tmp[8];
    #pragma unroll
    for (int u = 0; u < 8; ++u) tmp[u] = __float2bfloat16(Wc[(size_t)(k8 + u) * OUTD + n]);
    *reinterpret_cast<bf16x8*>(Wct + (size_t)n * CONVK + k8) = *reinterpret_cast<const bf16x8*>(tmp);
    return;
  }
  b -= nbC;
  {  // vones: vt row d=HD per head = 1.0
    int v = b * 256 + t;
    if (v < NHEAD * Mepad) {
      int h = v / Mepad, e = v - h * Mepad;
      vt[(size_t)(h * 64 + HD) * Mepad + e] = __float2bfloat16(1.0f);
    }
  }
}

// decode segment-max, add sine PE, emit bf16 activations
__global__ void pe_kernel(const unsigned* __restrict__ encP, const unsigned* __restrict__ encE,
                          __hip_bfloat16* __restrict__ pool16, __hip_bfloat16* __restrict__ emb16,
                          const int* __restrict__ pc, int Mp,
                          const int* __restrict__ ec, int Me,
                          const int* __restrict__ smin, const int* __restrict__ smax) {
  int gid = blockIdx.x * blockDim.x + threadIdx.x;
  int total = (Mp + Me) * CDIM;
  if (gid >= total) return;
  int row = gid / CDIM, c = gid - row * CDIM;
  const int* coords;
  const unsigned* src;
  __hip_bfloat16* dst;
  int lrow;
  if (row < Me) { lrow = row; coords = ec + 4 * row; src = encE; dst = emb16; }
  else { lrow = row - Me; coords = pc + 4 * lrow; src = encP; dst = pool16; }
  int b = coords[0];
  int dim = c >> 7;
  int i = c & 127;
  int j = i >> 1;
  float x = (float)coords[1 + dim];
  float mn = (float)smin[b * 3 + dim];
  float mx = (float)smax[b * 3 + dim];
  float nrm = (x - mn) / (mx - mn + 1e-6f);
  float freq = exp2f(-(float)j * 0.20762050593046014f);  // 10000^(-j/64)
  float arg = nrm * 6.283185307179586f * freq;
  float pe = (i & 1) ? cosf(arg) : sinf(arg);
  float val = dec_f(src[(size_t)lrow * CDIM + c]) + pe;
  dst[(size_t)lrow * CDIM + c] = __float2bfloat16(val);
}

// Unified bf16 MFMA GEMM (EPI2 scale now folds log2(e) for exp2-softmax)
template <int EPI>
__global__ __launch_bounds__(256) void mgemm_kernel(
    const __hip_bfloat16* __restrict__ A, int M,
    const __hip_bfloat16* __restrict__ Wt,
    const float* __restrict__ bias0, const float* __restrict__ bias1,
    void* __restrict__ d0, void* __restrict__ d1,
    const int* __restrict__ inv0, const int* __restrict__ inv1,
    int Mepad) {
  __shared__ __align__(16) __hip_bfloat16 As[128][72];
  __shared__ __align__(16) __hip_bfloat16 Bs[64][72];
  const int m0 = blockIdx.x * 128;
  const int n0 = blockIdx.y * 64;
  const int t = threadIdx.x;
  const int lane = t & 63, w = t >> 6;
  const int wr = w >> 1, wc = w & 1;
  const int lq = lane & 15, lg = lane >> 4;

  f32x4 acc[4][2];
  #pragma unroll
  for (int i = 0; i < 4; ++i) {
    acc[i][0] = (f32x4){0.f, 0.f, 0.f, 0.f};
    acc[i][1] = (f32x4){0.f, 0.f, 0.f, 0.f};
  }
  const int arow = t >> 3;
  const int acol = (t & 7) * 8;

  for (int k0 = 0; k0 < CDIM; k0 += 64) {
    #pragma unroll
    for (int i = 0; i < 4; ++i) {
      int r = arow + i * 32;
      int gr = m0 + r;
      bf16x8 val = zero8();
      if (gr < M) val = *reinterpret_cast<const bf16x8*>(A + (size_t)gr * CDIM + k0 + acol);
      *reinterpret_cast<bf16x8*>(&As[r][acol]) = val;
    }
    #pragma unroll
    for (int i = 0; i < 2; ++i) {
      int r = arow + i * 32;
      bf16x8 val = *reinterpret_cast<const bf16x8*>(Wt + (size_t)(n0 + r) * CDIM + k0 + acol);
      *reinterpret_cast<bf16x8*>(&Bs[r][acol]) = val;
    }
    __syncthreads();
    #pragma unroll
    for (int ks = 0; ks < 2; ++ks) {
      bf16x8 af[4], bfv[2];
      #pragma unroll
      for (int fm = 0; fm < 4; ++fm)
        af[fm] = *reinterpret_cast<const bf16x8*>(&As[wr * 64 + fm * 16 + lq][ks * 32 + lg * 8]);
      #pragma unroll
      for (int fn = 0; fn < 2; ++fn)
        bfv[fn] = *reinterpret_cast<const bf16x8*>(&Bs[wc * 32 + fn * 16 + lq][ks * 32 + lg * 8]);
      #pragma unroll
      for (int fm = 0; fm < 4; ++fm)
        #pragma unroll
        for (int fn = 0; fn < 2; ++fn)
          acc[fm][fn] = mfma16(af[fm], bfv[fn], acc[fm][fn]);
    }
    __syncthreads();
  }

  const bool sec = (n0 >= CDIM);
  const int nb = n0 - (sec ? CDIM : 0) + wc * 32;
  const int nA = nb + lq, nB = nb + 16 + lq;

  if (EPI == 0) {
    const float* bias = sec ? bias1 : bias0;
    unsigned* dst = (unsigned*)(sec ? d1 : d0);
    const int* inv = sec ? inv1 : inv0;
    float bA = bias[nA], bB = bias[nB];
    #pragma unroll
    for (int fm = 0; fm < 4; ++fm)
      #pragma unroll
      for (int j = 0; j < 4; ++j) {
        int r = m0 + wr * 64 + fm * 16 + lg * 4 + j;
        if (r < M) {
          int seg = inv[r];
          atomicMax(&dst[(size_t)seg * CDIM + nA], enc_f(acc[fm][0][j] + bA));
          atomicMax(&dst[(size_t)seg * CDIM + nB], enc_f(acc[fm][1][j] + bB));
        }
      }
  } else if (EPI == 1) {
    float bA = bias0[nA], bB = bias0[nB];
    float* dst = (float*)d0;
    #pragma unroll
    for (int fm = 0; fm < 4; ++fm)
      #pragma unroll
      for (int j = 0; j < 4; ++j) {
        int r = m0 + wr * 64 + fm * 16 + lg * 4 + j;
        if (r < M) {
          dst[(size_t)r * CDIM + nA] = acc[fm][0][j] + bA;
          dst[(size_t)r * CDIM + nB] = acc[fm][1][j] + bB;
        }
      }
  } else if (EPI == 2) {
    // scale = log2(e)/sqrt(48): softmax via exp2 (exact rewrite of exp(s/sqrt48))
    const float scale = 0.2082350914f;
    float bA = bias0[nA], bB = bias0[nB];
    int hA = nA / HD, dA = nA - hA * HD;
    int hB = nB / HD, dB = nB - hB * HD;
    __hip_bfloat16* dst = (__hip_bfloat16*)d0;
    #pragma unroll
    for (int fm = 0; fm < 4; ++fm)
      #pragma unroll
      for (int j = 0; j < 4; ++j) {
        int r = m0 + wr * 64 + fm * 16 + lg * 4 + j;
        if (r < M) {
          dst[(size_t)r * 512 + hA * 64 + dA] = __float2bfloat16((acc[fm][0][j] + bA) * scale);
          dst[(size_t)r * 512 + hB * 64 + dB] = __float2bfloat16((acc[fm][1][j] + bB) * scale);
        }
      }
  } else {  // EPI 3
    if (!sec) {
      float bA = bias0[nA], bB = bias0[nB];
      int hA = nA / HD, dA = nA - hA * HD;
      int hB = nB / HD, dB = nB - hB * HD;
      __hip_bfloat16* dst = (__hip_bfloat16*)d0;
      #pragma unroll
      for (int fm = 0; fm < 4; ++fm)
        #pragma unroll
        for (int j = 0; j < 4; ++j) {
          int r = m0 + wr * 64 + fm * 16 + lg * 4 + j;
          if (r < M) {
            dst[(size_t)r * 512 + hA * 64 + dA] = __float2bfloat16(acc[fm][0][j] + bA);
            dst[(size_t)r * 512 + hB * 64 + dB] = __float2bfloat16(acc[fm][1][j] + bB);
          }
        }
    } else {
      float bA = bias1[nA], bB = bias1[nB];
      int hA = nA / HD, dA = nA - hA * HD;
      int hB = nB / HD, dB = nB - hB * HD;
      __hip_bfloat16* dst = (__hip_bfloat16*)d1;
      #pragma unroll
      for (int fm = 0; fm < 4; ++fm)
        #pragma unroll
        for (int j = 0; j < 4; ++j) {
          int r = m0 + wr * 64 + fm * 16 + lg * 4 + j;
          if (r < M) {
            dst[(size_t)(hA * 64 + dA) * Mepad + r] = __float2bfloat16(acc[fm][0][j] + bA);
            dst[(size_t)(hB * 64 + dB) * Mepad + r] = __float2bfloat16(acc[fm][1][j] + bB);
          }
        }
    }
  }
}

// MFMA flash attention, round 7: swapped QK^T (lane holds P[q=lq][4e] -> packed
// b64 P-writes), exp2 softmax (log2e folded into q), mask hoisted out of
// interior tiles (batch-uniform blocks skip all cmps). Same LDS staging +
// register prefetch as round 6.
__global__ __launch_bounds__(256) void attn_mfma_kernel(
    const __hip_bfloat16* __restrict__ qb, const __hip_bfloat16* __restrict__ kb,
    const __hip_bfloat16* __restrict__ vt, int Mepad,
    const int* __restrict__ pc, const int* __restrict__ eb,
    int Mp, int Me, __hip_bfloat16* __restrict__ ob) {
  __shared__ __align__(16) __hip_bfloat16 Ks[64][72];
  __shared__ __align__(16) __hip_bfloat16 Vs[64][72];
  __shared__ __align__(16) __hip_bfloat16 pl[4][16][72];
  __shared__ int sred[16];
  const int h = blockIdx.y;
  const int t = threadIdx.x;
  const int wv = t >> 6, lane = t & 63;
  const int lq = lane & 15, lg = lane >> 4;
  const int q0 = blockIdx.x * 64 + wv * 16;

  // per-lane query range (this lane's q = q0 + lq; identical across lg groups)
  const int q_l = min(q0 + lq, Mp - 1);
  const int b_l = pc[4 * q_l];
  const int lo_q = eb[b_l], hi_q = eb[b_l + 1];

  int lomin = lo_q, lomax = lo_q, himin = hi_q, himax = hi_q;
  #pragma unroll
  for (int off = 1; off < 16; off <<= 1) {
    lomin = min(lomin, __shfl_xor(lomin, off));
    lomax = max(lomax, __shfl_xor(lomax, off));
    himin = min(himin, __shfl_xor(himin, off));
    himax = max(himax, __shfl_xor(himax, off));
  }
  if (lane == 0) {
    sred[wv * 4 + 0] = lomin; sred[wv * 4 + 1] = lomax;
    sred[wv * 4 + 2] = himin; sred[wv * 4 + 3] = himax;
  }
  __syncthreads();
  lomin = min(min(sred[0], sred[4]), min(sred[8], sred[12]));
  lomax = max(max(sred[1], sred[5]), max(sred[9], sred[13]));
  himin = min(min(sred[2], sred[6]), min(sred[10], sred[14]));
  himax = max(max(sred[3], sred[7]), max(sred[11], sred[15]));
  const bool uniform = (lomin == lomax) && (himin == himax);

  const __hip_bfloat16* qp = qb + (size_t)q_l * 512 + h * 64 + lg * 8;
  bf16x8 aq0 = *reinterpret_cast<const bf16x8*>(qp);
  bf16x8 aq1 = *reinterpret_cast<const bf16x8*>(qp + 32);

  // staging coords: tiles 64 rows x 64 cols, 32B/thread
  const int str = t >> 2;
  const int stc = (t & 3) * 16;
  const __hip_bfloat16* vrow = vt + (size_t)(h * 64 + str) * Mepad + stc;

  f32x4 zero = {0.f, 0.f, 0.f, 0.f};
  f32x4 oacc[4];
  oacc[0] = zero; oacc[1] = zero; oacc[2] = zero; oacc[3] = zero;

  bf16x8 k0, k1, v0, v1;
  auto load_tile = [&](int e0) {
    int er = e0 + str;
    k0 = zero8(); k1 = zero8();
    if (er < Me) {
      const __hip_bfloat16* kp = kb + (size_t)er * 512 + h * 64 + stc;
      k0 = *reinterpret_cast<const bf16x8*>(kp);
      k1 = *reinterpret_cast<const bf16x8*>(kp + 8);
    }
    v0 = *reinterpret_cast<const bf16x8*>(vrow + e0);
    v1 = *reinterpret_cast<const bf16x8*>(vrow + e0 + 8);
  };
  const int e0beg = lomin & ~63;
  load_tile(e0beg);

  for (int e0 = e0beg; e0 < himax; e0 += 64) {
    __syncthreads();   // previous tile's reads complete before overwrite
    *reinterpret_cast<bf16x8*>(&Ks[str][stc]) = k0;
    *reinterpret_cast<bf16x8*>(&Ks[str][stc + 8]) = k1;
    *reinterpret_cast<bf16x8*>(&Vs[str][stc]) = v0;
    *reinterpret_cast<bf16x8*>(&Vs[str][stc + 8]) = v1;
    __syncthreads();   // tile visible
    if (e0 + 64 < himax) load_tile(e0 + 64);   // prefetch overlaps compute

    // swapped QK^T: D[e'][q] with col=q=lq, row=e'=lg*4+j
    f32x4 sf[4];
    #pragma unroll
    for (int s = 0; s < 4; ++s) {
      bf16x8 bk0 = *reinterpret_cast<const bf16x8*>(&Ks[s * 16 + lq][lg * 8]);
      bf16x8 bk1 = *reinterpret_cast<const bf16x8*>(&Ks[s * 16 + lq][32 + lg * 8]);
      f32x4 z = zero;
      z = mfma16(bk0, aq0, z);
      z = mfma16(bk1, aq1, z);
      sf[s] = z;
    }
    const bool interior = uniform && (e0 >= lomin) && (e0 + 64 <= himin);
    if (interior) {
      #pragma unroll
      for (int s = 0; s < 4; ++s) {
        __hip_bfloat16 tmp[4];
        #pragma unroll
        for (int j = 0; j < 4; ++j) tmp[j] = __float2bfloat16(exp2f(sf[s][j]));
        *reinterpret_cast<uint2*>(&pl[wv][lq][s * 16 + lg * 4]) =
            *reinterpret_cast<const uint2*>(tmp);
      }
    } else {
      const int ebase = e0 + lg * 4;
      #pragma unroll
      for (int s = 0; s < 4; ++s) {
        __hip_bfloat16 tmp[4];
        #pragma unroll
        for (int j = 0; j < 4; ++j) {
          int e = ebase + s * 16 + j;
          float p = (e >= lo_q && e < hi_q) ? exp2f(sf[s][j]) : 0.f;
          tmp[j] = __float2bfloat16(p);
        }
        *reinterpret_cast<uint2*>(&pl[wv][lq][s * 16 + lg * 4]) =
            *reinterpret_cast<const uint2*>(tmp);
      }
    }
    asm volatile("s_waitcnt lgkmcnt(0)" ::: "memory");
    __builtin_amdgcn_sched_barrier(0);  // rule #18
    #pragma unroll
    for (int ks = 0; ks < 2; ++ks) {
      bf16x8 ap = *reinterpret_cast<const bf16x8*>(&pl[wv][lq][ks * 32 + lg * 8]);
      #pragma unroll
      for (int dt = 0; dt < 4; ++dt) {
        bf16x8 bv = *reinterpret_cast<const bf16x8*>(&Vs[dt * 16 + lq][ks * 32 + lg * 8]);
        oacc[dt] = mfma16(ap, bv, oacc[dt]);
      }
    }
  }

  #pragma unroll
  for (int r = 0; r < 4; ++r) {
    float l = __shfl(oacc[3][r], (lane & 48));
    int q = q0 + lg * 4 + r;
    if (q < Mp && l > 0.f) {
      float inv = 1.0f / l;
      __hip_bfloat16* op = ob + (size_t)q * CDIM + h * HD;
      op[lq]      = __float2bfloat16(oacc[0][r] * inv);
      op[16 + lq] = __float2bfloat16(oacc[1][r] * inv);
      op[32 + lq] = __float2bfloat16(oacc[2][r] * inv);
    }
  }
}

__global__ void newf16_kernel(const float* __restrict__ feats, const float* __restrict__ o2,
                              const int* __restrict__ pinv, __hip_bfloat16* __restrict__ nf,
                              int N) {
  int v = blockIdx.x * 256 + threadIdx.x;
  if (v >= N * 48) return;
  int n = v / 48, c8 = (v - n * 48) * 8;
  const float* fp = feats + (size_t)n * CDIM + c8;
  const float* op = o2 + (size_t)pinv[n] * CDIM + c8;
  float4 a0 = *reinterpret_cast<const float4*>(fp);
  float4 a1 = *reinterpret_cast<const float4*>(fp + 4);
  float4 b0 = *reinterpret_cast<const float4*>(op);
  float4 b1 = *reinterpret_cast<const float4*>(op + 4);
  __hip_bfloat16 tmp[8] = {
    __float2bfloat16(a0.x + b0.x), __float2bfloat16(a0.y + b0.y),
    __float2bfloat16(a0.z + b0.z), __float2bfloat16(a0.w + b0.w),
    __float2bfloat16(a1.x + b1.x), __float2bfloat16(a1.y + b1.y),
    __float2bfloat16(a1.z + b1.z), __float2bfloat16(a1.w + b1.w)};
  *reinterpret_cast<bf16x8*>(nf + (size_t)v * 8) = *reinterpret_cast<const bf16x8*>(tmp);
}

// conv as MFMA GEMM: M=N rows, 32 cols, K split by tap groups (9 x 3 taps).
__global__ __launch_bounds__(256) void mconv_kernel(
    const __hip_bfloat16* __restrict__ nf, const int* __restrict__ nbr,
    const __hip_bfloat16* __restrict__ Wct, float* __restrict__ outp, int N) {
  __shared__ __align__(16) __hip_bfloat16 As[128][72];
  __shared__ __align__(16) __hip_bfloat16 Bs[32][72];
  __shared__ int jrow[128];
  const int n0 = blockIdx.x * 128;
  const int kg = blockIdx.y;
  const int t = threadIdx.x;
  const int lane = t & 63, w = t >> 6;
  const int lq = lane & 15, lg = lane >> 4;
  f32x4 acc[2][2];
  acc[0][0] = (f32x4){0.f,0.f,0.f,0.f}; acc[0][1] = acc[0][0];
  acc[1][0] = acc[0][0]; acc[1][1] = acc[0][0];
  const int arow = t >> 3, acol = (t & 7) * 8;

  for (int kk = kg * 3; kk < kg * 3 + 3; ++kk) {
    __syncthreads();
    if (t < 128) {
      int n = n0 + t;
      jrow[t] = (n < N) ? nbr[(size_t)n * 27 + kk] : -1;
    }
    __syncthreads();
    for (int c0 = 0; c0 < CDIM; c0 += 64) {
      #pragma unroll
      for (int i = 0; i < 4; ++i) {
        int r = arow + i * 32;
        int j = jrow[r];
        bf16x8 val = zero8();
        if (j >= 0) val = *reinterpret_cast<const bf16x8*>(nf + (size_t)j * CDIM + c0 + acol);
        *reinterpret_cast<bf16x8*>(&As[r][acol]) = val;
      }
      {
        int r = t >> 3;
        bf16x8 val = *reinterpret_cast<const bf16x8*>(Wct + (size_t)r * CONVK + kk * CDIM + c0 + acol);
        *reinterpret_cast<bf16x8*>(&Bs[r][acol]) = val;
      }
      __syncthreads();
      #pragma unroll
      for (int ks = 0; ks < 2; ++ks) {
        bf16x8 af[2], bfv[2];
        #pragma unroll
        for (int fm = 0; fm < 2; ++fm)
          af[fm] = *reinterpret_cast<const bf16x8*>(&As[w * 32 + fm * 16 + lq][ks * 32 + lg * 8]);
        #pragma unroll
        for (int fn = 0; fn < 2; ++fn)
          bfv[fn] = *reinterpret_cast<const bf16x8*>(&Bs[fn * 16 + lq][ks * 32 + lg * 8]);
        #pragma unroll
        for (int fm = 0; fm < 2; ++fm)
          #pragma unroll
          for (int fn = 0; fn < 2; ++fn)
            acc[fm][fn] = mfma16(af[fm], bfv[fn], acc[fm][fn]);
      }
      __syncthreads();
    }
  }
  #pragma unroll
  for (int fm = 0; fm < 2; ++fm)
    #pragma unroll
    for (int j = 0; j < 4; ++j) {
      int r = n0 + w * 32 + fm * 16 + lg * 4 + j;
      if (r < N) {
        #pragma unroll
        for (int fn = 0; fn < 2; ++fn)
          outp[((size_t)kg * N + r) * OUTD + fn * 16 + lq] = acc[fm][fn][j];
      }
    }
}

__global__ void conv_reduce_kernel(const float* __restrict__ outp,
                                   const float* __restrict__ bc,
                                   float* __restrict__ out, int N) {
  int v = blockIdx.x * 256 + threadIdx.x;
  if (v >= N * OUTD) return;
  int oo = v & (OUTD - 1);
  float s = bc[oo];
  #pragma unroll
  for (int kg = 0; kg < 9; ++kg) s += outp[(size_t)kg * N * OUTD + v];
  out[v] = s;
}

extern "C" void kernel_launch(void* const* d_in, const int* in_sizes, int n_in,
                              void* d_out, int out_size, void* d_ws, size_t ws_size,
                              hipStream_t stream) {
  const float* feats  = (const float*)d_in[0];
  const float* W_pool = (const float*)d_in[1];
  const float* b_pool = (const float*)d_in[2];
  const float* W_emb  = (const float*)d_in[3];
  const float* b_emb  = (const float*)d_in[4];
  const float* Wq = (const float*)d_in[5];  const float* bq = (const float*)d_in[6];
  const float* Wk = (const float*)d_in[7];  const float* bk = (const float*)d_in[8];
  const float* Wv = (const float*)d_in[9];  const float* bv = (const float*)d_in[10];
  const float* Wo = (const float*)d_in[11]; const float* bo = (const float*)d_in[12];
  const float* Wc = (const float*)d_in[13]; const float* bc = (const float*)d_in[14];
  const int* pool_inv    = (const int*)d_in[15];
  const int* pool_coords = (const int*)d_in[16];
  const int* emb_inv     = (const int*)d_in[17];
  const int* emb_coords  = (const int*)d_in[18];
  const int* nbr         = (const int*)d_in[19];
  const int* bsz         = (const int*)d_in[20];
  int N  = in_sizes[0] / CDIM;
  int Mp = in_sizes[16] / 4;
  int Me = in_sizes[18] / 4;
  int Mepad = ((Me >> 6) + 2) << 6;

  char* wsb = (char*)d_ws;
  size_t off = 0;
  auto alloc = [&](size_t bytes) { void* p = wsb + off; off += (bytes + 255) & ~(size_t)255; return p; };
  // encA, encB, vt adjacent -> single startup memset over the whole span.
  unsigned* encA = (unsigned*)alloc((size_t)Mp * CDIM * 4);
  unsigned* encB = (unsigned*)alloc((size_t)Me * CDIM * 4);
  __hip_bfloat16* vt = (__hip_bfloat16*)alloc((size_t)512 * Mepad * 2);
  size_t zspan1 = off;   // bytes to zero at start
  __hip_bfloat16* pool16  = (__hip_bfloat16*)alloc((size_t)Mp * CDIM * 2);
  __hip_bfloat16* emb16   = (__hip_bfloat16*)alloc((size_t)Me * CDIM * 2);
  __hip_bfloat16* feats16 = (__hip_bfloat16*)alloc((size_t)N * CDIM * 2);
  float* o2 = (float*)alloc((size_t)Mp * CDIM * 4 > (size_t)9 * N * OUTD * 4
                                ? (size_t)Mp * CDIM * 4 : (size_t)9 * N * OUTD * 4);
  __hip_bfloat16* Wt_pe = (__hip_bfloat16*)alloc((size_t)768 * CDIM * 2);
  __hip_bfloat16* Wt_kv = (__hip_bfloat16*)alloc((size_t)768 * CDIM * 2);
  __hip_bfloat16* Wt_q  = (__hip_bfloat16*)alloc((size_t)CDIM * CDIM * 2);
  __hip_bfloat16* Wt_o  = (__hip_bfloat16*)alloc((size_t)CDIM * CDIM * 2);
  __hip_bfloat16* Wct   = (__hip_bfloat16*)alloc((size_t)OUTD * CONVK * 2);
  int* smin = (int*)alloc(MAXB * 3 * 4);
  int* smax = (int*)alloc(MAXB * 3 * 4);
  int* eb   = (int*)alloc((MAXB + 1) * 4);

  __hip_bfloat16* q16  = (__hip_bfloat16*)encA;   // [Mp][512]
  __hip_bfloat16* k16  = (__hip_bfloat16*)encB;   // [Me][512]
  __hip_bfloat16* ob16 = pool16;                  // [Mp][384]
  __hip_bfloat16* newf16 = feats16;               // [N][384]
  float* outp = o2;                               // [9][N][32]

  // single startup memset: encA + encB + vt (incl. alignment gaps)
  hipMemsetAsync(wsb, 0, zspan1, stream);
  init_small_kernel<<<1, 64, 0, stream>>>(smin, smax, eb);
  {
    int tot = Me + Mp;
    minmax_kernel<<<(tot + 255) / 256, 256, 0, stream>>>(emb_coords, Me, pool_coords, Mp, smin, smax);
    ebound_kernel<<<(Me + 255) / 256, 256, 0, stream>>>(emb_coords, Me, bsz, eb);
  }
  // fused one-shot conversions
  int nbF = (N * 48 + 255) / 256;
  int nbW = (CDIM * 48 + 255) / 256;
  int nbC = (OUTD * (CONVK / 8) + 255) / 256;
  int nbV = (NHEAD * Mepad + 255) / 256;
  prep_kernel<<<nbF + 6 * nbW + nbC + nbV, 256, 0, stream>>>(
      feats, feats16, N, W_pool, W_emb, Wk, Wv, Wq, Wo,
      Wt_pe, Wt_kv, Wt_q, Wt_o, Wc, Wct, vt, Mepad, nbF, nbW, nbC);

  // fused pool+emb scatter-max projection
  mgemm_kernel<0><<<dim3((N + 127) / 128, 12), 256, 0, stream>>>(
      feats16, N, Wt_pe, b_pool, b_emb, encA, encB, pool_inv, emb_inv, 0);
  pe_kernel<<<((Mp + Me) * CDIM + 255) / 256, 256, 0, stream>>>(
      encA, encB, pool16, emb16, pool_coords, Mp, emb_coords, Me, smin, smax);

  // q16/k16 alias encA/encB (stale enc bits = garbage bf16); EPI2/EPI3 only
  // write head lanes d<48 -> single spanning memset zeroes both incl. pads.
  hipMemsetAsync(encA, 0, (size_t)((char*)encB - (char*)encA) + (size_t)Me * 1024, stream);

  // q / kv projections (write attention-ready layouts)
  mgemm_kernel<2><<<dim3((Mp + 127) / 128, 6), 256, 0, stream>>>(
      pool16, Mp, Wt_q, bq, nullptr, q16, nullptr, nullptr, nullptr, 0);
  mgemm_kernel<3><<<dim3((Me + 127) / 128, 12), 256, 0, stream>>>(
      emb16, Me, Wt_kv, bk, bv, k16, vt, nullptr, nullptr, Mepad);

  attn_mfma_kernel<<<dim3((Mp + 63) / 64, NHEAD), 256, 0, stream>>>(
      q16, k16, vt, Mepad, pool_coords, eb, Mp, Me, ob16);

  mgemm_kernel<1><<<dim3((Mp + 127) / 128, 6), 256, 0, stream>>>(
      ob16, Mp, Wt_o, bo, nullptr, o2, nullptr, nullptr, nullptr, 0);

  newf16_kernel<<<(N * 48 + 255) / 256, 256, 0, stream>>>(feats, o2, pool_inv, newf16, N);

  mconv_kernel<<<dim3((N + 127) / 128, 9), 256, 0, stream>>>(newf16, nbr, Wct, outp, N);
  conv_reduce_kernel<<<(N * OUTD + 255) / 256, 256, 0, stream>>>(outp, bc, (float*)d_out, N);
}

// Round 8
// 192.490 us; speedup vs baseline: 9.3069x; 1.0029x over previous
//
#include <hip/hip_runtime.h>
#include <hip/hip_bf16.h>
#include <math.h>

#define CDIM 384
#define NHEAD 8
#define HD 48
#define OUTD 32
#define MAXB 16
#define CONVK 10368  // 27*384

typedef __bf16 bf16x8 __attribute__((ext_vector_type(8)));
typedef float f32x4 __attribute__((ext_vector_type(4)));

__device__ __forceinline__ f32x4 mfma16(bf16x8 a, bf16x8 b, f32x4 c) {
  return __builtin_amdgcn_mfma_f32_16x16x32_bf16(a, b, c, 0, 0, 0);
}
__device__ __forceinline__ bf16x8 zero8() {
  bf16x8 z = {(__bf16)0.f, (__bf16)0.f, (__bf16)0.f, (__bf16)0.f,
              (__bf16)0.f, (__bf16)0.f, (__bf16)0.f, (__bf16)0.f};
  return z;
}

// ---- order-preserving float<->uint encoding for atomicMax segment max ----
__device__ __forceinline__ unsigned enc_f(float f) {
  unsigned u = __float_as_uint(f);
  return (u & 0x80000000u) ? ~u : (u | 0x80000000u);
}
__device__ __forceinline__ float dec_f(unsigned u) {
  unsigned v = (u & 0x80000000u) ? (u ^ 0x80000000u) : ~u;
  return __uint_as_float(v);
}

// fused one-shot prep: feats->bf16, 6x W^T, Wc^T, vones, coord minmax, ebound.
// flat grid; host passes segment block counts. smin pre-set to 0x7f7f7f7f,
// smax to 0x80808080 via memset (valid +-inf sentinels for coords <= 256).
__global__ __launch_bounds__(256) void prep_kernel(
    const float* __restrict__ feats, __hip_bfloat16* __restrict__ feats16, int N,
    const float* __restrict__ W_pool, const float* __restrict__ W_emb,
    const float* __restrict__ Wk, const float* __restrict__ Wv,
    const float* __restrict__ Wq, const float* __restrict__ Wo,
    __hip_bfloat16* __restrict__ Wt_pe, __hip_bfloat16* __restrict__ Wt_kv,
    __hip_bfloat16* __restrict__ Wt_q, __hip_bfloat16* __restrict__ Wt_o,
    const float* __restrict__ Wc, __hip_bfloat16* __restrict__ Wct,
    __hip_bfloat16* __restrict__ vt, int Mepad,
    const int* __restrict__ ec, const int* __restrict__ pc, int Mp, int Me,
    const int* __restrict__ bsz, int* smin, int* smax, int* ebv,
    int nbF, int nbW, int nbC, int nbV, int nbM) {
  __shared__ int lmin[MAXB * 3], lmax[MAXB * 3];
  int b = blockIdx.x;
  int t = threadIdx.x;
  if (b < nbF) {  // feats -> bf16, 8 elems/thread
    int v = b * 256 + t;
    if (v < N * 48) {
      float4 a0 = *reinterpret_cast<const float4*>(feats + (size_t)v * 8);
      float4 a1 = *reinterpret_cast<const float4*>(feats + (size_t)v * 8 + 4);
      __hip_bfloat16 tmp[8] = {
        __float2bfloat16(a0.x), __float2bfloat16(a0.y), __float2bfloat16(a0.z), __float2bfloat16(a0.w),
        __float2bfloat16(a1.x), __float2bfloat16(a1.y), __float2bfloat16(a1.z), __float2bfloat16(a1.w)};
      *reinterpret_cast<bf16x8*>(feats16 + (size_t)v * 8) = *reinterpret_cast<const bf16x8*>(tmp);
    }
    return;
  }
  b -= nbF;
  if (b < 6 * nbW) {  // 384x384 weight transposes (coalesced reads)
    int m = b / nbW;
    int v = (b - m * nbW) * 256 + t;
    if (v >= CDIM * 48) return;
    const float* src;
    __hip_bfloat16* dst;
    switch (m) {
      case 0: src = W_pool; dst = Wt_pe; break;
      case 1: src = W_emb;  dst = Wt_pe + (size_t)CDIM * CDIM; break;
      case 2: src = Wk;     dst = Wt_kv; break;
      case 3: src = Wv;     dst = Wt_kv + (size_t)CDIM * CDIM; break;
      case 4: src = Wq;     dst = Wt_q; break;
      default: src = Wo;    dst = Wt_o; break;
    }
    int k8i = v / CDIM;            // slow
    int n = v - k8i * CDIM;        // fast -> coalesced
    int k8 = k8i * 8;
    __hip_bfloat16 tmp[8];
    #pragma unroll
    for (int u = 0; u < 8; ++u) tmp[u] = __float2bfloat16(src[(size_t)(k8 + u) * CDIM + n]);
    *reinterpret_cast<bf16x8*>(dst + (size_t)n * CDIM + k8) = *reinterpret_cast<const bf16x8*>(tmp);
    return;
  }
  b -= 6 * nbW;
  if (b < nbC) {  // Wc [10368][32] -> Wct [32][10368] (coalesced reads)
    int v = b * 256 + t;
    if (v >= OUTD * (CONVK / 8)) return;
    int k8i = v >> 5;
    int n = v & 31;
    int k8 = k8i * 8;
    __hip_bfloat16 tmp[8];
    #pragma unroll
    for (int u = 0; u < 8; ++u) tmp[u] = __float2bfloat16(Wc[(size_t)(k8 + u) * OUTD + n]);
    *reinterpret_cast<bf16x8*>(Wct + (size_t)n * CONVK + k8) = *reinterpret_cast<const bf16x8*>(tmp);
    return;
  }
  b -= nbC;
  if (b < nbV) {  // vones: vt row d=HD per head = 1.0
    int v = b * 256 + t;
    if (v < NHEAD * Mepad) {
      int h = v / Mepad, e = v - h * Mepad;
      vt[(size_t)(h * 64 + HD) * Mepad + e] = __float2bfloat16(1.0f);
    }
    return;
  }
  b -= nbV;
  if (b < nbM) {  // per-batch coord min/max
    if (t < MAXB * 3) { lmin[t] = 0x7fffffff; lmax[t] = (int)0x80000000; }
    __syncthreads();
    int i = b * 256 + t;
    int tot = Me + Mp;
    if (i < tot) {
      const int* r = (i < Me) ? (ec + 4 * i) : (pc + 4 * (i - Me));
      int bb = r[0];
      #pragma unroll
      for (int d = 0; d < 3; ++d) {
        atomicMin(&lmin[bb * 3 + d], r[1 + d]);
        atomicMax(&lmax[bb * 3 + d], r[1 + d]);
      }
    }
    __syncthreads();
    if (t < MAXB * 3) {
      if (lmin[t] != 0x7fffffff) atomicMin(&smin[t], lmin[t]);
      if (lmax[t] != (int)0x80000000) atomicMax(&smax[t], lmax[t]);
    }
    return;
  }
  b -= nbM;
  {  // ebound: per-batch [start,end) over batch-sorted emb_coords
    int e = b * 256 + t;
    if (e == 0) { ebv[0] = 0; ebv[bsz[0]] = Me; }
    if (e > 0 && e < Me) {
      int b0 = ec[4 * (e - 1)], b1 = ec[4 * e];
      for (int bb = b0 + 1; bb <= b1; ++bb) ebv[bb] = e;
    }
  }
}

// decode segment-max, add sine PE, emit bf16 activations
__global__ void pe_kernel(const unsigned* __restrict__ encP, const unsigned* __restrict__ encE,
                          __hip_bfloat16* __restrict__ pool16, __hip_bfloat16* __restrict__ emb16,
                          const int* __restrict__ pc, int Mp,
                          const int* __restrict__ ec, int Me,
                          const int* __restrict__ smin, const int* __restrict__ smax) {
  int gid = blockIdx.x * blockDim.x + threadIdx.x;
  int total = (Mp + Me) * CDIM;
  if (gid >= total) return;
  int row = gid / CDIM, c = gid - row * CDIM;
  const int* coords;
  const unsigned* src;
  __hip_bfloat16* dst;
  int lrow;
  if (row < Me) { lrow = row; coords = ec + 4 * row; src = encE; dst = emb16; }
  else { lrow = row - Me; coords = pc + 4 * lrow; src = encP; dst = pool16; }
  int b = coords[0];
  int dim = c >> 7;
  int i = c & 127;
  int j = i >> 1;
  float x = (float)coords[1 + dim];
  float mn = (float)smin[b * 3 + dim];
  float mx = (float)smax[b * 3 + dim];
  float nrm = (x - mn) / (mx - mn + 1e-6f);
  float freq = exp2f(-(float)j * 0.20762050593046014f);  // 10000^(-j/64)
  float arg = nrm * 6.283185307179586f * freq;
  float pe = (i & 1) ? cosf(arg) : sinf(arg);
  float val = dec_f(src[(size_t)lrow * CDIM + c]) + pe;
  dst[(size_t)lrow * CDIM + c] = __float2bfloat16(val);
}

// Unified bf16 MFMA GEMM. EPI2 folds log2(e)/sqrt(48) (exp2 softmax).
// EPI0 merges consecutive equal-segment maxes before the atomic (rows are
// coord-sorted -> up-to-8 rows share a segment; max is associative ->
// deterministic).
template <int EPI>
__global__ __launch_bounds__(256) void mgemm_kernel(
    const __hip_bfloat16* __restrict__ A, int M,
    const __hip_bfloat16* __restrict__ Wt,
    const float* __restrict__ bias0, const float* __restrict__ bias1,
    void* __restrict__ d0, void* __restrict__ d1,
    const int* __restrict__ inv0, const int* __restrict__ inv1,
    int Mepad) {
  __shared__ __align__(16) __hip_bfloat16 As[128][72];
  __shared__ __align__(16) __hip_bfloat16 Bs[64][72];
  const int m0 = blockIdx.x * 128;
  const int n0 = blockIdx.y * 64;
  const int t = threadIdx.x;
  const int lane = t & 63, w = t >> 6;
  const int wr = w >> 1, wc = w & 1;
  const int lq = lane & 15, lg = lane >> 4;

  f32x4 acc[4][2];
  #pragma unroll
  for (int i = 0; i < 4; ++i) {
    acc[i][0] = (f32x4){0.f, 0.f, 0.f, 0.f};
    acc[i][1] = (f32x4){0.f, 0.f, 0.f, 0.f};
  }
  const int arow = t >> 3;
  const int acol = (t & 7) * 8;

  for (int k0 = 0; k0 < CDIM; k0 += 64) {
    #pragma unroll
    for (int i = 0; i < 4; ++i) {
      int r = arow + i * 32;
      int gr = m0 + r;
      bf16x8 val = zero8();
      if (gr < M) val = *reinterpret_cast<const bf16x8*>(A + (size_t)gr * CDIM + k0 + acol);
      *reinterpret_cast<bf16x8*>(&As[r][acol]) = val;
    }
    #pragma unroll
    for (int i = 0; i < 2; ++i) {
      int r = arow + i * 32;
      bf16x8 val = *reinterpret_cast<const bf16x8*>(Wt + (size_t)(n0 + r) * CDIM + k0 + acol);
      *reinterpret_cast<bf16x8*>(&Bs[r][acol]) = val;
    }
    __syncthreads();
    #pragma unroll
    for (int ks = 0; ks < 2; ++ks) {
      bf16x8 af[4], bfv[2];
      #pragma unroll
      for (int fm = 0; fm < 4; ++fm)
        af[fm] = *reinterpret_cast<const bf16x8*>(&As[wr * 64 + fm * 16 + lq][ks * 32 + lg * 8]);
      #pragma unroll
      for (int fn = 0; fn < 2; ++fn)
        bfv[fn] = *reinterpret_cast<const bf16x8*>(&Bs[wc * 32 + fn * 16 + lq][ks * 32 + lg * 8]);
      #pragma unroll
      for (int fm = 0; fm < 4; ++fm)
        #pragma unroll
        for (int fn = 0; fn < 2; ++fn)
          acc[fm][fn] = mfma16(af[fm], bfv[fn], acc[fm][fn]);
    }
    __syncthreads();
  }

  const bool sec = (n0 >= CDIM);
  const int nb = n0 - (sec ? CDIM : 0) + wc * 32;
  const int nA = nb + lq, nB = nb + 16 + lq;

  if (EPI == 0) {
    const float* bias = sec ? bias1 : bias0;
    unsigned* dst = (unsigned*)(sec ? d1 : d0);
    const int* inv = sec ? inv1 : inv0;
    float bA = bias[nA], bB = bias[nB];
    #pragma unroll
    for (int fm = 0; fm < 4; ++fm) {
      int rbase = m0 + wr * 64 + fm * 16 + lg * 4;
      int cs = -1;
      float mA = 0.f, mB = 0.f;
      #pragma unroll
      for (int j = 0; j < 4; ++j) {
        int r = rbase + j;
        if (r < M) {
          int s = inv[r];
          float vA = acc[fm][0][j] + bA;
          float vB = acc[fm][1][j] + bB;
          if (s == cs) { mA = fmaxf(mA, vA); mB = fmaxf(mB, vB); }
          else {
            if (cs >= 0) {
              atomicMax(&dst[(size_t)cs * CDIM + nA], enc_f(mA));
              atomicMax(&dst[(size_t)cs * CDIM + nB], enc_f(mB));
            }
            cs = s; mA = vA; mB = vB;
          }
        }
      }
      if (cs >= 0) {
        atomicMax(&dst[(size_t)cs * CDIM + nA], enc_f(mA));
        atomicMax(&dst[(size_t)cs * CDIM + nB], enc_f(mB));
      }
    }
  } else if (EPI == 1) {
    float bA = bias0[nA], bB = bias0[nB];
    float* dst = (float*)d0;
    #pragma unroll
    for (int fm = 0; fm < 4; ++fm)
      #pragma unroll
      for (int j = 0; j < 4; ++j) {
        int r = m0 + wr * 64 + fm * 16 + lg * 4 + j;
        if (r < M) {
          dst[(size_t)r * CDIM + nA] = acc[fm][0][j] + bA;
          dst[(size_t)r * CDIM + nB] = acc[fm][1][j] + bB;
        }
      }
  } else if (EPI == 2) {
    // scale = log2(e)/sqrt(48): softmax via exp2 (exact rewrite)
    const float scale = 0.2082350914f;
    float bA = bias0[nA], bB = bias0[nB];
    int hA = nA / HD, dA = nA - hA * HD;
    int hB = nB / HD, dB = nB - hB * HD;
    __hip_bfloat16* dst = (__hip_bfloat16*)d0;
    #pragma unroll
    for (int fm = 0; fm < 4; ++fm)
      #pragma unroll
      for (int j = 0; j < 4; ++j) {
        int r = m0 + wr * 64 + fm * 16 + lg * 4 + j;
        if (r < M) {
          dst[(size_t)r * 512 + hA * 64 + dA] = __float2bfloat16((acc[fm][0][j] + bA) * scale);
          dst[(size_t)r * 512 + hB * 64 + dB] = __float2bfloat16((acc[fm][1][j] + bB) * scale);
        }
      }
  } else {  // EPI 3
    if (!sec) {
      float bA = bias0[nA], bB = bias0[nB];
      int hA = nA / HD, dA = nA - hA * HD;
      int hB = nB / HD, dB = nB - hB * HD;
      __hip_bfloat16* dst = (__hip_bfloat16*)d0;
      #pragma unroll
      for (int fm = 0; fm < 4; ++fm)
        #pragma unroll
        for (int j = 0; j < 4; ++j) {
          int r = m0 + wr * 64 + fm * 16 + lg * 4 + j;
          if (r < M) {
            dst[(size_t)r * 512 + hA * 64 + dA] = __float2bfloat16(acc[fm][0][j] + bA);
            dst[(size_t)r * 512 + hB * 64 + dB] = __float2bfloat16(acc[fm][1][j] + bB);
          }
        }
    } else {
      float bA = bias1[nA], bB = bias1[nB];
      int hA = nA / HD, dA = nA - hA * HD;
      int hB = nB / HD, dB = nB - hB * HD;
      __hip_bfloat16* dst = (__hip_bfloat16*)d1;
      #pragma unroll
      for (int fm = 0; fm < 4; ++fm)
        #pragma unroll
        for (int j = 0; j < 4; ++j) {
          int r = m0 + wr * 64 + fm * 16 + lg * 4 + j;
          if (r < M) {
            dst[(size_t)(hA * 64 + dA) * Mepad + r] = __float2bfloat16(acc[fm][0][j] + bA);
            dst[(size_t)(hB * 64 + dB) * Mepad + r] = __float2bfloat16(acc[fm][1][j] + bB);
          }
        }
    }
  }
}

// MFMA flash attention, round 8: round-6 compute path (measured best) +
// exp2 softmax (scale pre-folded into q) + interior-tile mask skip.
// Interior = tile inside EVERY query's [lo,hi) -> no uniformity needed.
__global__ __launch_bounds__(256) void attn_mfma_kernel(
    const __hip_bfloat16* __restrict__ qb, const __hip_bfloat16* __restrict__ kb,
    const __hip_bfloat16* __restrict__ vt, int Mepad,
    const int* __restrict__ pc, const int* __restrict__ eb,
    int Mp, int Me, __hip_bfloat16* __restrict__ ob) {
  __shared__ __align__(16) __hip_bfloat16 Ks[64][72];
  __shared__ __align__(16) __hip_bfloat16 Vs[64][72];
  __shared__ __align__(16) __hip_bfloat16 pl[4][16][72];
  __shared__ int sred[4][4];
  const int h = blockIdx.y;
  const int t = threadIdx.x;
  const int wv = t >> 6, lane = t & 63;
  const int lq = lane & 15, lg = lane >> 4;
  const int q0 = blockIdx.x * 64 + wv * 16;

  int lo[4], hi[4];
  #pragma unroll
  for (int r = 0; r < 4; ++r) {
    int q = q0 + lg * 4 + r;
    if (q < Mp) { int b = pc[4 * q]; lo[r] = eb[b]; hi[r] = eb[b + 1]; }
    else { lo[r] = 0x7fffffff; hi[r] = 0; }
  }
  // block bounds: lomin (loop start), lomax & himin (interior test), himax (end)
  int lomin = min(min(lo[0], lo[1]), min(lo[2], lo[3]));
  int lomax = max(max(lo[0], lo[1]), max(lo[2], lo[3]));
  int himin = min(min(hi[0], hi[1]), min(hi[2], hi[3]));
  int himax = max(max(hi[0], hi[1]), max(hi[2], hi[3]));
  #pragma unroll
  for (int off = 1; off < 64; off <<= 1) {
    lomin = min(lomin, __shfl_xor(lomin, off));
    lomax = max(lomax, __shfl_xor(lomax, off));
    himin = min(himin, __shfl_xor(himin, off));
    himax = max(himax, __shfl_xor(himax, off));
  }
  if (lane == 0) {
    sred[wv][0] = lomin; sred[wv][1] = lomax;
    sred[wv][2] = himin; sred[wv][3] = himax;
  }
  __syncthreads();
  lomin = min(min(sred[0][0], sred[1][0]), min(sred[2][0], sred[3][0]));
  lomax = max(max(sred[0][1], sred[1][1]), max(sred[2][1], sred[3][1]));
  himin = min(min(sred[0][2], sred[1][2]), min(sred[2][2], sred[3][2]));
  himax = max(max(sred[0][3], sred[1][3]), max(sred[2][3], sred[3][3]));

  int qrow = min(q0 + lq, Mp - 1);
  const __hip_bfloat16* qp = qb + (size_t)qrow * 512 + h * 64 + lg * 8;
  bf16x8 aq0 = *reinterpret_cast<const bf16x8*>(qp);
  bf16x8 aq1 = *reinterpret_cast<const bf16x8*>(qp + 32);

  // staging coords: tiles 64 rows x 64 cols, 32B/thread
  const int str = t >> 2;
  const int stc = (t & 3) * 16;
  const __hip_bfloat16* vrow = vt + (size_t)(h * 64 + str) * Mepad + stc;

  f32x4 zero = {0.f, 0.f, 0.f, 0.f};
  f32x4 oacc[4];
  oacc[0] = zero; oacc[1] = zero; oacc[2] = zero; oacc[3] = zero;

  bf16x8 k0, k1, v0, v1;
  auto load_tile = [&](int e0) {
    int er = e0 + str;
    k0 = zero8(); k1 = zero8();
    if (er < Me) {
      const __hip_bfloat16* kp = kb + (size_t)er * 512 + h * 64 + stc;
      k0 = *reinterpret_cast<const bf16x8*>(kp);
      k1 = *reinterpret_cast<const bf16x8*>(kp + 8);
    }
    v0 = *reinterpret_cast<const bf16x8*>(vrow + e0);
    v1 = *reinterpret_cast<const bf16x8*>(vrow + e0 + 8);
  };
  const int e0beg = lomin & ~63;
  load_tile(e0beg);

  for (int e0 = e0beg; e0 < himax; e0 += 64) {
    __syncthreads();   // previous tile's reads complete before overwrite
    *reinterpret_cast<bf16x8*>(&Ks[str][stc]) = k0;
    *reinterpret_cast<bf16x8*>(&Ks[str][stc + 8]) = k1;
    *reinterpret_cast<bf16x8*>(&Vs[str][stc]) = v0;
    *reinterpret_cast<bf16x8*>(&Vs[str][stc + 8]) = v1;
    __syncthreads();   // tile visible
    if (e0 + 64 < himax) load_tile(e0 + 64);   // prefetch overlaps compute

    f32x4 sf[4];
    #pragma unroll
    for (int s = 0; s < 4; ++s) {
      bf16x8 bk0 = *reinterpret_cast<const bf16x8*>(&Ks[s * 16 + lq][lg * 8]);
      bf16x8 bk1 = *reinterpret_cast<const bf16x8*>(&Ks[s * 16 + lq][32 + lg * 8]);
      f32x4 z = zero;
      z = mfma16(aq0, bk0, z);
      z = mfma16(aq1, bk1, z);
      sf[s] = z;
    }
    const bool interior = (e0 >= lomax) && (e0 + 64 <= himin);
    if (interior) {
      #pragma unroll
      for (int s = 0; s < 4; ++s)
        #pragma unroll
        for (int r = 0; r < 4; ++r)
          pl[wv][lg * 4 + r][s * 16 + lq] = __float2bfloat16(exp2f(sf[s][r]));
    } else {
      #pragma unroll
      for (int s = 0; s < 4; ++s) {
        int e = e0 + s * 16 + lq;
        #pragma unroll
        for (int r = 0; r < 4; ++r) {
          bool m = (e >= lo[r]) && (e < hi[r]);
          float p = m ? exp2f(sf[s][r]) : 0.f;
          pl[wv][lg * 4 + r][s * 16 + lq] = __float2bfloat16(p);
        }
      }
    }
    asm volatile("s_waitcnt lgkmcnt(0)" ::: "memory");
    __builtin_amdgcn_sched_barrier(0);  // rule #18
    #pragma unroll
    for (int ks = 0; ks < 2; ++ks) {
      bf16x8 ap = *reinterpret_cast<const bf16x8*>(&pl[wv][lq][ks * 32 + lg * 8]);
      #pragma unroll
      for (int dt = 0; dt < 4; ++dt) {
        bf16x8 bv = *reinterpret_cast<const bf16x8*>(&Vs[dt * 16 + lq][ks * 32 + lg * 8]);
        oacc[dt] = mfma16(ap, bv, oacc[dt]);
      }
    }
  }

  #pragma unroll
  for (int r = 0; r < 4; ++r) {
    float l = __shfl(oacc[3][r], (lane & 48));
    int q = q0 + lg * 4 + r;
    if (q < Mp && l > 0.f) {
      float inv = 1.0f / l;
      __hip_bfloat16* op = ob + (size_t)q * CDIM + h * HD;
      op[lq]      = __float2bfloat16(oacc[0][r] * inv);
      op[16 + lq] = __float2bfloat16(oacc[1][r] * inv);
      op[32 + lq] = __float2bfloat16(oacc[2][r] * inv);
    }
  }
}

__global__ void newf16_kernel(const float* __restrict__ feats, const float* __restrict__ o2,
                              const int* __restrict__ pinv, __hip_bfloat16* __restrict__ nf,
                              int N) {
  int v = blockIdx.x * 256 + threadIdx.x;
  if (v >= N * 48) return;
  int n = v / 48, c8 = (v - n * 48) * 8;
  const float* fp = feats + (size_t)n * CDIM + c8;
  const float* op = o2 + (size_t)pinv[n] * CDIM + c8;
  float4 a0 = *reinterpret_cast<const float4*>(fp);
  float4 a1 = *reinterpret_cast<const float4*>(fp + 4);
  float4 b0 = *reinterpret_cast<const float4*>(op);
  float4 b1 = *reinterpret_cast<const float4*>(op + 4);
  __hip_bfloat16 tmp[8] = {
    __float2bfloat16(a0.x + b0.x), __float2bfloat16(a0.y + b0.y),
    __float2bfloat16(a0.z + b0.z), __float2bfloat16(a0.w + b0.w),
    __float2bfloat16(a1.x + b1.x), __float2bfloat16(a1.y + b1.y),
    __float2bfloat16(a1.z + b1.z), __float2bfloat16(a1.w + b1.w)};
  *reinterpret_cast<bf16x8*>(nf + (size_t)v * 8) = *reinterpret_cast<const bf16x8*>(tmp);
}

// conv as MFMA GEMM: M=N rows, 32 cols, K split by tap groups (9 x 3 taps).
__global__ __launch_bounds__(256) void mconv_kernel(
    const __hip_bfloat16* __restrict__ nf, const int* __restrict__ nbr,
    const __hip_bfloat16* __restrict__ Wct, float* __restrict__ outp, int N) {
  __shared__ __align__(16) __hip_bfloat16 As[128][72];
  __shared__ __align__(16) __hip_bfloat16 Bs[32][72];
  __shared__ int jrow[128];
  const int n0 = blockIdx.x * 128;
  const int kg = blockIdx.y;
  const int t = threadIdx.x;
  const int lane = t & 63, w = t >> 6;
  const int lq = lane & 15, lg = lane >> 4;
  f32x4 acc[2][2];
  acc[0][0] = (f32x4){0.f,0.f,0.f,0.f}; acc[0][1] = acc[0][0];
  acc[1][0] = acc[0][0]; acc[1][1] = acc[0][0];
  const int arow = t >> 3, acol = (t & 7) * 8;

  for (int kk = kg * 3; kk < kg * 3 + 3; ++kk) {
    __syncthreads();
    if (t < 128) {
      int n = n0 + t;
      jrow[t] = (n < N) ? nbr[(size_t)n * 27 + kk] : -1;
    }
    __syncthreads();
    for (int c0 = 0; c0 < CDIM; c0 += 64) {
      #pragma unroll
      for (int i = 0; i < 4; ++i) {
        int r = arow + i * 32;
        int j = jrow[r];
        bf16x8 val = zero8();
        if (j >= 0) val = *reinterpret_cast<const bf16x8*>(nf + (size_t)j * CDIM + c0 + acol);
        *reinterpret_cast<bf16x8*>(&As[r][acol]) = val;
      }
      {
        int r = t >> 3;
        bf16x8 val = *reinterpret_cast<const bf16x8*>(Wct + (size_t)r * CONVK + kk * CDIM + c0 + acol);
        *reinterpret_cast<bf16x8*>(&Bs[r][acol]) = val;
      }
      __syncthreads();
      #pragma unroll
      for (int ks = 0; ks < 2; ++ks) {
        bf16x8 af[2], bfv[2];
        #pragma unroll
        for (int fm = 0; fm < 2; ++fm)
          af[fm] = *reinterpret_cast<const bf16x8*>(&As[w * 32 + fm * 16 + lq][ks * 32 + lg * 8]);
        #pragma unroll
        for (int fn = 0; fn < 2; ++fn)
          bfv[fn] = *reinterpret_cast<const bf16x8*>(&Bs[fn * 16 + lq][ks * 32 + lg * 8]);
        #pragma unroll
        for (int fm = 0; fm < 2; ++fm)
          #pragma unroll
          for (int fn = 0; fn < 2; ++fn)
            acc[fm][fn] = mfma16(af[fm], bfv[fn], acc[fm][fn]);
      }
      __syncthreads();
    }
  }
  #pragma unroll
  for (int fm = 0; fm < 2; ++fm)
    #pragma unroll
    for (int j = 0; j < 4; ++j) {
      int r = n0 + w * 32 + fm * 16 + lg * 4 + j;
      if (r < N) {
        #pragma unroll
        for (int fn = 0; fn < 2; ++fn)
          outp[((size_t)kg * N + r) * OUTD + fn * 16 + lq] = acc[fm][fn][j];
      }
    }
}

__global__ void conv_reduce_kernel(const float* __restrict__ outp,
                                   const float* __restrict__ bc,
                                   float* __restrict__ out, int N) {
  int v = blockIdx.x * 256 + threadIdx.x;
  if (v >= N * OUTD) return;
  int oo = v & (OUTD - 1);
  float s = bc[oo];
  #pragma unroll
  for (int kg = 0; kg < 9; ++kg) s += outp[(size_t)kg * N * OUTD + v];
  out[v] = s;
}

extern "C" void kernel_launch(void* const* d_in, const int* in_sizes, int n_in,
                              void* d_out, int out_size, void* d_ws, size_t ws_size,
                              hipStream_t stream) {
  const float* feats  = (const float*)d_in[0];
  const float* W_pool = (const float*)d_in[1];
  const float* b_pool = (const float*)d_in[2];
  const float* W_emb  = (const float*)d_in[3];
  const float* b_emb  = (const float*)d_in[4];
  const float* Wq = (const float*)d_in[5];  const float* bq = (const float*)d_in[6];
  const float* Wk = (const float*)d_in[7];  const float* bk = (const float*)d_in[8];
  const float* Wv = (const float*)d_in[9];  const float* bv = (const float*)d_in[10];
  const float* Wo = (const float*)d_in[11]; const float* bo = (const float*)d_in[12];
  const float* Wc = (const float*)d_in[13]; const float* bc = (const float*)d_in[14];
  const int* pool_inv    = (const int*)d_in[15];
  const int* pool_coords = (const int*)d_in[16];
  const int* emb_inv     = (const int*)d_in[17];
  const int* emb_coords  = (const int*)d_in[18];
  const int* nbr         = (const int*)d_in[19];
  const int* bsz         = (const int*)d_in[20];
  int N  = in_sizes[0] / CDIM;
  int Mp = in_sizes[16] / 4;
  int Me = in_sizes[18] / 4;
  int Mepad = ((Me >> 6) + 2) << 6;

  char* wsb = (char*)d_ws;
  size_t off = 0;
  auto alloc = [&](size_t bytes) { void* p = wsb + off; off += (bytes + 255) & ~(size_t)255; return p; };
  unsigned* encA = (unsigned*)alloc((size_t)Mp * CDIM * 4);
  unsigned* encB = (unsigned*)alloc((size_t)Me * CDIM * 4);
  __hip_bfloat16* vt = (__hip_bfloat16*)alloc((size_t)512 * Mepad * 2);
  size_t zspan1 = off;   // bytes to zero at start
  __hip_bfloat16* pool16  = (__hip_bfloat16*)alloc((size_t)Mp * CDIM * 2);
  __hip_bfloat16* emb16   = (__hip_bfloat16*)alloc((size_t)Me * CDIM * 2);
  __hip_bfloat16* feats16 = (__hip_bfloat16*)alloc((size_t)N * CDIM * 2);
  float* o2 = (float*)alloc((size_t)Mp * CDIM * 4 > (size_t)9 * N * OUTD * 4
                                ? (size_t)Mp * CDIM * 4 : (size_t)9 * N * OUTD * 4);
  __hip_bfloat16* Wt_pe = (__hip_bfloat16*)alloc((size_t)768 * CDIM * 2);
  __hip_bfloat16* Wt_kv = (__hip_bfloat16*)alloc((size_t)768 * CDIM * 2);
  __hip_bfloat16* Wt_q  = (__hip_bfloat16*)alloc((size_t)CDIM * CDIM * 2);
  __hip_bfloat16* Wt_o  = (__hip_bfloat16*)alloc((size_t)CDIM * CDIM * 2);
  __hip_bfloat16* Wct   = (__hip_bfloat16*)alloc((size_t)OUTD * CONVK * 2);
  int* smin = (int*)alloc(MAXB * 3 * 4);
  int* smax = (int*)alloc(MAXB * 3 * 4);
  int* eb   = (int*)alloc((MAXB + 1) * 4);

  __hip_bfloat16* q16  = (__hip_bfloat16*)encA;   // [Mp][512]
  __hip_bfloat16* k16  = (__hip_bfloat16*)encB;   // [Me][512]
  __hip_bfloat16* ob16 = pool16;                  // [Mp][384]
  __hip_bfloat16* newf16 = feats16;               // [N][384]
  float* outp = o2;                               // [9][N][32]

  // startup inits: enc buffers + vt zeroed; smin/smax sentinel patterns
  hipMemsetAsync(wsb, 0, zspan1, stream);
  hipMemsetAsync(smin, 0x7f, MAXB * 3 * 4, stream);   // 0x7f7f7f7f ~ +inf for coords
  hipMemsetAsync(smax, 0x80, MAXB * 3 * 4, stream);   // 0x80808080 ~ -inf

  // fused one-shot prep (conversions + minmax + ebound)
  int nbF = (N * 48 + 255) / 256;
  int nbW = (CDIM * 48 + 255) / 256;
  int nbC = (OUTD * (CONVK / 8) + 255) / 256;
  int nbV = (NHEAD * Mepad + 255) / 256;
  int nbM = (Mp + Me + 255) / 256;
  int nbE = (Me + 255) / 256;
  prep_kernel<<<nbF + 6 * nbW + nbC + nbV + nbM + nbE, 256, 0, stream>>>(
      feats, feats16, N, W_pool, W_emb, Wk, Wv, Wq, Wo,
      Wt_pe, Wt_kv, Wt_q, Wt_o, Wc, Wct, vt, Mepad,
      emb_coords, pool_coords, Mp, Me, bsz, smin, smax, eb,
      nbF, nbW, nbC, nbV, nbM);

  // fused pool+emb scatter-max projection
  mgemm_kernel<0><<<dim3((N + 127) / 128, 12), 256, 0, stream>>>(
      feats16, N, Wt_pe, b_pool, b_emb, encA, encB, pool_inv, emb_inv, 0);
  pe_kernel<<<((Mp + Me) * CDIM + 255) / 256, 256, 0, stream>>>(
      encA, encB, pool16, emb16, pool_coords, Mp, emb_coords, Me, smin, smax);

  // q16/k16 alias encA/encB (stale enc bits = garbage bf16); EPI2/EPI3 only
  // write head lanes d<48 -> single spanning memset zeroes both incl. pads.
  hipMemsetAsync(encA, 0, (size_t)((char*)encB - (char*)encA) + (size_t)Me * 1024, stream);

  // q / kv projections (write attention-ready layouts)
  mgemm_kernel<2><<<dim3((Mp + 127) / 128, 6), 256, 0, stream>>>(
      pool16, Mp, Wt_q, bq, nullptr, q16, nullptr, nullptr, nullptr, 0);
  mgemm_kernel<3><<<dim3((Me + 127) / 128, 12), 256, 0, stream>>>(
      emb16, Me, Wt_kv, bk, bv, k16, vt, nullptr, nullptr, Mepad);

  attn_mfma_kernel<<<dim3((Mp + 63) / 64, NHEAD), 256, 0, stream>>>(
      q16, k16, vt, Mepad, pool_coords, eb, Mp, Me, ob16);

  mgemm_kernel<1><<<dim3((Mp + 127) / 128, 6), 256, 0, stream>>>(
      ob16, Mp, Wt_o, bo, nullptr, o2, nullptr, nullptr, nullptr, 0);

  newf16_kernel<<<(N * 48 + 255) / 256, 256, 0, stream>>>(feats, o2, pool_inv, newf16, N);

  mconv_kernel<<<dim3((N + 127) / 128, 9), 256, 0, stream>>>(newf16, nbr, Wct, outp, N);
  conv_reduce_kernel<<<(N * OUTD + 255) / 256, 256, 0, stream>>>(outp, bc, (float*)d_out, N);
}

// Round 9
// 163.601 us; speedup vs baseline: 10.9503x; 1.1766x over previous
//
#include <hip/hip_runtime.h>
#include <hip/hip_bf16.h>
#include <math.h>

#define CDIM 384
#define NHEAD 8
#define HD 48
#define OUTD 32
#define MAXB 16
#define CONVK 10368  // 27*384

typedef __bf16 bf16x8 __attribute__((ext_vector_type(8)));
typedef float f32x4 __attribute__((ext_vector_type(4)));

__device__ __forceinline__ f32x4 mfma16(bf16x8 a, bf16x8 b, f32x4 c) {
  return __builtin_amdgcn_mfma_f32_16x16x32_bf16(a, b, c, 0, 0, 0);
}
__device__ __forceinline__ bf16x8 zero8() {
  bf16x8 z = {(__bf16)0.f, (__bf16)0.f, (__bf16)0.f, (__bf16)0.f,
              (__bf16)0.f, (__bf16)0.f, (__bf16)0.f, (__bf16)0.f};
  return z;
}

// ---- order-preserving float<->uint encoding for atomicMax segment max ----
__device__ __forceinline__ unsigned enc_f(float f) {
  unsigned u = __float_as_uint(f);
  return (u & 0x80000000u) ? ~u : (u | 0x80000000u);
}
__device__ __forceinline__ float dec_f(unsigned u) {
  unsigned v = (u & 0x80000000u) ? (u ^ 0x80000000u) : ~u;
  return __uint_as_float(v);
}

// fused one-shot prep: feats->bf16, 6x W^T, Wc^T, vones, coord minmax, ebound.
__global__ __launch_bounds__(256) void prep_kernel(
    const float* __restrict__ feats, __hip_bfloat16* __restrict__ feats16, int N,
    const float* __restrict__ W_pool, const float* __restrict__ W_emb,
    const float* __restrict__ Wk, const float* __restrict__ Wv,
    const float* __restrict__ Wq, const float* __restrict__ Wo,
    __hip_bfloat16* __restrict__ Wt_pe, __hip_bfloat16* __restrict__ Wt_kv,
    __hip_bfloat16* __restrict__ Wt_q, __hip_bfloat16* __restrict__ Wt_o,
    const float* __restrict__ Wc, __hip_bfloat16* __restrict__ Wct,
    __hip_bfloat16* __restrict__ vt, int Mepad,
    const int* __restrict__ ec, const int* __restrict__ pc, int Mp, int Me,
    const int* __restrict__ bsz, int* smin, int* smax, int* ebv,
    int nbF, int nbW, int nbC, int nbV, int nbM) {
  __shared__ int lmin[MAXB * 3], lmax[MAXB * 3];
  int b = blockIdx.x;
  int t = threadIdx.x;
  if (b < nbF) {
    int v = b * 256 + t;
    if (v < N * 48) {
      float4 a0 = *reinterpret_cast<const float4*>(feats + (size_t)v * 8);
      float4 a1 = *reinterpret_cast<const float4*>(feats + (size_t)v * 8 + 4);
      __hip_bfloat16 tmp[8] = {
        __float2bfloat16(a0.x), __float2bfloat16(a0.y), __float2bfloat16(a0.z), __float2bfloat16(a0.w),
        __float2bfloat16(a1.x), __float2bfloat16(a1.y), __float2bfloat16(a1.z), __float2bfloat16(a1.w)};
      *reinterpret_cast<bf16x8*>(feats16 + (size_t)v * 8) = *reinterpret_cast<const bf16x8*>(tmp);
    }
    return;
  }
  b -= nbF;
  if (b < 6 * nbW) {  // 384x384 weight transposes (coalesced reads)
    int m = b / nbW;
    int v = (b - m * nbW) * 256 + t;
    if (v >= CDIM * 48) return;
    const float* src;
    __hip_bfloat16* dst;
    switch (m) {
      case 0: src = W_pool; dst = Wt_pe; break;
      case 1: src = W_emb;  dst = Wt_pe + (size_t)CDIM * CDIM; break;
      case 2: src = Wk;     dst = Wt_kv; break;
      case 3: src = Wv;     dst = Wt_kv + (size_t)CDIM * CDIM; break;
      case 4: src = Wq;     dst = Wt_q; break;
      default: src = Wo;    dst = Wt_o; break;
    }
    int k8i = v / CDIM;
    int n = v - k8i * CDIM;        // fast -> coalesced
    int k8 = k8i * 8;
    __hip_bfloat16 tmp[8];
    #pragma unroll
    for (int u = 0; u < 8; ++u) tmp[u] = __float2bfloat16(src[(size_t)(k8 + u) * CDIM + n]);
    *reinterpret_cast<bf16x8*>(dst + (size_t)n * CDIM + k8) = *reinterpret_cast<const bf16x8*>(tmp);
    return;
  }
  b -= 6 * nbW;
  if (b < nbC) {  // Wc [10368][32] -> Wct [32][10368]
    int v = b * 256 + t;
    if (v >= OUTD * (CONVK / 8)) return;
    int k8i = v >> 5;
    int n = v & 31;
    int k8 = k8i * 8;
    __hip_bfloat16 tmp[8];
    #pragma unroll
    for (int u = 0; u < 8; ++u) tmp[u] = __float2bfloat16(Wc[(size_t)(k8 + u) * OUTD + n]);
    *reinterpret_cast<bf16x8*>(Wct + (size_t)n * CONVK + k8) = *reinterpret_cast<const bf16x8*>(tmp);
    return;
  }
  b -= nbC;
  if (b < nbV) {  // vones
    int v = b * 256 + t;
    if (v < NHEAD * Mepad) {
      int h = v / Mepad, e = v - h * Mepad;
      vt[(size_t)(h * 64 + HD) * Mepad + e] = __float2bfloat16(1.0f);
    }
    return;
  }
  b -= nbV;
  if (b < nbM) {  // per-batch coord min/max
    if (t < MAXB * 3) { lmin[t] = 0x7fffffff; lmax[t] = (int)0x80000000; }
    __syncthreads();
    int i = b * 256 + t;
    int tot = Me + Mp;
    if (i < tot) {
      const int* r = (i < Me) ? (ec + 4 * i) : (pc + 4 * (i - Me));
      int bb = r[0];
      #pragma unroll
      for (int d = 0; d < 3; ++d) {
        atomicMin(&lmin[bb * 3 + d], r[1 + d]);
        atomicMax(&lmax[bb * 3 + d], r[1 + d]);
      }
    }
    __syncthreads();
    if (t < MAXB * 3) {
      if (lmin[t] != 0x7fffffff) atomicMin(&smin[t], lmin[t]);
      if (lmax[t] != (int)0x80000000) atomicMax(&smax[t], lmax[t]);
    }
    return;
  }
  b -= nbM;
  {  // ebound
    int e = b * 256 + t;
    if (e == 0) { ebv[0] = 0; ebv[bsz[0]] = Me; }
    if (e > 0 && e < Me) {
      int b0 = ec[4 * (e - 1)], b1 = ec[4 * e];
      for (int bb = b0 + 1; bb <= b1; ++bb) ebv[bb] = e;
    }
  }
}

// decode segment-max, add sine PE (fast hw sin/cos), emit bf16 activations
__global__ void pe_kernel(const unsigned* __restrict__ encP, const unsigned* __restrict__ encE,
                          __hip_bfloat16* __restrict__ pool16, __hip_bfloat16* __restrict__ emb16,
                          const int* __restrict__ pc, int Mp,
                          const int* __restrict__ ec, int Me,
                          const int* __restrict__ smin, const int* __restrict__ smax) {
  int gid = blockIdx.x * blockDim.x + threadIdx.x;
  int total = (Mp + Me) * CDIM;
  if (gid >= total) return;
  int row = gid / CDIM, c = gid - row * CDIM;
  const int* coords;
  const unsigned* src;
  __hip_bfloat16* dst;
  int lrow;
  if (row < Me) { lrow = row; coords = ec + 4 * row; src = encE; dst = emb16; }
  else { lrow = row - Me; coords = pc + 4 * lrow; src = encP; dst = pool16; }
  int b = coords[0];
  int dim = c >> 7;
  int i = c & 127;
  int j = i >> 1;
  float x = (float)coords[1 + dim];
  float mn = (float)smin[b * 3 + dim];
  float mx = (float)smax[b * 3 + dim];
  float nrm = (x - mn) / (mx - mn + 1e-6f);
  float freq = exp2f(-(float)j * 0.20762050593046014f);  // 10000^(-j/64)
  float arg = nrm * 6.283185307179586f * freq;
  float pe = (i & 1) ? __cosf(arg) : __sinf(arg);   // hw v_cos/v_sin; err << bf16 ulp
  float val = dec_f(src[(size_t)lrow * CDIM + c]) + pe;
  dst[(size_t)lrow * CDIM + c] = __float2bfloat16(val);
}

// Unified bf16 MFMA GEMM body. EPI semantics as before; EPI2/EPI3 n0==0
// blocks additionally zero the head-pad lanes d=48..63 (replaces memset).
template <int EPI>
__device__ __forceinline__ void mgemm_body(
    int bx, int by,
    __hip_bfloat16 (*As)[72], __hip_bfloat16 (*Bs)[72],
    const __hip_bfloat16* __restrict__ A, int M,
    const __hip_bfloat16* __restrict__ Wt,
    const float* __restrict__ bias0, const float* __restrict__ bias1,
    void* __restrict__ d0, void* __restrict__ d1,
    const int* __restrict__ inv0, const int* __restrict__ inv1,
    int Mepad) {
  const int m0 = bx * 128;
  const int n0 = by * 64;
  const int t = threadIdx.x;
  const int lane = t & 63, w = t >> 6;
  const int wr = w >> 1, wc = w & 1;
  const int lq = lane & 15, lg = lane >> 4;

  f32x4 acc[4][2];
  #pragma unroll
  for (int i = 0; i < 4; ++i) {
    acc[i][0] = (f32x4){0.f, 0.f, 0.f, 0.f};
    acc[i][1] = (f32x4){0.f, 0.f, 0.f, 0.f};
  }
  const int arow = t >> 3;
  const int acol = (t & 7) * 8;

  for (int k0 = 0; k0 < CDIM; k0 += 64) {
    #pragma unroll
    for (int i = 0; i < 4; ++i) {
      int r = arow + i * 32;
      int gr = m0 + r;
      bf16x8 val = zero8();
      if (gr < M) val = *reinterpret_cast<const bf16x8*>(A + (size_t)gr * CDIM + k0 + acol);
      *reinterpret_cast<bf16x8*>(&As[r][acol]) = val;
    }
    #pragma unroll
    for (int i = 0; i < 2; ++i) {
      int r = arow + i * 32;
      bf16x8 val = *reinterpret_cast<const bf16x8*>(Wt + (size_t)(n0 + r) * CDIM + k0 + acol);
      *reinterpret_cast<bf16x8*>(&Bs[r][acol]) = val;
    }
    __syncthreads();
    #pragma unroll
    for (int ks = 0; ks < 2; ++ks) {
      bf16x8 af[4], bfv[2];
      #pragma unroll
      for (int fm = 0; fm < 4; ++fm)
        af[fm] = *reinterpret_cast<const bf16x8*>(&As[wr * 64 + fm * 16 + lq][ks * 32 + lg * 8]);
      #pragma unroll
      for (int fn = 0; fn < 2; ++fn)
        bfv[fn] = *reinterpret_cast<const bf16x8*>(&Bs[wc * 32 + fn * 16 + lq][ks * 32 + lg * 8]);
      #pragma unroll
      for (int fm = 0; fm < 4; ++fm)
        #pragma unroll
        for (int fn = 0; fn < 2; ++fn)
          acc[fm][fn] = mfma16(af[fm], bfv[fn], acc[fm][fn]);
    }
    __syncthreads();
  }

  const bool sec = (n0 >= CDIM);
  const int nb = n0 - (sec ? CDIM : 0) + wc * 32;
  const int nA = nb + lq, nB = nb + 16 + lq;

  if (EPI == 0) {
    const float* bias = sec ? bias1 : bias0;
    unsigned* dst = (unsigned*)(sec ? d1 : d0);
    const int* inv = sec ? inv1 : inv0;
    float bA = bias[nA], bB = bias[nB];
    #pragma unroll
    for (int fm = 0; fm < 4; ++fm) {
      int rbase = m0 + wr * 64 + fm * 16 + lg * 4;
      int cs = -1;
      float mA = 0.f, mB = 0.f;
      #pragma unroll
      for (int j = 0; j < 4; ++j) {
        int r = rbase + j;
        if (r < M) {
          int s = inv[r];
          float vA = acc[fm][0][j] + bA;
          float vB = acc[fm][1][j] + bB;
          if (s == cs) { mA = fmaxf(mA, vA); mB = fmaxf(mB, vB); }
          else {
            if (cs >= 0) {
              atomicMax(&dst[(size_t)cs * CDIM + nA], enc_f(mA));
              atomicMax(&dst[(size_t)cs * CDIM + nB], enc_f(mB));
            }
            cs = s; mA = vA; mB = vB;
          }
        }
      }
      if (cs >= 0) {
        atomicMax(&dst[(size_t)cs * CDIM + nA], enc_f(mA));
        atomicMax(&dst[(size_t)cs * CDIM + nB], enc_f(mB));
      }
    }
  } else if (EPI == 1) {
    float bA = bias0[nA], bB = bias0[nB];
    float* dst = (float*)d0;
    #pragma unroll
    for (int fm = 0; fm < 4; ++fm)
      #pragma unroll
      for (int j = 0; j < 4; ++j) {
        int r = m0 + wr * 64 + fm * 16 + lg * 4 + j;
        if (r < M) {
          dst[(size_t)r * CDIM + nA] = acc[fm][0][j] + bA;
          dst[(size_t)r * CDIM + nB] = acc[fm][1][j] + bB;
        }
      }
  } else if (EPI == 2) {
    // scale = log2(e)/sqrt(48): softmax via exp2 (exact rewrite)
    const float scale = 0.2082350914f;
    float bA = bias0[nA], bB = bias0[nB];
    int hA = nA / HD, dA = nA - hA * HD;
    int hB = nB / HD, dB = nB - hB * HD;
    __hip_bfloat16* dst = (__hip_bfloat16*)d0;
    #pragma unroll
    for (int fm = 0; fm < 4; ++fm)
      #pragma unroll
      for (int j = 0; j < 4; ++j) {
        int r = m0 + wr * 64 + fm * 16 + lg * 4 + j;
        if (r < M) {
          dst[(size_t)r * 512 + hA * 64 + dA] = __float2bfloat16((acc[fm][0][j] + bA) * scale);
          dst[(size_t)r * 512 + hB * 64 + dB] = __float2bfloat16((acc[fm][1][j] + bB) * scale);
        }
      }
  } else {  // EPI 3
    if (!sec) {
      float bA = bias0[nA], bB = bias0[nB];
      int hA = nA / HD, dA = nA - hA * HD;
      int hB = nB / HD, dB = nB - hB * HD;
      __hip_bfloat16* dst = (__hip_bfloat16*)d0;
      #pragma unroll
      for (int fm = 0; fm < 4; ++fm)
        #pragma unroll
        for (int j = 0; j < 4; ++j) {
          int r = m0 + wr * 64 + fm * 16 + lg * 4 + j;
          if (r < M) {
            dst[(size_t)r * 512 + hA * 64 + dA] = __float2bfloat16(acc[fm][0][j] + bA);
            dst[(size_t)r * 512 + hB * 64 + dB] = __float2bfloat16(acc[fm][1][j] + bB);
          }
        }
    } else {
      float bA = bias1[nA], bB = bias1[nB];
      int hA = nA / HD, dA = nA - hA * HD;
      int hB = nB / HD, dB = nB - hB * HD;
      __hip_bfloat16* dst = (__hip_bfloat16*)d1;
      #pragma unroll
      for (int fm = 0; fm < 4; ++fm)
        #pragma unroll
        for (int j = 0; j < 4; ++j) {
          int r = m0 + wr * 64 + fm * 16 + lg * 4 + j;
          if (r < M) {
            dst[(size_t)(hA * 64 + dA) * Mepad + r] = __float2bfloat16(acc[fm][0][j] + bA);
            dst[(size_t)(hB * 64 + dB) * Mepad + r] = __float2bfloat16(acc[fm][1][j] + bB);
          }
        }
    }
  }
  // pad-zero for q16/k16 head lanes d=48..63 (replaces the 12MB memset).
  // Pad addresses are disjoint from data lanes -> no inter-block race.
  if ((EPI == 2 || EPI == 3) && n0 == 0) {
    __hip_bfloat16* dst = (__hip_bfloat16*)d0;
    for (int c = t; c < 1024; c += 256) {
      int r = m0 + (c >> 3);
      int hh = c & 7;
      if (r < M) {
        bf16x8 z = zero8();
        *reinterpret_cast<bf16x8*>(dst + (size_t)r * 512 + hh * 64 + 48) = z;
        *reinterpret_cast<bf16x8*>(dst + (size_t)r * 512 + hh * 64 + 56) = z;
      }
    }
  }
}

__global__ __launch_bounds__(256) void mgemm0_kernel(
    const __hip_bfloat16* __restrict__ A, int M, const __hip_bfloat16* __restrict__ Wt,
    const float* __restrict__ bias0, const float* __restrict__ bias1,
    unsigned* __restrict__ d0, unsigned* __restrict__ d1,
    const int* __restrict__ inv0, const int* __restrict__ inv1) {
  __shared__ __align__(16) __hip_bfloat16 As[128][72];
  __shared__ __align__(16) __hip_bfloat16 Bs[64][72];
  mgemm_body<0>(blockIdx.x, blockIdx.y, As, Bs, A, M, Wt, bias0, bias1, d0, d1, inv0, inv1, 0);
}

__global__ __launch_bounds__(256) void mgemm1_kernel(
    const __hip_bfloat16* __restrict__ A, int M, const __hip_bfloat16* __restrict__ Wt,
    const float* __restrict__ bias0, float* __restrict__ d0) {
  __shared__ __align__(16) __hip_bfloat16 As[128][72];
  __shared__ __align__(16) __hip_bfloat16 Bs[64][72];
  mgemm_body<1>(blockIdx.x, blockIdx.y, As, Bs, A, M, Wt, bias0, nullptr, d0, nullptr, nullptr, nullptr, 0);
}

// horizontally fused q-projection (EPI2) + kv-projection (EPI3)
__global__ __launch_bounds__(256) void qkv_kernel(
    const __hip_bfloat16* __restrict__ pool16, int Mp, const __hip_bfloat16* __restrict__ Wt_q,
    const float* __restrict__ bq,
    const __hip_bfloat16* __restrict__ emb16, int Me, const __hip_bfloat16* __restrict__ Wt_kv,
    const float* __restrict__ bk, const float* __restrict__ bv,
    __hip_bfloat16* __restrict__ q16, __hip_bfloat16* __restrict__ k16,
    __hip_bfloat16* __restrict__ vt, int Mepad, int nbQ, int gxQ, int gxK) {
  __shared__ __align__(16) __hip_bfloat16 As[128][72];
  __shared__ __align__(16) __hip_bfloat16 Bs[64][72];
  int b = blockIdx.x;
  if (b < nbQ) {
    mgemm_body<2>(b % gxQ, b / gxQ, As, Bs, pool16, Mp, Wt_q, bq, nullptr,
                  q16, nullptr, nullptr, nullptr, 0);
  } else {
    b -= nbQ;
    mgemm_body<3>(b % gxK, b / gxK, As, Bs, emb16, Me, Wt_kv, bk, bv,
                  k16, vt, nullptr, nullptr, Mepad);
  }
}

// MFMA flash attention, round 9: double-buffered LDS K/V -> ONE barrier/iter.
// Schedule per iter: {barrier; write tile i+1 to buf[(i+1)&1]; prefetch i+2;
// compute tile i from buf[i&1]}. Writes overlap other waves' reads.
__global__ __launch_bounds__(256) void attn_mfma_kernel(
    const __hip_bfloat16* __restrict__ qb, const __hip_bfloat16* __restrict__ kb,
    const __hip_bfloat16* __restrict__ vt, int Mepad,
    const int* __restrict__ pc, const int* __restrict__ eb,
    int Mp, int Me, __hip_bfloat16* __restrict__ ob) {
  __shared__ __align__(16) __hip_bfloat16 Ks[2][64][72];
  __shared__ __align__(16) __hip_bfloat16 Vs[2][64][72];
  __shared__ __align__(16) __hip_bfloat16 pl[4][16][72];
  __shared__ int sred[4][4];
  const int h = blockIdx.y;
  const int t = threadIdx.x;
  const int wv = t >> 6, lane = t & 63;
  const int lq = lane & 15, lg = lane >> 4;
  const int q0 = blockIdx.x * 64 + wv * 16;

  int lo[4], hi[4];
  #pragma unroll
  for (int r = 0; r < 4; ++r) {
    int q = q0 + lg * 4 + r;
    if (q < Mp) { int b = pc[4 * q]; lo[r] = eb[b]; hi[r] = eb[b + 1]; }
    else { lo[r] = 0x7fffffff; hi[r] = 0; }
  }
  int lomin = min(min(lo[0], lo[1]), min(lo[2], lo[3]));
  int lomax = max(max(lo[0], lo[1]), max(lo[2], lo[3]));
  int himin = min(min(hi[0], hi[1]), min(hi[2], hi[3]));
  int himax = max(max(hi[0], hi[1]), max(hi[2], hi[3]));
  #pragma unroll
  for (int off = 1; off < 64; off <<= 1) {
    lomin = min(lomin, __shfl_xor(lomin, off));
    lomax = max(lomax, __shfl_xor(lomax, off));
    himin = min(himin, __shfl_xor(himin, off));
    himax = max(himax, __shfl_xor(himax, off));
  }
  if (lane == 0) {
    sred[wv][0] = lomin; sred[wv][1] = lomax;
    sred[wv][2] = himin; sred[wv][3] = himax;
  }
  __syncthreads();
  lomin = min(min(sred[0][0], sred[1][0]), min(sred[2][0], sred[3][0]));
  lomax = max(max(sred[0][1], sred[1][1]), max(sred[2][1], sred[3][1]));
  himin = min(min(sred[0][2], sred[1][2]), min(sred[2][2], sred[3][2]));
  himax = max(max(sred[0][3], sred[1][3]), max(sred[2][3], sred[3][3]));

  int qrow = min(q0 + lq, Mp - 1);
  const __hip_bfloat16* qp = qb + (size_t)qrow * 512 + h * 64 + lg * 8;
  bf16x8 aq0 = *reinterpret_cast<const bf16x8*>(qp);
  bf16x8 aq1 = *reinterpret_cast<const bf16x8*>(qp + 32);

  const int str = t >> 2;
  const int stc = (t & 3) * 16;
  const __hip_bfloat16* vrow = vt + (size_t)(h * 64 + str) * Mepad + stc;

  f32x4 zero = {0.f, 0.f, 0.f, 0.f};
  f32x4 oacc[4];
  oacc[0] = zero; oacc[1] = zero; oacc[2] = zero; oacc[3] = zero;

  bf16x8 k0, k1, v0, v1;
  auto load_tile = [&](int e0) {
    int er = e0 + str;
    k0 = zero8(); k1 = zero8();
    if (er < Me) {
      const __hip_bfloat16* kp = kb + (size_t)er * 512 + h * 64 + stc;
      k0 = *reinterpret_cast<const bf16x8*>(kp);
      k1 = *reinterpret_cast<const bf16x8*>(kp + 8);
    }
    v0 = *reinterpret_cast<const bf16x8*>(vrow + e0);
    v1 = *reinterpret_cast<const bf16x8*>(vrow + e0 + 8);
  };
  auto store_tile = [&](int nb) {
    *reinterpret_cast<bf16x8*>(&Ks[nb][str][stc]) = k0;
    *reinterpret_cast<bf16x8*>(&Ks[nb][str][stc + 8]) = k1;
    *reinterpret_cast<bf16x8*>(&Vs[nb][str][stc]) = v0;
    *reinterpret_cast<bf16x8*>(&Vs[nb][str][stc + 8]) = v1;
  };
  const int e0beg = lomin & ~63;
  load_tile(e0beg);
  store_tile(0);
  if (e0beg + 64 < himax) load_tile(e0beg + 64);

  int it = 0;
  for (int e0 = e0beg; e0 < himax; e0 += 64, ++it) {
    __syncthreads();   // makes buf[cur] writes visible; all prior reads done
    const int cur = it & 1;
    if (e0 + 64 < himax) {
      store_tile(cur ^ 1);                      // write tile i+1 (overlaps reads)
      if (e0 + 128 < himax) load_tile(e0 + 128);  // prefetch tile i+2
    }

    f32x4 sf[4];
    #pragma unroll
    for (int s = 0; s < 4; ++s) {
      bf16x8 bk0 = *reinterpret_cast<const bf16x8*>(&Ks[cur][s * 16 + lq][lg * 8]);
      bf16x8 bk1 = *reinterpret_cast<const bf16x8*>(&Ks[cur][s * 16 + lq][32 + lg * 8]);
      f32x4 z = zero;
      z = mfma16(aq0, bk0, z);
      z = mfma16(aq1, bk1, z);
      sf[s] = z;
    }
    const bool interior = (e0 >= lomax) && (e0 + 64 <= himin);
    if (interior) {
      #pragma unroll
      for (int s = 0; s < 4; ++s)
        #pragma unroll
        for (int r = 0; r < 4; ++r)
          pl[wv][lg * 4 + r][s * 16 + lq] = __float2bfloat16(exp2f(sf[s][r]));
    } else {
      #pragma unroll
      for (int s = 0; s < 4; ++s) {
        int e = e0 + s * 16 + lq;
        #pragma unroll
        for (int r = 0; r < 4; ++r) {
          bool m = (e >= lo[r]) && (e < hi[r]);
          float p = m ? exp2f(sf[s][r]) : 0.f;
          pl[wv][lg * 4 + r][s * 16 + lq] = __float2bfloat16(p);
        }
      }
    }
    asm volatile("s_waitcnt lgkmcnt(0)" ::: "memory");
    __builtin_amdgcn_sched_barrier(0);  // rule #18
    #pragma unroll
    for (int ks = 0; ks < 2; ++ks) {
      bf16x8 ap = *reinterpret_cast<const bf16x8*>(&pl[wv][lq][ks * 32 + lg * 8]);
      #pragma unroll
      for (int dt = 0; dt < 4; ++dt) {
        bf16x8 bv = *reinterpret_cast<const bf16x8*>(&Vs[cur][dt * 16 + lq][ks * 32 + lg * 8]);
        oacc[dt] = mfma16(ap, bv, oacc[dt]);
      }
    }
  }

  #pragma unroll
  for (int r = 0; r < 4; ++r) {
    float l = __shfl(oacc[3][r], (lane & 48));
    int q = q0 + lg * 4 + r;
    if (q < Mp && l > 0.f) {
      float inv = 1.0f / l;
      __hip_bfloat16* op = ob + (size_t)q * CDIM + h * HD;
      op[lq]      = __float2bfloat16(oacc[0][r] * inv);
      op[16 + lq] = __float2bfloat16(oacc[1][r] * inv);
      op[32 + lq] = __float2bfloat16(oacc[2][r] * inv);
    }
  }
}

__global__ void newf16_kernel(const float* __restrict__ feats, const float* __restrict__ o2,
                              const int* __restrict__ pinv, __hip_bfloat16* __restrict__ nf,
                              int N) {
  int v = blockIdx.x * 256 + threadIdx.x;
  if (v >= N * 48) return;
  int n = v / 48, c8 = (v - n * 48) * 8;
  const float* fp = feats + (size_t)n * CDIM + c8;
  const float* op = o2 + (size_t)pinv[n] * CDIM + c8;
  float4 a0 = *reinterpret_cast<const float4*>(fp);
  float4 a1 = *reinterpret_cast<const float4*>(fp + 4);
  float4 b0 = *reinterpret_cast<const float4*>(op);
  float4 b1 = *reinterpret_cast<const float4*>(op + 4);
  __hip_bfloat16 tmp[8] = {
    __float2bfloat16(a0.x + b0.x), __float2bfloat16(a0.y + b0.y),
    __float2bfloat16(a0.z + b0.z), __float2bfloat16(a0.w + b0.w),
    __float2bfloat16(a1.x + b1.x), __float2bfloat16(a1.y + b1.y),
    __float2bfloat16(a1.z + b1.z), __float2bfloat16(a1.w + b1.w)};
  *reinterpret_cast<bf16x8*>(nf + (size_t)v * 8) = *reinterpret_cast<const bf16x8*>(tmp);
}

// conv as MFMA GEMM: M=N rows, 32 cols, K split by tap groups (9 x 3 taps).
__global__ __launch_bounds__(256) void mconv_kernel(
    const __hip_bfloat16* __restrict__ nf, const int* __restrict__ nbr,
    const __hip_bfloat16* __restrict__ Wct, float* __restrict__ outp, int N) {
  __shared__ __align__(16) __hip_bfloat16 As[128][72];
  __shared__ __align__(16) __hip_bfloat16 Bs[32][72];
  __shared__ int jrow[128];
  const int n0 = blockIdx.x * 128;
  const int kg = blockIdx.y;
  const int t = threadIdx.x;
  const int lane = t & 63, w = t >> 6;
  const int lq = lane & 15, lg = lane >> 4;
  f32x4 acc[2][2];
  acc[0][0] = (f32x4){0.f,0.f,0.f,0.f}; acc[0][1] = acc[0][0];
  acc[1][0] = acc[0][0]; acc[1][1] = acc[0][0];
  const int arow = t >> 3, acol = (t & 7) * 8;

  for (int kk = kg * 3; kk < kg * 3 + 3; ++kk) {
    __syncthreads();
    if (t < 128) {
      int n = n0 + t;
      jrow[t] = (n < N) ? nbr[(size_t)n * 27 + kk] : -1;
    }
    __syncthreads();
    for (int c0 = 0; c0 < CDIM; c0 += 64) {
      #pragma unroll
      for (int i = 0; i < 4; ++i) {
        int r = arow + i * 32;
        int j = jrow[r];
        bf16x8 val = zero8();
        if (j >= 0) val = *reinterpret_cast<const bf16x8*>(nf + (size_t)j * CDIM + c0 + acol);
        *reinterpret_cast<bf16x8*>(&As[r][acol]) = val;
      }
      {
        int r = t >> 3;
        bf16x8 val = *reinterpret_cast<const bf16x8*>(Wct + (size_t)r * CONVK + kk * CDIM + c0 + acol);
        *reinterpret_cast<bf16x8*>(&Bs[r][acol]) = val;
      }
      __syncthreads();
      #pragma unroll
      for (int ks = 0; ks < 2; ++ks) {
        bf16x8 af[2], bfv[2];
        #pragma unroll
        for (int fm = 0; fm < 2; ++fm)
          af[fm] = *reinterpret_cast<const bf16x8*>(&As[w * 32 + fm * 16 + lq][ks * 32 + lg * 8]);
        #pragma unroll
        for (int fn = 0; fn < 2; ++fn)
          bfv[fn] = *reinterpret_cast<const bf16x8*>(&Bs[fn * 16 + lq][ks * 32 + lg * 8]);
        #pragma unroll
        for (int fm = 0; fm < 2; ++fm)
          #pragma unroll
          for (int fn = 0; fn < 2; ++fn)
            acc[fm][fn] = mfma16(af[fm], bfv[fn], acc[fm][fn]);
      }
      __syncthreads();
    }
  }
  #pragma unroll
  for (int fm = 0; fm < 2; ++fm)
    #pragma unroll
    for (int j = 0; j < 4; ++j) {
      int r = n0 + w * 32 + fm * 16 + lg * 4 + j;
      if (r < N) {
        #pragma unroll
        for (int fn = 0; fn < 2; ++fn)
          outp[((size_t)kg * N + r) * OUTD + fn * 16 + lq] = acc[fm][fn][j];
      }
    }
}

__global__ void conv_reduce_kernel(const float* __restrict__ outp,
                                   const float* __restrict__ bc,
                                   float* __restrict__ out, int N) {
  int v = blockIdx.x * 256 + threadIdx.x;
  if (v >= N * OUTD) return;
  int oo = v & (OUTD - 1);
  float s = bc[oo];
  #pragma unroll
  for (int kg = 0; kg < 9; ++kg) s += outp[(size_t)kg * N * OUTD + v];
  out[v] = s;
}

extern "C" void kernel_launch(void* const* d_in, const int* in_sizes, int n_in,
                              void* d_out, int out_size, void* d_ws, size_t ws_size,
                              hipStream_t stream) {
  const float* feats  = (const float*)d_in[0];
  const float* W_pool = (const float*)d_in[1];
  const float* b_pool = (const float*)d_in[2];
  const float* W_emb  = (const float*)d_in[3];
  const float* b_emb  = (const float*)d_in[4];
  const float* Wq = (const float*)d_in[5];  const float* bq = (const float*)d_in[6];
  const float* Wk = (const float*)d_in[7];  const float* bk = (const float*)d_in[8];
  const float* Wv = (const float*)d_in[9];  const float* bv = (const float*)d_in[10];
  const float* Wo = (const float*)d_in[11]; const float* bo = (const float*)d_in[12];
  const float* Wc = (const float*)d_in[13]; const float* bc = (const float*)d_in[14];
  const int* pool_inv    = (const int*)d_in[15];
  const int* pool_coords = (const int*)d_in[16];
  const int* emb_inv     = (const int*)d_in[17];
  const int* emb_coords  = (const int*)d_in[18];
  const int* nbr         = (const int*)d_in[19];
  const int* bsz         = (const int*)d_in[20];
  int N  = in_sizes[0] / CDIM;
  int Mp = in_sizes[16] / 4;
  int Me = in_sizes[18] / 4;
  int Mepad = ((Me >> 6) + 2) << 6;

  char* wsb = (char*)d_ws;
  size_t off = 0;
  auto alloc = [&](size_t bytes) { void* p = wsb + off; off += (bytes + 255) & ~(size_t)255; return p; };
  unsigned* encA = (unsigned*)alloc((size_t)Mp * CDIM * 4);
  unsigned* encB = (unsigned*)alloc((size_t)Me * CDIM * 4);
  __hip_bfloat16* vt = (__hip_bfloat16*)alloc((size_t)512 * Mepad * 2);
  size_t zspan1 = off;
  __hip_bfloat16* pool16  = (__hip_bfloat16*)alloc((size_t)Mp * CDIM * 2);
  __hip_bfloat16* emb16   = (__hip_bfloat16*)alloc((size_t)Me * CDIM * 2);
  __hip_bfloat16* feats16 = (__hip_bfloat16*)alloc((size_t)N * CDIM * 2);
  float* o2 = (float*)alloc((size_t)Mp * CDIM * 4 > (size_t)9 * N * OUTD * 4
                                ? (size_t)Mp * CDIM * 4 : (size_t)9 * N * OUTD * 4);
  __hip_bfloat16* Wt_pe = (__hip_bfloat16*)alloc((size_t)768 * CDIM * 2);
  __hip_bfloat16* Wt_kv = (__hip_bfloat16*)alloc((size_t)768 * CDIM * 2);
  __hip_bfloat16* Wt_q  = (__hip_bfloat16*)alloc((size_t)CDIM * CDIM * 2);
  __hip_bfloat16* Wt_o  = (__hip_bfloat16*)alloc((size_t)CDIM * CDIM * 2);
  __hip_bfloat16* Wct   = (__hip_bfloat16*)alloc((size_t)OUTD * CONVK * 2);
  int* smin = (int*)alloc(MAXB * 3 * 4);
  int* smax = (int*)alloc(MAXB * 3 * 4);
  int* eb   = (int*)alloc((MAXB + 1) * 4);

  __hip_bfloat16* q16  = (__hip_bfloat16*)encA;   // [Mp][512]
  __hip_bfloat16* k16  = (__hip_bfloat16*)encB;   // [Me][512]
  __hip_bfloat16* ob16 = pool16;                  // [Mp][384]
  __hip_bfloat16* newf16 = feats16;               // [N][384]
  float* outp = o2;                               // [9][N][32]

  hipMemsetAsync(wsb, 0, zspan1, stream);
  hipMemsetAsync(smin, 0x7f, MAXB * 3 * 4, stream);
  hipMemsetAsync(smax, 0x80, MAXB * 3 * 4, stream);

  int nbF = (N * 48 + 255) / 256;
  int nbW = (CDIM * 48 + 255) / 256;
  int nbC = (OUTD * (CONVK / 8) + 255) / 256;
  int nbV = (NHEAD * Mepad + 255) / 256;
  int nbM = (Mp + Me + 255) / 256;
  int nbE = (Me + 255) / 256;
  prep_kernel<<<nbF + 6 * nbW + nbC + nbV + nbM + nbE, 256, 0, stream>>>(
      feats, feats16, N, W_pool, W_emb, Wk, Wv, Wq, Wo,
      Wt_pe, Wt_kv, Wt_q, Wt_o, Wc, Wct, vt, Mepad,
      emb_coords, pool_coords, Mp, Me, bsz, smin, smax, eb,
      nbF, nbW, nbC, nbV, nbM);

  mgemm0_kernel<<<dim3((N + 127) / 128, 12), 256, 0, stream>>>(
      feats16, N, Wt_pe, b_pool, b_emb, encA, encB, pool_inv, emb_inv);
  pe_kernel<<<((Mp + Me) * CDIM + 255) / 256, 256, 0, stream>>>(
      encA, encB, pool16, emb16, pool_coords, Mp, emb_coords, Me, smin, smax);

  // fused q + kv projections (pads zeroed in-kernel; no memset needed)
  {
    int gxQ = (Mp + 127) / 128, gxK = (Me + 127) / 128;
    int nbQ = gxQ * 6;
    qkv_kernel<<<nbQ + gxK * 12, 256, 0, stream>>>(
        pool16, Mp, Wt_q, bq, emb16, Me, Wt_kv, bk, bv,
        q16, k16, vt, Mepad, nbQ, gxQ, gxK);
  }

  attn_mfma_kernel<<<dim3((Mp + 63) / 64, NHEAD), 256, 0, stream>>>(
      q16, k16, vt, Mepad, pool_coords, eb, Mp, Me, ob16);

  mgemm1_kernel<<<dim3((Mp + 127) / 128, 6), 256, 0, stream>>>(
      ob16, Mp, Wt_o, bo, o2);

  newf16_kernel<<<(N * 48 + 255) / 256, 256, 0, stream>>>(feats, o2, pool_inv, newf16, N);

  mconv_kernel<<<dim3((N + 127) / 128, 9), 256, 0, stream>>>(newf16, nbr, Wct, outp, N);
  conv_reduce_kernel<<<(N * OUTD + 255) / 256, 256, 0, stream>>>(outp, bc, (float*)d_out, N);
}

// Round 10
// 158.871 us; speedup vs baseline: 11.2763x; 1.0298x over previous
//
#include <hip/hip_runtime.h>
#include <hip/hip_bf16.h>
#include <math.h>

#define CDIM 384
#define NHEAD 8
#define HD 48
#define OUTD 32
#define MAXB 16
#define CONVK 10368  // 27*384

typedef __bf16 bf16x8 __attribute__((ext_vector_type(8)));
typedef float f32x4 __attribute__((ext_vector_type(4)));

__device__ __forceinline__ f32x4 mfma16(bf16x8 a, bf16x8 b, f32x4 c) {
  return __builtin_amdgcn_mfma_f32_16x16x32_bf16(a, b, c, 0, 0, 0);
}
__device__ __forceinline__ bf16x8 zero8() {
  bf16x8 z = {(__bf16)0.f, (__bf16)0.f, (__bf16)0.f, (__bf16)0.f,
              (__bf16)0.f, (__bf16)0.f, (__bf16)0.f, (__bf16)0.f};
  return z;
}

// ---- order-preserving float<->uint encoding for atomicMax segment max ----
__device__ __forceinline__ unsigned enc_f(float f) {
  unsigned u = __float_as_uint(f);
  return (u & 0x80000000u) ? ~u : (u | 0x80000000u);
}
__device__ __forceinline__ float dec_f(unsigned u) {
  unsigned v = (u & 0x80000000u) ? (u ^ 0x80000000u) : ~u;
  return __uint_as_float(v);
}

// tiny init (replaces 2 rocclr fills): smin/smax sentinels + eb zeros
__global__ void init_small_kernel(int* smin, int* smax, int* eb) {
  int t = threadIdx.x;
  if (t < MAXB * 3) { smin[t] = 0x7fffffff; smax[t] = (int)0x80000000; }
  if (t <= MAXB) eb[t] = 0;
}

// fused one-shot prep: feats->bf16, 6x W^T, Wc^T, zero encA/encB, vt init
// (0 everywhere, ones-row at d=48), coord minmax, ebound.
// Replaces ALL hipMemsetAsync in the graph (rocclr fill kernels measured
// ~40us each at ~8% occupancy in round 9 — 25% of total runtime).
__global__ __launch_bounds__(256) void prep_kernel(
    const float* __restrict__ feats, __hip_bfloat16* __restrict__ feats16, int N,
    const float* __restrict__ W_pool, const float* __restrict__ W_emb,
    const float* __restrict__ Wk, const float* __restrict__ Wv,
    const float* __restrict__ Wq, const float* __restrict__ Wo,
    __hip_bfloat16* __restrict__ Wt_pe, __hip_bfloat16* __restrict__ Wt_kv,
    __hip_bfloat16* __restrict__ Wt_q, __hip_bfloat16* __restrict__ Wt_o,
    const float* __restrict__ Wc, __hip_bfloat16* __restrict__ Wct,
    unsigned* __restrict__ encA, unsigned* __restrict__ encB,
    __hip_bfloat16* __restrict__ vt, int Mepad,
    const int* __restrict__ ec, const int* __restrict__ pc, int Mp, int Me,
    const int* __restrict__ bsz, int* smin, int* smax, int* ebv,
    int nbF, int nbW, int nbC, int nbZA, int nbZB, int nbVt, int nbM) {
  __shared__ int lmin[MAXB * 3], lmax[MAXB * 3];
  int b = blockIdx.x;
  int t = threadIdx.x;
  if (b < nbF) {  // feats -> bf16
    int v = b * 256 + t;
    if (v < N * 48) {
      float4 a0 = *reinterpret_cast<const float4*>(feats + (size_t)v * 8);
      float4 a1 = *reinterpret_cast<const float4*>(feats + (size_t)v * 8 + 4);
      __hip_bfloat16 tmp[8] = {
        __float2bfloat16(a0.x), __float2bfloat16(a0.y), __float2bfloat16(a0.z), __float2bfloat16(a0.w),
        __float2bfloat16(a1.x), __float2bfloat16(a1.y), __float2bfloat16(a1.z), __float2bfloat16(a1.w)};
      *reinterpret_cast<bf16x8*>(feats16 + (size_t)v * 8) = *reinterpret_cast<const bf16x8*>(tmp);
    }
    return;
  }
  b -= nbF;
  if (b < 6 * nbW) {  // 384x384 weight transposes (coalesced reads)
    int m = b / nbW;
    int v = (b - m * nbW) * 256 + t;
    if (v >= CDIM * 48) return;
    const float* src;
    __hip_bfloat16* dst;
    switch (m) {
      case 0: src = W_pool; dst = Wt_pe; break;
      case 1: src = W_emb;  dst = Wt_pe + (size_t)CDIM * CDIM; break;
      case 2: src = Wk;     dst = Wt_kv; break;
      case 3: src = Wv;     dst = Wt_kv + (size_t)CDIM * CDIM; break;
      case 4: src = Wq;     dst = Wt_q; break;
      default: src = Wo;    dst = Wt_o; break;
    }
    int k8i = v / CDIM;
    int n = v - k8i * CDIM;        // fast -> coalesced
    int k8 = k8i * 8;
    __hip_bfloat16 tmp[8];
    #pragma unroll
    for (int u = 0; u < 8; ++u) tmp[u] = __float2bfloat16(src[(size_t)(k8 + u) * CDIM + n]);
    *reinterpret_cast<bf16x8*>(dst + (size_t)n * CDIM + k8) = *reinterpret_cast<const bf16x8*>(tmp);
    return;
  }
  b -= 6 * nbW;
  if (b < nbC) {  // Wc [10368][32] -> Wct [32][10368]
    int v = b * 256 + t;
    if (v >= OUTD * (CONVK / 8)) return;
    int k8i = v >> 5;
    int n = v & 31;
    int k8 = k8i * 8;
    __hip_bfloat16 tmp[8];
    #pragma unroll
    for (int u = 0; u < 8; ++u) tmp[u] = __float2bfloat16(Wc[(size_t)(k8 + u) * OUTD + n]);
    *reinterpret_cast<bf16x8*>(Wct + (size_t)n * CONVK + k8) = *reinterpret_cast<const bf16x8*>(tmp);
    return;
  }
  b -= nbC;
  if (b < nbZA) {  // zero encA (enc(-inf) floor), 16B/thread
    size_t v = (size_t)b * 256 + t;
    if (v < (size_t)Mp * 96) {
      uint4 z = {0u, 0u, 0u, 0u};
      reinterpret_cast<uint4*>(encA)[v] = z;
    }
    return;
  }
  b -= nbZA;
  if (b < nbZB) {  // zero encB
    size_t v = (size_t)b * 256 + t;
    if (v < (size_t)Me * 96) {
      uint4 z = {0u, 0u, 0u, 0u};
      reinterpret_cast<uint4*>(encB)[v] = z;
    }
    return;
  }
  b -= nbZB;
  if (b < nbVt) {  // vt init: 0 everywhere, 1.0 on d=48 row of each head
    int v = b * 256 + t;
    int g = Mepad >> 3;
    if (v < 512 * g) {
      int row = v / g;
      int c8 = (v - row * g) * 8;
      __hip_bfloat16 bv = __float2bfloat16(((row & 63) == HD) ? 1.0f : 0.0f);
      __hip_bfloat16 tmp[8] = {bv, bv, bv, bv, bv, bv, bv, bv};
      *reinterpret_cast<bf16x8*>(vt + (size_t)row * Mepad + c8) =
          *reinterpret_cast<const bf16x8*>(tmp);
    }
    return;
  }
  b -= nbVt;
  if (b < nbM) {  // per-batch coord min/max (smin/smax pre-set by init_small)
    if (t < MAXB * 3) { lmin[t] = 0x7fffffff; lmax[t] = (int)0x80000000; }
    __syncthreads();
    int i = b * 256 + t;
    int tot = Me + Mp;
    if (i < tot) {
      const int* r = (i < Me) ? (ec + 4 * i) : (pc + 4 * (i - Me));
      int bb = r[0];
      #pragma unroll
      for (int d = 0; d < 3; ++d) {
        atomicMin(&lmin[bb * 3 + d], r[1 + d]);
        atomicMax(&lmax[bb * 3 + d], r[1 + d]);
      }
    }
    __syncthreads();
    if (t < MAXB * 3) {
      if (lmin[t] != 0x7fffffff) atomicMin(&smin[t], lmin[t]);
      if (lmax[t] != (int)0x80000000) atomicMax(&smax[t], lmax[t]);
    }
    return;
  }
  b -= nbM;
  {  // ebound
    int e = b * 256 + t;
    if (e == 0) { ebv[0] = 0; ebv[bsz[0]] = Me; }
    if (e > 0 && e < Me) {
      int b0 = ec[4 * (e - 1)], b1 = ec[4 * e];
      for (int bb = b0 + 1; bb <= b1; ++bb) ebv[bb] = e;
    }
  }
}

// decode segment-max, add sine PE (fast hw sin/cos), emit bf16 activations
__global__ void pe_kernel(const unsigned* __restrict__ encP, const unsigned* __restrict__ encE,
                          __hip_bfloat16* __restrict__ pool16, __hip_bfloat16* __restrict__ emb16,
                          const int* __restrict__ pc, int Mp,
                          const int* __restrict__ ec, int Me,
                          const int* __restrict__ smin, const int* __restrict__ smax) {
  int gid = blockIdx.x * blockDim.x + threadIdx.x;
  int total = (Mp + Me) * CDIM;
  if (gid >= total) return;
  int row = gid / CDIM, c = gid - row * CDIM;
  const int* coords;
  const unsigned* src;
  __hip_bfloat16* dst;
  int lrow;
  if (row < Me) { lrow = row; coords = ec + 4 * row; src = encE; dst = emb16; }
  else { lrow = row - Me; coords = pc + 4 * lrow; src = encP; dst = pool16; }
  int b = coords[0];
  int dim = c >> 7;
  int i = c & 127;
  int j = i >> 1;
  float x = (float)coords[1 + dim];
  float mn = (float)smin[b * 3 + dim];
  float mx = (float)smax[b * 3 + dim];
  float nrm = (x - mn) / (mx - mn + 1e-6f);
  float freq = exp2f(-(float)j * 0.20762050593046014f);  // 10000^(-j/64)
  float arg = nrm * 6.283185307179586f * freq;
  float pe = (i & 1) ? __cosf(arg) : __sinf(arg);   // hw v_cos/v_sin; err << bf16 ulp
  float val = dec_f(src[(size_t)lrow * CDIM + c]) + pe;
  dst[(size_t)lrow * CDIM + c] = __float2bfloat16(val);
}

// Unified bf16 MFMA GEMM body. EPI2/EPI3 n0==0 blocks zero head-pad lanes.
template <int EPI>
__device__ __forceinline__ void mgemm_body(
    int bx, int by,
    __hip_bfloat16 (*As)[72], __hip_bfloat16 (*Bs)[72],
    const __hip_bfloat16* __restrict__ A, int M,
    const __hip_bfloat16* __restrict__ Wt,
    const float* __restrict__ bias0, const float* __restrict__ bias1,
    void* __restrict__ d0, void* __restrict__ d1,
    const int* __restrict__ inv0, const int* __restrict__ inv1,
    int Mepad) {
  const int m0 = bx * 128;
  const int n0 = by * 64;
  const int t = threadIdx.x;
  const int lane = t & 63, w = t >> 6;
  const int wr = w >> 1, wc = w & 1;
  const int lq = lane & 15, lg = lane >> 4;

  f32x4 acc[4][2];
  #pragma unroll
  for (int i = 0; i < 4; ++i) {
    acc[i][0] = (f32x4){0.f, 0.f, 0.f, 0.f};
    acc[i][1] = (f32x4){0.f, 0.f, 0.f, 0.f};
  }
  const int arow = t >> 3;
  const int acol = (t & 7) * 8;

  for (int k0 = 0; k0 < CDIM; k0 += 64) {
    #pragma unroll
    for (int i = 0; i < 4; ++i) {
      int r = arow + i * 32;
      int gr = m0 + r;
      bf16x8 val = zero8();
      if (gr < M) val = *reinterpret_cast<const bf16x8*>(A + (size_t)gr * CDIM + k0 + acol);
      *reinterpret_cast<bf16x8*>(&As[r][acol]) = val;
    }
    #pragma unroll
    for (int i = 0; i < 2; ++i) {
      int r = arow + i * 32;
      bf16x8 val = *reinterpret_cast<const bf16x8*>(Wt + (size_t)(n0 + r) * CDIM + k0 + acol);
      *reinterpret_cast<bf16x8*>(&Bs[r][acol]) = val;
    }
    __syncthreads();
    #pragma unroll
    for (int ks = 0; ks < 2; ++ks) {
      bf16x8 af[4], bfv[2];
      #pragma unroll
      for (int fm = 0; fm < 4; ++fm)
        af[fm] = *reinterpret_cast<const bf16x8*>(&As[wr * 64 + fm * 16 + lq][ks * 32 + lg * 8]);
      #pragma unroll
      for (int fn = 0; fn < 2; ++fn)
        bfv[fn] = *reinterpret_cast<const bf16x8*>(&Bs[wc * 32 + fn * 16 + lq][ks * 32 + lg * 8]);
      #pragma unroll
      for (int fm = 0; fm < 4; ++fm)
        #pragma unroll
        for (int fn = 0; fn < 2; ++fn)
          acc[fm][fn] = mfma16(af[fm], bfv[fn], acc[fm][fn]);
    }
    __syncthreads();
  }

  const bool sec = (n0 >= CDIM);
  const int nb = n0 - (sec ? CDIM : 0) + wc * 32;
  const int nA = nb + lq, nB = nb + 16 + lq;

  if (EPI == 0) {
    const float* bias = sec ? bias1 : bias0;
    unsigned* dst = (unsigned*)(sec ? d1 : d0);
    const int* inv = sec ? inv1 : inv0;
    float bA = bias[nA], bB = bias[nB];
    #pragma unroll
    for (int fm = 0; fm < 4; ++fm) {
      int rbase = m0 + wr * 64 + fm * 16 + lg * 4;
      int cs = -1;
      float mA = 0.f, mB = 0.f;
      #pragma unroll
      for (int j = 0; j < 4; ++j) {
        int r = rbase + j;
        if (r < M) {
          int s = inv[r];
          float vA = acc[fm][0][j] + bA;
          float vB = acc[fm][1][j] + bB;
          if (s == cs) { mA = fmaxf(mA, vA); mB = fmaxf(mB, vB); }
          else {
            if (cs >= 0) {
              atomicMax(&dst[(size_t)cs * CDIM + nA], enc_f(mA));
              atomicMax(&dst[(size_t)cs * CDIM + nB], enc_f(mB));
            }
            cs = s; mA = vA; mB = vB;
          }
        }
      }
      if (cs >= 0) {
        atomicMax(&dst[(size_t)cs * CDIM + nA], enc_f(mA));
        atomicMax(&dst[(size_t)cs * CDIM + nB], enc_f(mB));
      }
    }
  } else if (EPI == 1) {
    float bA = bias0[nA], bB = bias0[nB];
    float* dst = (float*)d0;
    #pragma unroll
    for (int fm = 0; fm < 4; ++fm)
      #pragma unroll
      for (int j = 0; j < 4; ++j) {
        int r = m0 + wr * 64 + fm * 16 + lg * 4 + j;
        if (r < M) {
          dst[(size_t)r * CDIM + nA] = acc[fm][0][j] + bA;
          dst[(size_t)r * CDIM + nB] = acc[fm][1][j] + bB;
        }
      }
  } else if (EPI == 2) {
    // scale = log2(e)/sqrt(48): softmax via exp2 (exact rewrite)
    const float scale = 0.2082350914f;
    float bA = bias0[nA], bB = bias0[nB];
    int hA = nA / HD, dA = nA - hA * HD;
    int hB = nB / HD, dB = nB - hB * HD;
    __hip_bfloat16* dst = (__hip_bfloat16*)d0;
    #pragma unroll
    for (int fm = 0; fm < 4; ++fm)
      #pragma unroll
      for (int j = 0; j < 4; ++j) {
        int r = m0 + wr * 64 + fm * 16 + lg * 4 + j;
        if (r < M) {
          dst[(size_t)r * 512 + hA * 64 + dA] = __float2bfloat16((acc[fm][0][j] + bA) * scale);
          dst[(size_t)r * 512 + hB * 64 + dB] = __float2bfloat16((acc[fm][1][j] + bB) * scale);
        }
      }
  } else {  // EPI 3
    if (!sec) {
      float bA = bias0[nA], bB = bias0[nB];
      int hA = nA / HD, dA = nA - hA * HD;
      int hB = nB / HD, dB = nB - hB * HD;
      __hip_bfloat16* dst = (__hip_bfloat16*)d0;
      #pragma unroll
      for (int fm = 0; fm < 4; ++fm)
        #pragma unroll
        for (int j = 0; j < 4; ++j) {
          int r = m0 + wr * 64 + fm * 16 + lg * 4 + j;
          if (r < M) {
            dst[(size_t)r * 512 + hA * 64 + dA] = __float2bfloat16(acc[fm][0][j] + bA);
            dst[(size_t)r * 512 + hB * 64 + dB] = __float2bfloat16(acc[fm][1][j] + bB);
          }
        }
    } else {
      float bA = bias1[nA], bB = bias1[nB];
      int hA = nA / HD, dA = nA - hA * HD;
      int hB = nB / HD, dB = nB - hB * HD;
      __hip_bfloat16* dst = (__hip_bfloat16*)d1;
      #pragma unroll
      for (int fm = 0; fm < 4; ++fm)
        #pragma unroll
        for (int j = 0; j < 4; ++j) {
          int r = m0 + wr * 64 + fm * 16 + lg * 4 + j;
          if (r < M) {
            dst[(size_t)(hA * 64 + dA) * Mepad + r] = __float2bfloat16(acc[fm][0][j] + bA);
            dst[(size_t)(hB * 64 + dB) * Mepad + r] = __float2bfloat16(acc[fm][1][j] + bB);
          }
        }
    }
  }
  // pad-zero for q16/k16 head lanes d=48..63 (disjoint from data lanes).
  if ((EPI == 2 || EPI == 3) && n0 == 0) {
    __hip_bfloat16* dst = (__hip_bfloat16*)d0;
    for (int c = t; c < 1024; c += 256) {
      int r = m0 + (c >> 3);
      int hh = c & 7;
      if (r < M) {
        bf16x8 z = zero8();
        *reinterpret_cast<bf16x8*>(dst + (size_t)r * 512 + hh * 64 + 48) = z;
        *reinterpret_cast<bf16x8*>(dst + (size_t)r * 512 + hh * 64 + 56) = z;
      }
    }
  }
}

__global__ __launch_bounds__(256) void mgemm0_kernel(
    const __hip_bfloat16* __restrict__ A, int M, const __hip_bfloat16* __restrict__ Wt,
    const float* __restrict__ bias0, const float* __restrict__ bias1,
    unsigned* __restrict__ d0, unsigned* __restrict__ d1,
    const int* __restrict__ inv0, const int* __restrict__ inv1) {
  __shared__ __align__(16) __hip_bfloat16 As[128][72];
  __shared__ __align__(16) __hip_bfloat16 Bs[64][72];
  mgemm_body<0>(blockIdx.x, blockIdx.y, As, Bs, A, M, Wt, bias0, bias1, d0, d1, inv0, inv1, 0);
}

__global__ __launch_bounds__(256) void mgemm1_kernel(
    const __hip_bfloat16* __restrict__ A, int M, const __hip_bfloat16* __restrict__ Wt,
    const float* __restrict__ bias0, float* __restrict__ d0) {
  __shared__ __align__(16) __hip_bfloat16 As[128][72];
  __shared__ __align__(16) __hip_bfloat16 Bs[64][72];
  mgemm_body<1>(blockIdx.x, blockIdx.y, As, Bs, A, M, Wt, bias0, nullptr, d0, nullptr, nullptr, nullptr, 0);
}

// horizontally fused q-projection (EPI2) + kv-projection (EPI3)
__global__ __launch_bounds__(256) void qkv_kernel(
    const __hip_bfloat16* __restrict__ pool16, int Mp, const __hip_bfloat16* __restrict__ Wt_q,
    const float* __restrict__ bq,
    const __hip_bfloat16* __restrict__ emb16, int Me, const __hip_bfloat16* __restrict__ Wt_kv,
    const float* __restrict__ bk, const float* __restrict__ bv,
    __hip_bfloat16* __restrict__ q16, __hip_bfloat16* __restrict__ k16,
    __hip_bfloat16* __restrict__ vt, int Mepad, int nbQ, int gxQ, int gxK) {
  __shared__ __align__(16) __hip_bfloat16 As[128][72];
  __shared__ __align__(16) __hip_bfloat16 Bs[64][72];
  int b = blockIdx.x;
  if (b < nbQ) {
    mgemm_body<2>(b % gxQ, b / gxQ, As, Bs, pool16, Mp, Wt_q, bq, nullptr,
                  q16, nullptr, nullptr, nullptr, 0);
  } else {
    b -= nbQ;
    mgemm_body<3>(b % gxK, b / gxK, As, Bs, emb16, Me, Wt_kv, bk, bv,
                  k16, vt, nullptr, nullptr, Mepad);
  }
}

// MFMA flash attention: double-buffered LDS K/V, ONE barrier/iter.
__global__ __launch_bounds__(256) void attn_mfma_kernel(
    const __hip_bfloat16* __restrict__ qb, const __hip_bfloat16* __restrict__ kb,
    const __hip_bfloat16* __restrict__ vt, int Mepad,
    const int* __restrict__ pc, const int* __restrict__ eb,
    int Mp, int Me, __hip_bfloat16* __restrict__ ob) {
  __shared__ __align__(16) __hip_bfloat16 Ks[2][64][72];
  __shared__ __align__(16) __hip_bfloat16 Vs[2][64][72];
  __shared__ __align__(16) __hip_bfloat16 pl[4][16][72];
  __shared__ int sred[4][4];
  const int h = blockIdx.y;
  const int t = threadIdx.x;
  const int wv = t >> 6, lane = t & 63;
  const int lq = lane & 15, lg = lane >> 4;
  const int q0 = blockIdx.x * 64 + wv * 16;

  int lo[4], hi[4];
  #pragma unroll
  for (int r = 0; r < 4; ++r) {
    int q = q0 + lg * 4 + r;
    if (q < Mp) { int b = pc[4 * q]; lo[r] = eb[b]; hi[r] = eb[b + 1]; }
    else { lo[r] = 0x7fffffff; hi[r] = 0; }
  }
  int lomin = min(min(lo[0], lo[1]), min(lo[2], lo[3]));
  int lomax = max(max(lo[0], lo[1]), max(lo[2], lo[3]));
  int himin = min(min(hi[0], hi[1]), min(hi[2], hi[3]));
  int himax = max(max(hi[0], hi[1]), max(hi[2], hi[3]));
  #pragma unroll
  for (int off = 1; off < 64; off <<= 1) {
    lomin = min(lomin, __shfl_xor(lomin, off));
    lomax = max(lomax, __shfl_xor(lomax, off));
    himin = min(himin, __shfl_xor(himin, off));
    himax = max(himax, __shfl_xor(himax, off));
  }
  if (lane == 0) {
    sred[wv][0] = lomin; sred[wv][1] = lomax;
    sred[wv][2] = himin; sred[wv][3] = himax;
  }
  __syncthreads();
  lomin = min(min(sred[0][0], sred[1][0]), min(sred[2][0], sred[3][0]));
  lomax = max(max(sred[0][1], sred[1][1]), max(sred[2][1], sred[3][1]));
  himin = min(min(sred[0][2], sred[1][2]), min(sred[2][2], sred[3][2]));
  himax = max(max(sred[0][3], sred[1][3]), max(sred[2][3], sred[3][3]));

  int qrow = min(q0 + lq, Mp - 1);
  const __hip_bfloat16* qp = qb + (size_t)qrow * 512 + h * 64 + lg * 8;
  bf16x8 aq0 = *reinterpret_cast<const bf16x8*>(qp);
  bf16x8 aq1 = *reinterpret_cast<const bf16x8*>(qp + 32);

  const int str = t >> 2;
  const int stc = (t & 3) * 16;
  const __hip_bfloat16* vrow = vt + (size_t)(h * 64 + str) * Mepad + stc;

  f32x4 zero = {0.f, 0.f, 0.f, 0.f};
  f32x4 oacc[4];
  oacc[0] = zero; oacc[1] = zero; oacc[2] = zero; oacc[3] = zero;

  bf16x8 k0, k1, v0, v1;
  auto load_tile = [&](int e0) {
    int er = e0 + str;
    k0 = zero8(); k1 = zero8();
    if (er < Me) {
      const __hip_bfloat16* kp = kb + (size_t)er * 512 + h * 64 + stc;
      k0 = *reinterpret_cast<const bf16x8*>(kp);
      k1 = *reinterpret_cast<const bf16x8*>(kp + 8);
    }
    v0 = *reinterpret_cast<const bf16x8*>(vrow + e0);
    v1 = *reinterpret_cast<const bf16x8*>(vrow + e0 + 8);
  };
  auto store_tile = [&](int nb) {
    *reinterpret_cast<bf16x8*>(&Ks[nb][str][stc]) = k0;
    *reinterpret_cast<bf16x8*>(&Ks[nb][str][stc + 8]) = k1;
    *reinterpret_cast<bf16x8*>(&Vs[nb][str][stc]) = v0;
    *reinterpret_cast<bf16x8*>(&Vs[nb][str][stc + 8]) = v1;
  };
  const int e0beg = lomin & ~63;
  load_tile(e0beg);
  store_tile(0);
  if (e0beg + 64 < himax) load_tile(e0beg + 64);

  int it = 0;
  for (int e0 = e0beg; e0 < himax; e0 += 64, ++it) {
    __syncthreads();
    const int cur = it & 1;
    if (e0 + 64 < himax) {
      store_tile(cur ^ 1);
      if (e0 + 128 < himax) load_tile(e0 + 128);
    }

    f32x4 sf[4];
    #pragma unroll
    for (int s = 0; s < 4; ++s) {
      bf16x8 bk0 = *reinterpret_cast<const bf16x8*>(&Ks[cur][s * 16 + lq][lg * 8]);
      bf16x8 bk1 = *reinterpret_cast<const bf16x8*>(&Ks[cur][s * 16 + lq][32 + lg * 8]);
      f32x4 z = zero;
      z = mfma16(aq0, bk0, z);
      z = mfma16(aq1, bk1, z);
      sf[s] = z;
    }
    const bool interior = (e0 >= lomax) && (e0 + 64 <= himin);
    if (interior) {
      #pragma unroll
      for (int s = 0; s < 4; ++s)
        #pragma unroll
        for (int r = 0; r < 4; ++r)
          pl[wv][lg * 4 + r][s * 16 + lq] = __float2bfloat16(exp2f(sf[s][r]));
    } else {
      #pragma unroll
      for (int s = 0; s < 4; ++s) {
        int e = e0 + s * 16 + lq;
        #pragma unroll
        for (int r = 0; r < 4; ++r) {
          bool m = (e >= lo[r]) && (e < hi[r]);
          float p = m ? exp2f(sf[s][r]) : 0.f;
          pl[wv][lg * 4 + r][s * 16 + lq] = __float2bfloat16(p);
        }
      }
    }
    asm volatile("s_waitcnt lgkmcnt(0)" ::: "memory");
    __builtin_amdgcn_sched_barrier(0);  // rule #18
    #pragma unroll
    for (int ks = 0; ks < 2; ++ks) {
      bf16x8 ap = *reinterpret_cast<const bf16x8*>(&pl[wv][lq][ks * 32 + lg * 8]);
      #pragma unroll
      for (int dt = 0; dt < 4; ++dt) {
        bf16x8 bv = *reinterpret_cast<const bf16x8*>(&Vs[cur][dt * 16 + lq][ks * 32 + lg * 8]);
        oacc[dt] = mfma16(ap, bv, oacc[dt]);
      }
    }
  }

  #pragma unroll
  for (int r = 0; r < 4; ++r) {
    float l = __shfl(oacc[3][r], (lane & 48));
    int q = q0 + lg * 4 + r;
    if (q < Mp && l > 0.f) {
      float inv = 1.0f / l;
      __hip_bfloat16* op = ob + (size_t)q * CDIM + h * HD;
      op[lq]      = __float2bfloat16(oacc[0][r] * inv);
      op[16 + lq] = __float2bfloat16(oacc[1][r] * inv);
      op[32 + lq] = __float2bfloat16(oacc[2][r] * inv);
    }
  }
}

__global__ void newf16_kernel(const float* __restrict__ feats, const float* __restrict__ o2,
                              const int* __restrict__ pinv, __hip_bfloat16* __restrict__ nf,
                              int N) {
  int v = blockIdx.x * 256 + threadIdx.x;
  if (v >= N * 48) return;
  int n = v / 48, c8 = (v - n * 48) * 8;
  const float* fp = feats + (size_t)n * CDIM + c8;
  const float* op = o2 + (size_t)pinv[n] * CDIM + c8;
  float4 a0 = *reinterpret_cast<const float4*>(fp);
  float4 a1 = *reinterpret_cast<const float4*>(fp + 4);
  float4 b0 = *reinterpret_cast<const float4*>(op);
  float4 b1 = *reinterpret_cast<const float4*>(op + 4);
  __hip_bfloat16 tmp[8] = {
    __float2bfloat16(a0.x + b0.x), __float2bfloat16(a0.y + b0.y),
    __float2bfloat16(a0.z + b0.z), __float2bfloat16(a0.w + b0.w),
    __float2bfloat16(a1.x + b1.x), __float2bfloat16(a1.y + b1.y),
    __float2bfloat16(a1.z + b1.z), __float2bfloat16(a1.w + b1.w)};
  *reinterpret_cast<bf16x8*>(nf + (size_t)v * 8) = *reinterpret_cast<const bf16x8*>(tmp);
}

// conv as MFMA GEMM: M=N rows, 32 cols, K split by tap groups (9 x 3 taps).
__global__ __launch_bounds__(256) void mconv_kernel(
    const __hip_bfloat16* __restrict__ nf, const int* __restrict__ nbr,
    const __hip_bfloat16* __restrict__ Wct, float* __restrict__ outp, int N) {
  __shared__ __align__(16) __hip_bfloat16 As[128][72];
  __shared__ __align__(16) __hip_bfloat16 Bs[32][72];
  __shared__ int jrow[128];
  const int n0 = blockIdx.x * 128;
  const int kg = blockIdx.y;
  const int t = threadIdx.x;
  const int lane = t & 63, w = t >> 6;
  const int lq = lane & 15, lg = lane >> 4;
  f32x4 acc[2][2];
  acc[0][0] = (f32x4){0.f,0.f,0.f,0.f}; acc[0][1] = acc[0][0];
  acc[1][0] = acc[0][0]; acc[1][1] = acc[0][0];
  const int arow = t >> 3, acol = (t & 7) * 8;

  for (int kk = kg * 3; kk < kg * 3 + 3; ++kk) {
    __syncthreads();
    if (t < 128) {
      int n = n0 + t;
      jrow[t] = (n < N) ? nbr[(size_t)n * 27 + kk] : -1;
    }
    __syncthreads();
    for (int c0 = 0; c0 < CDIM; c0 += 64) {
      #pragma unroll
      for (int i = 0; i < 4; ++i) {
        int r = arow + i * 32;
        int j = jrow[r];
        bf16x8 val = zero8();
        if (j >= 0) val = *reinterpret_cast<const bf16x8*>(nf + (size_t)j * CDIM + c0 + acol);
        *reinterpret_cast<bf16x8*>(&As[r][acol]) = val;
      }
      {
        int r = t >> 3;
        bf16x8 val = *reinterpret_cast<const bf16x8*>(Wct + (size_t)r * CONVK + kk * CDIM + c0 + acol);
        *reinterpret_cast<bf16x8*>(&Bs[r][acol]) = val;
      }
      __syncthreads();
      #pragma unroll
      for (int ks = 0; ks < 2; ++ks) {
        bf16x8 af[2], bfv[2];
        #pragma unroll
        for (int fm = 0; fm < 2; ++fm)
          af[fm] = *reinterpret_cast<const bf16x8*>(&As[w * 32 + fm * 16 + lq][ks * 32 + lg * 8]);
        #pragma unroll
        for (int fn = 0; fn < 2; ++fn)
          bfv[fn] = *reinterpret_cast<const bf16x8*>(&Bs[fn * 16 + lq][ks * 32 + lg * 8]);
        #pragma unroll
        for (int fm = 0; fm < 2; ++fm)
          #pragma unroll
          for (int fn = 0; fn < 2; ++fn)
            acc[fm][fn] = mfma16(af[fm], bfv[fn], acc[fm][fn]);
      }
      __syncthreads();
    }
  }
  #pragma unroll
  for (int fm = 0; fm < 2; ++fm)
    #pragma unroll
    for (int j = 0; j < 4; ++j) {
      int r = n0 + w * 32 + fm * 16 + lg * 4 + j;
      if (r < N) {
        #pragma unroll
        for (int fn = 0; fn < 2; ++fn)
          outp[((size_t)kg * N + r) * OUTD + fn * 16 + lq] = acc[fm][fn][j];
      }
    }
}

__global__ void conv_reduce_kernel(const float* __restrict__ outp,
                                   const float* __restrict__ bc,
                                   float* __restrict__ out, int N) {
  int v = blockIdx.x * 256 + threadIdx.x;
  if (v >= N * OUTD) return;
  int oo = v & (OUTD - 1);
  float s = bc[oo];
  #pragma unroll
  for (int kg = 0; kg < 9; ++kg) s += outp[(size_t)kg * N * OUTD + v];
  out[v] = s;
}

extern "C" void kernel_launch(void* const* d_in, const int* in_sizes, int n_in,
                              void* d_out, int out_size, void* d_ws, size_t ws_size,
                              hipStream_t stream) {
  const float* feats  = (const float*)d_in[0];
  const float* W_pool = (const float*)d_in[1];
  const float* b_pool = (const float*)d_in[2];
  const float* W_emb  = (const float*)d_in[3];
  const float* b_emb  = (const float*)d_in[4];
  const float* Wq = (const float*)d_in[5];  const float* bq = (const float*)d_in[6];
  const float* Wk = (const float*)d_in[7];  const float* bk = (const float*)d_in[8];
  const float* Wv = (const float*)d_in[9];  const float* bv = (const float*)d_in[10];
  const float* Wo = (const float*)d_in[11]; const float* bo = (const float*)d_in[12];
  const float* Wc = (const float*)d_in[13]; const float* bc = (const float*)d_in[14];
  const int* pool_inv    = (const int*)d_in[15];
  const int* pool_coords = (const int*)d_in[16];
  const int* emb_inv     = (const int*)d_in[17];
  const int* emb_coords  = (const int*)d_in[18];
  const int* nbr         = (const int*)d_in[19];
  const int* bsz         = (const int*)d_in[20];
  int N  = in_sizes[0] / CDIM;
  int Mp = in_sizes[16] / 4;
  int Me = in_sizes[18] / 4;
  int Mepad = ((Me >> 6) + 2) << 6;

  char* wsb = (char*)d_ws;
  size_t off = 0;
  auto alloc = [&](size_t bytes) { void* p = wsb + off; off += (bytes + 255) & ~(size_t)255; return p; };
  unsigned* encA = (unsigned*)alloc((size_t)Mp * CDIM * 4);
  unsigned* encB = (unsigned*)alloc((size_t)Me * CDIM * 4);
  __hip_bfloat16* vt = (__hip_bfloat16*)alloc((size_t)512 * Mepad * 2);
  __hip_bfloat16* pool16  = (__hip_bfloat16*)alloc((size_t)Mp * CDIM * 2);
  __hip_bfloat16* emb16   = (__hip_bfloat16*)alloc((size_t)Me * CDIM * 2);
  __hip_bfloat16* feats16 = (__hip_bfloat16*)alloc((size_t)N * CDIM * 2);
  float* o2 = (float*)alloc((size_t)Mp * CDIM * 4 > (size_t)9 * N * OUTD * 4
                                ? (size_t)Mp * CDIM * 4 : (size_t)9 * N * OUTD * 4);
  __hip_bfloat16* Wt_pe = (__hip_bfloat16*)alloc((size_t)768 * CDIM * 2);
  __hip_bfloat16* Wt_kv = (__hip_bfloat16*)alloc((size_t)768 * CDIM * 2);
  __hip_bfloat16* Wt_q  = (__hip_bfloat16*)alloc((size_t)CDIM * CDIM * 2);
  __hip_bfloat16* Wt_o  = (__hip_bfloat16*)alloc((size_t)CDIM * CDIM * 2);
  __hip_bfloat16* Wct   = (__hip_bfloat16*)alloc((size_t)OUTD * CONVK * 2);
  int* smin = (int*)alloc(MAXB * 3 * 4);
  int* smax = (int*)alloc(MAXB * 3 * 4);
  int* eb   = (int*)alloc((MAXB + 1) * 4);

  __hip_bfloat16* q16  = (__hip_bfloat16*)encA;   // [Mp][512]
  __hip_bfloat16* k16  = (__hip_bfloat16*)encB;   // [Me][512]
  __hip_bfloat16* ob16 = pool16;                  // [Mp][384]
  __hip_bfloat16* newf16 = feats16;               // [N][384]
  float* outp = o2;                               // [9][N][32]

  // no hipMemsetAsync anywhere: rocclr fill kernels measured ~40us each.
  init_small_kernel<<<1, 64, 0, stream>>>(smin, smax, eb);

  int nbF  = (N * 48 + 255) / 256;
  int nbW  = (CDIM * 48 + 255) / 256;
  int nbC  = (OUTD * (CONVK / 8) + 255) / 256;
  int nbZA = ((Mp * 96) + 255) / 256;
  int nbZB = ((Me * 96) + 255) / 256;
  int nbVt = ((512 * (Mepad >> 3)) + 255) / 256;
  int nbM  = (Mp + Me + 255) / 256;
  int nbE  = (Me + 255) / 256;
  prep_kernel<<<nbF + 6 * nbW + nbC + nbZA + nbZB + nbVt + nbM + nbE, 256, 0, stream>>>(
      feats, feats16, N, W_pool, W_emb, Wk, Wv, Wq, Wo,
      Wt_pe, Wt_kv, Wt_q, Wt_o, Wc, Wct, encA, encB, vt, Mepad,
      emb_coords, pool_coords, Mp, Me, bsz, smin, smax, eb,
      nbF, nbW, nbC, nbZA, nbZB, nbVt, nbM);

  mgemm0_kernel<<<dim3((N + 127) / 128, 12), 256, 0, stream>>>(
      feats16, N, Wt_pe, b_pool, b_emb, encA, encB, pool_inv, emb_inv);
  pe_kernel<<<((Mp + Me) * CDIM + 255) / 256, 256, 0, stream>>>(
      encA, encB, pool16, emb16, pool_coords, Mp, emb_coords, Me, smin, smax);

  // fused q + kv projections (pads zeroed in-kernel)
  {
    int gxQ = (Mp + 127) / 128, gxK = (Me + 127) / 128;
    int nbQ = gxQ * 6;
    qkv_kernel<<<nbQ + gxK * 12, 256, 0, stream>>>(
        pool16, Mp, Wt_q, bq, emb16, Me, Wt_kv, bk, bv,
        q16, k16, vt, Mepad, nbQ, gxQ, gxK);
  }

  attn_mfma_kernel<<<dim3((Mp + 63) / 64, NHEAD), 256, 0, stream>>>(
      q16, k16, vt, Mepad, pool_coords, eb, Mp, Me, ob16);

  mgemm1_kernel<<<dim3((Mp + 127) / 128, 6), 256, 0, stream>>>(
      ob16, Mp, Wt_o, bo, o2);

  newf16_kernel<<<(N * 48 + 255) / 256, 256, 0, stream>>>(feats, o2, pool_inv, newf16, N);

  mconv_kernel<<<dim3((N + 127) / 128, 9), 256, 0, stream>>>(newf16, nbr, Wct, outp, N);
  conv_reduce_kernel<<<(N * OUTD + 255) / 256, 256, 0, stream>>>(outp, bc, (float*)d_out, N);
}